// Round 1
// baseline (2195.572 us; speedup 1.0000x reference)
//
#include <hip/hip_runtime.h>
#include <cstdint>

constexpr int Bb  = 8;
constexpr int Ls  = 1024;
constexpr int DM  = 512;
constexpr int NH  = 8;
constexpr int DHd = 64;
constexpr int MR  = Bb * Ls;   // 8192 rows
constexpr int ZH  = Bb * NH;   // 64 (b,h) pairs
constexpr int CQ  = 256;       // q-chunk for full attention

// ---------------- generic GEMM: C = act(A @ W + bias) ----------------
// A: M x K row-major, W: K x N row-major. M%128==0, N%64==0, K%16==0.
template<int RELU>
__global__ __launch_bounds__(256) void k_gemm_bias(
    const float* __restrict__ A, const float* __restrict__ W,
    const float* __restrict__ bias, float* __restrict__ C,
    int M, int N, int K)
{
  constexpr int BM = 128, BN = 64, BK = 16;
  __shared__ float As[BK][BM + 4];
  __shared__ float Bs[BK][BN + 4];
  const int tid = threadIdx.x;
  const int bm = blockIdx.x * BM, bn = blockIdx.y * BN;
  const int arow = tid >> 2, acol = (tid & 3) << 2;
  const int brow = tid >> 4, bcol = (tid & 15) << 2;
  const int mB = (tid >> 4) << 3, nB = (tid & 15) << 2;
  float acc[8][4] = {};
  for (int k0 = 0; k0 < K; k0 += BK) {
#pragma unroll
    for (int i = 0; i < 2; ++i) {
      int r = arow + (i << 6);
      float4 a4 = *reinterpret_cast<const float4*>(A + (size_t)(bm + r) * K + k0 + acol);
      As[acol + 0][r] = a4.x; As[acol + 1][r] = a4.y;
      As[acol + 2][r] = a4.z; As[acol + 3][r] = a4.w;
    }
    *reinterpret_cast<float4*>(&Bs[brow][bcol]) =
        *reinterpret_cast<const float4*>(W + (size_t)(k0 + brow) * N + bn + bcol);
    __syncthreads();
#pragma unroll
    for (int kk = 0; kk < BK; ++kk) {
      float4 b4 = *reinterpret_cast<const float4*>(&Bs[kk][nB]);
      float4 a0 = *reinterpret_cast<const float4*>(&As[kk][mB]);
      float4 a1 = *reinterpret_cast<const float4*>(&As[kk][mB + 4]);
      const float av[8] = {a0.x, a0.y, a0.z, a0.w, a1.x, a1.y, a1.z, a1.w};
#pragma unroll
      for (int i = 0; i < 8; ++i) {
        acc[i][0] += av[i] * b4.x; acc[i][1] += av[i] * b4.y;
        acc[i][2] += av[i] * b4.z; acc[i][3] += av[i] * b4.w;
      }
    }
    __syncthreads();
  }
  float4 bi4 = *reinterpret_cast<const float4*>(bias + bn + nB);
#pragma unroll
  for (int i = 0; i < 8; ++i) {
    float4 o;
    o.x = acc[i][0] + bi4.x; o.y = acc[i][1] + bi4.y;
    o.z = acc[i][2] + bi4.z; o.w = acc[i][3] + bi4.w;
    if (RELU) {
      o.x = fmaxf(o.x, 0.f); o.y = fmaxf(o.y, 0.f);
      o.z = fmaxf(o.z, 0.f); o.w = fmaxf(o.w, 0.f);
    }
    *reinterpret_cast<float4*>(C + (size_t)(bm + mB + i) * N + bn + nB) = o;
  }
}

// ---------------- batched scores: S[z] = scale * Qrows @ K^T ----------------
// z = b*NH+h over gridDim.z. Q/K in merged (B*L, DM) layout, head cols h*64..
// If top != nullptr, q-row r is top[z*topStride + r] (clamped), else q0+row.
__global__ __launch_bounds__(256) void k_qkT(
    const float* __restrict__ Qm, const float* __restrict__ Km,
    float* __restrict__ S, const int* __restrict__ top,
    int q0, int Mrows, int Mld, int topStride, float scale)
{
  __shared__ float Qs[DHd][64 + 4];
  __shared__ float Ks[DHd][64 + 4];
  const int tid = threadIdx.x;
  const int z = blockIdx.z, b = z >> 3, h = z & 7;
  const int m0 = blockIdx.x << 6, n0 = blockIdx.y << 6;
  const float* Kbase = Km + ((size_t)(b * Ls + n0)) * DM + h * DHd;
#pragma unroll
  for (int i = 0; i < 4; ++i) {
    int idx = tid + (i << 8);
    int r = idx >> 4, c4 = (idx & 15) << 2;
    int qr;
    if (top) { int u = m0 + r; if (u >= Mrows) u = Mrows - 1; qr = top[z * topStride + u]; }
    else qr = q0 + m0 + r;
    float4 q4 = *reinterpret_cast<const float4*>(Qm + ((size_t)(b * Ls + qr)) * DM + h * DHd + c4);
    Qs[c4 + 0][r] = q4.x; Qs[c4 + 1][r] = q4.y; Qs[c4 + 2][r] = q4.z; Qs[c4 + 3][r] = q4.w;
    float4 k4 = *reinterpret_cast<const float4*>(Kbase + (size_t)r * DM + c4);
    Ks[c4 + 0][r] = k4.x; Ks[c4 + 1][r] = k4.y; Ks[c4 + 2][r] = k4.z; Ks[c4 + 3][r] = k4.w;
  }
  __syncthreads();
  const int mB = (tid >> 4) << 2, nB = (tid & 15) << 2;
  float acc[4][4] = {};
#pragma unroll
  for (int kk = 0; kk < DHd; ++kk) {
    float4 a4 = *reinterpret_cast<const float4*>(&Qs[kk][mB]);
    float4 b4 = *reinterpret_cast<const float4*>(&Ks[kk][nB]);
    const float av[4] = {a4.x, a4.y, a4.z, a4.w};
#pragma unroll
    for (int i = 0; i < 4; ++i) {
      acc[i][0] += av[i] * b4.x; acc[i][1] += av[i] * b4.y;
      acc[i][2] += av[i] * b4.z; acc[i][3] += av[i] * b4.w;
    }
  }
#pragma unroll
  for (int i = 0; i < 4; ++i) {
    int m = m0 + mB + i;
    if (m < Mrows) {
      float4 o;
      o.x = acc[i][0] * scale; o.y = acc[i][1] * scale;
      o.z = acc[i][2] * scale; o.w = acc[i][3] * scale;
      *reinterpret_cast<float4*>(S + ((size_t)z * Mld + m) * Ls + n0 + nB) = o;
    }
  }
}

// ---------------- row softmax over length 1024 (in place) ----------------
__global__ __launch_bounds__(256) void k_softmax(float* __restrict__ S)
{
  __shared__ float red[4];
  const int row = blockIdx.x, tid = threadIdx.x;
  float* p = S + (size_t)row * Ls;
  float4 v = *reinterpret_cast<float4*>(p + (tid << 2));
  float mx = fmaxf(fmaxf(v.x, v.y), fmaxf(v.z, v.w));
#pragma unroll
  for (int off = 32; off; off >>= 1) mx = fmaxf(mx, __shfl_xor(mx, off));
  if ((tid & 63) == 0) red[tid >> 6] = mx;
  __syncthreads();
  mx = fmaxf(fmaxf(red[0], red[1]), fmaxf(red[2], red[3]));
  __syncthreads();
  v.x = __expf(v.x - mx); v.y = __expf(v.y - mx);
  v.z = __expf(v.z - mx); v.w = __expf(v.w - mx);
  float s = v.x + v.y + v.z + v.w;
#pragma unroll
  for (int off = 32; off; off >>= 1) s += __shfl_xor(s, off);
  if ((tid & 63) == 0) red[tid >> 6] = s;
  __syncthreads();
  s = red[0] + red[1] + red[2] + red[3];
  float inv = 1.0f / s;
  v.x *= inv; v.y *= inv; v.z *= inv; v.w *= inv;
  *reinterpret_cast<float4*>(p + (tid << 2)) = v;
}

// ---------------- PV: Out = P @ V (batched over z) ----------------
// probMode: Out compact (z*outStride + m)*64; else merged rows q0+m, cols h*64..
__global__ __launch_bounds__(256) void k_pv(
    const float* __restrict__ S, const float* __restrict__ Vm,
    float* __restrict__ Out, int q0, int Mrows, int Mld, int outStride, int probMode)
{
  __shared__ float Ps[16][64 + 4];
  __shared__ float Vs[16][64 + 4];
  const int tid = threadIdx.x;
  const int z = blockIdx.z, b = z >> 3, h = z & 7;
  const int m0 = blockIdx.x << 6;
  const int pr = tid >> 2, pc = (tid & 3) << 2;
  const int vr = tid >> 4, vc = (tid & 15) << 2;
  const int mB = (tid >> 4) << 2, nB = (tid & 15) << 2;
  float acc[4][4] = {};
  for (int k0 = 0; k0 < Ls; k0 += 16) {
    float4 p4 = *reinterpret_cast<const float4*>(S + ((size_t)z * Mld + m0 + pr) * Ls + k0 + pc);
    Ps[pc + 0][pr] = p4.x; Ps[pc + 1][pr] = p4.y; Ps[pc + 2][pr] = p4.z; Ps[pc + 3][pr] = p4.w;
    *reinterpret_cast<float4*>(&Vs[vr][vc]) =
        *reinterpret_cast<const float4*>(Vm + ((size_t)(b * Ls + k0 + vr)) * DM + h * DHd + vc);
    __syncthreads();
#pragma unroll
    for (int kk = 0; kk < 16; ++kk) {
      float4 a4 = *reinterpret_cast<const float4*>(&Ps[kk][mB]);
      float4 b4 = *reinterpret_cast<const float4*>(&Vs[kk][nB]);
      const float av[4] = {a4.x, a4.y, a4.z, a4.w};
#pragma unroll
      for (int i = 0; i < 4; ++i) {
        acc[i][0] += av[i] * b4.x; acc[i][1] += av[i] * b4.y;
        acc[i][2] += av[i] * b4.z; acc[i][3] += av[i] * b4.w;
      }
    }
    __syncthreads();
  }
#pragma unroll
  for (int i = 0; i < 4; ++i) {
    int m = m0 + mB + i;
    if (m < Mrows) {
      float4 o; o.x = acc[i][0]; o.y = acc[i][1]; o.z = acc[i][2]; o.w = acc[i][3];
      if (probMode)
        *reinterpret_cast<float4*>(Out + ((size_t)z * outStride + m) * DHd + nB) = o;
      else
        *reinterpret_cast<float4*>(Out + ((size_t)(b * Ls + q0 + m)) * DM + h * DHd + nB) = o;
    }
  }
}

// ---------------- ProbSparse sampled scores: M = max_u(q.k_u) - sum_u(q.k_u)/Lk ----------------
__global__ __launch_bounds__(256) void k_mscore(
    const float* __restrict__ Qm, const float* __restrict__ Km,
    const int* __restrict__ smp, float* __restrict__ Ms, int U)
{
  const int gw = blockIdx.x * 4 + (threadIdx.x >> 6);   // global wave = (b,h,l)
  const int lane = threadIdx.x & 63;
  const int l = gw & (Ls - 1);
  const int z = gw >> 10, b = z >> 3, h = z & 7;
  const float q = Qm[((size_t)(b * Ls + l)) * DM + h * DHd + lane];
  float mx = -1e30f, sm = 0.f;
  for (int u = 0; u < U; ++u) {
    int ki = smp[l * U + u];
    float p = q * Km[((size_t)(b * Ls + ki)) * DM + h * DHd + lane];
#pragma unroll
    for (int off = 32; off; off >>= 1) p += __shfl_xor(p, off);
    mx = fmaxf(mx, p); sm += p;
  }
  if (lane == 0) Ms[z * Ls + l] = mx - sm * (1.0f / Ls);
}

// ---------------- iterative top-U (ties -> lowest index, matches lax.top_k set) ----------------
__global__ __launch_bounds__(256) void k_topk(
    const float* __restrict__ Ms, int* __restrict__ top, int U)
{
  __shared__ float v[Ls];
  __shared__ float rv[256];
  __shared__ int   ri[256];
  const int z = blockIdx.x, tid = threadIdx.x;
  for (int i = tid; i < Ls; i += 256) v[i] = Ms[z * Ls + i];
  __syncthreads();
  for (int it = 0; it < U; ++it) {
    float bv = -1e30f; int bi = 0x7fffffff;
    for (int i = tid; i < Ls; i += 256) {
      float x = v[i];
      if (x > bv || (x == bv && i < bi)) { bv = x; bi = i; }
    }
    rv[tid] = bv; ri[tid] = bi;
    __syncthreads();
    for (int s = 128; s; s >>= 1) {
      if (tid < s) {
        float xv = rv[tid + s]; int xi = ri[tid + s];
        if (xv > rv[tid] || (xv == rv[tid] && xi < ri[tid])) { rv[tid] = xv; ri[tid] = xi; }
      }
      __syncthreads();
    }
    if (tid == 0) { top[z * U + it] = ri[0]; v[ri[0]] = -1e30f; }
    __syncthreads();
  }
}

// ---------------- mean of V over keys per (b,h,d) ----------------
__global__ __launch_bounds__(256) void k_meanv(
    const float* __restrict__ Vm, float* __restrict__ mv)
{
  __shared__ float ps[4][64];
  const int z = blockIdx.x, b = z >> 3, h = z & 7;
  const int d = threadIdx.x & 63, g = threadIdx.x >> 6;
  float s = 0.f;
  for (int k = g * 256; k < (g + 1) * 256; ++k)
    s += Vm[((size_t)(b * Ls + k)) * DM + h * DHd + d];
  ps[g][d] = s;
  __syncthreads();
  if (g == 0) mv[z * 64 + d] = (ps[0][d] + ps[1][d] + ps[2][d] + ps[3][d]) * (1.0f / Ls);
}

// ---------------- broadcast mean-V into merged ctx ----------------
__global__ __launch_bounds__(256) void k_ctxfill(
    const float* __restrict__ mv, float* __restrict__ ctx)
{
  const int i = blockIdx.x * 256 + threadIdx.x;    // float4 index
  const int c4 = (i & 127) << 2;
  const int row = i >> 7;
  const int b = row >> 10;
  const int h = c4 >> 6;
  float4 m4 = *reinterpret_cast<const float4*>(mv + ((b * 8 + h) * 64) + (c4 & 63));
  *reinterpret_cast<float4*>(ctx + (size_t)row * DM + c4) = m4;
}

// ---------------- scatter upd rows into ctx at top indices ----------------
__global__ __launch_bounds__(256) void k_scatter(
    const float* __restrict__ upd, const int* __restrict__ top,
    float* __restrict__ ctx, int U, int Uld)
{
  const int z = blockIdx.x, b = z >> 3, h = z & 7;
  const int d = threadIdx.x & 63;
  for (int u = threadIdx.x >> 6; u < U; u += 4) {
    int row = top[z * U + u];
    ctx[((size_t)(b * Ls + row)) * DM + h * DHd + d] =
        upd[((size_t)z * Uld + u) * DHd + d];
  }
}

// ---------------- fused (residual +) LayerNorm over rows of 512 ----------------
__global__ __launch_bounds__(256) void k_ln(
    const float* __restrict__ x, const float* __restrict__ res,
    const float* __restrict__ g, const float* __restrict__ be,
    float* __restrict__ out)
{
  __shared__ float red[4];
  const int row = blockIdx.x, tid = threadIdx.x;
  const size_t base = (size_t)row * DM;
  float2 v = *reinterpret_cast<const float2*>(x + base + tid * 2);
  if (res) {
    float2 r2 = *reinterpret_cast<const float2*>(res + base + tid * 2);
    v.x += r2.x; v.y += r2.y;
  }
  float s = v.x + v.y;
#pragma unroll
  for (int off = 32; off; off >>= 1) s += __shfl_xor(s, off);
  if ((tid & 63) == 0) red[tid >> 6] = s;
  __syncthreads();
  s = red[0] + red[1] + red[2] + red[3];
  const float mean = s * (1.0f / DM);
  __syncthreads();
  float dx = v.x - mean, dy = v.y - mean;
  float q = dx * dx + dy * dy;
#pragma unroll
  for (int off = 32; off; off >>= 1) q += __shfl_xor(q, off);
  if ((tid & 63) == 0) red[tid >> 6] = q;
  __syncthreads();
  q = red[0] + red[1] + red[2] + red[3];
  const float inv = rsqrtf(q * (1.0f / DM) + 1e-5f);
  float2 gg = *reinterpret_cast<const float2*>(g + tid * 2);
  float2 bb = *reinterpret_cast<const float2*>(be + tid * 2);
  float2 o;
  o.x = dx * inv * gg.x + bb.x;
  o.y = dy * inv * gg.y + bb.y;
  *reinterpret_cast<float2*>(out + base + tid * 2) = o;
}

extern "C" void kernel_launch(void* const* d_in, const int* in_sizes, int n_in,
                              void* d_out, int out_size, void* d_ws, size_t ws_size,
                              hipStream_t stream)
{
  const float* tgt = (const float*)d_in[0];
  const float* mem = (const float*)d_in[1];
  const int*   smp = (const int*)d_in[2];
  const float* wq1 = (const float*)d_in[3];  const float* bq1 = (const float*)d_in[4];
  const float* wk1 = (const float*)d_in[5];  const float* bk1 = (const float*)d_in[6];
  const float* wv1 = (const float*)d_in[7];  const float* bv1 = (const float*)d_in[8];
  const float* wo1 = (const float*)d_in[9];  const float* bo1 = (const float*)d_in[10];
  const float* wq2 = (const float*)d_in[11]; const float* bq2 = (const float*)d_in[12];
  const float* wk2 = (const float*)d_in[13]; const float* bk2 = (const float*)d_in[14];
  const float* wv2 = (const float*)d_in[15]; const float* bv2 = (const float*)d_in[16];
  const float* wo2 = (const float*)d_in[17]; const float* bo2 = (const float*)d_in[18];
  const float* c1w = (const float*)d_in[19]; const float* c1b = (const float*)d_in[20];
  const float* c2w = (const float*)d_in[21]; const float* c2b = (const float*)d_in[22];
  const float* g1  = (const float*)d_in[23]; const float* be1 = (const float*)d_in[24];
  const float* g2  = (const float*)d_in[25]; const float* be2 = (const float*)d_in[26];
  const float* g3  = (const float*)d_in[27]; const float* be3 = (const float*)d_in[28];
  float* outp = (float*)d_out;

  const int U   = in_sizes[2] / Ls;            // 35
  const int Uld = ((U + 63) / 64) * 64;        // 64

  char* ws = (char*)d_ws;
  const size_t SZ = (size_t)MR * DM * sizeof(float);  // 16.78 MB
  float* W0   = (float*)(ws);
  float* W1   = (float*)(ws + SZ);
  float* W2   = (float*)(ws + 2 * SZ);
  float* Sbuf = (float*)(ws + 3 * SZ);                // 67 MB: ZH*CQ*Ls floats
  char* tail  = ws + 7 * SZ;
  float* Ms  = (float*)tail; tail += (size_t)ZH * Ls * 4;
  int*   top = (int*)tail;   tail += (size_t)ZH * Uld * 4;
  float* mv  = (float*)tail; tail += (size_t)ZH * DHd * 4;
  float* upd = (float*)tail; tail += (size_t)ZH * Uld * DHd * 4;
  float* W3  = outp;  // V2 parked in d_out (dead before final LN writes it)

  auto gemm = [&](const float* A, const float* Wm, const float* bi, float* C,
                  int M, int N, int K, bool relu) {
    dim3 g(M / 128, N / 64);
    if (relu) k_gemm_bias<1><<<g, 256, 0, stream>>>(A, Wm, bi, C, M, N, K);
    else      k_gemm_bias<0><<<g, 256, 0, stream>>>(A, Wm, bi, C, M, N, K);
  };

  // ---- layer-1 projections (Q1,K1,V1) ----
  gemm(tgt, wq1, bq1, W0, MR, DM, DM, false);
  gemm(tgt, wk1, bk1, W1, MR, DM, DM, false);
  gemm(tgt, wv1, bv1, W2, MR, DM, DM, false);

  // ---- ProbSparse: sampled scores, top-U, selected full attention ----
  k_mscore<<<dim3(ZH * Ls / 4), 256, 0, stream>>>(W0, W1, smp, Ms, U);
  k_topk<<<dim3(ZH), 256, 0, stream>>>(Ms, top, U);
  k_qkT<<<dim3(Uld / 64, Ls / 64, ZH), 256, 0, stream>>>(W0, W1, Sbuf, top, 0, U, Uld, U, 0.125f);
  k_softmax<<<dim3(ZH * Uld), 256, 0, stream>>>(Sbuf);
  k_pv<<<dim3(Uld / 64, 1, ZH), 256, 0, stream>>>(Sbuf, W2, upd, 0, U, Uld, Uld, 1);
  k_meanv<<<dim3(ZH), 256, 0, stream>>>(W2, mv);
  k_ctxfill<<<dim3(MR * DM / 4 / 256), 256, 0, stream>>>(mv, W1);   // ctx -> W1 (K1 dead)
  k_scatter<<<dim3(ZH), 256, 0, stream>>>(upd, top, W1, U, Uld);

  // ---- out-proj 1 + residual LN ----
  gemm(W1, wo1, bo1, W0, MR, DM, DM, false);                        // xn -> W0
  k_ln<<<dim3(MR), 256, 0, stream>>>(W0, tgt, g1, be1, W2);         // x1 -> W2

  // ---- layer-2 projections ----
  gemm(W2, wq2, bq2, W0, MR, DM, DM, false);                        // Q2 -> W0
  gemm(mem, wk2, bk2, W1, MR, DM, DM, false);                       // K2 -> W1
  gemm(mem, wv2, bv2, W3, MR, DM, DM, false);                       // V2 -> W3 (=d_out)

  // ---- full cross attention, chunked over q ----
  for (int q0 = 0; q0 < Ls; q0 += CQ) {
    k_qkT<<<dim3(CQ / 64, Ls / 64, ZH), 256, 0, stream>>>(W0, W1, Sbuf, nullptr, q0, CQ, CQ, U, 0.125f);
    k_softmax<<<dim3(ZH * CQ), 256, 0, stream>>>(Sbuf);
    k_pv<<<dim3(CQ / 64, 1, ZH), 256, 0, stream>>>(Sbuf, W3, W2, q0, CQ, CQ, 0, 0);  // attn -> W2
  }

  // ---- out-proj 2 + LN + FFN + final LN ----
  gemm(W2, wo2, bo2, W0, MR, DM, DM, false);                        // x2 -> W0
  k_ln<<<dim3(MR), 256, 0, stream>>>(W0, nullptr, g2, be2, W1);     // x2ln -> W1
  gemm(W1, c1w, c1b, Sbuf, MR, 4 * DM, DM, true);                   // h -> Sbuf (relu)
  gemm(Sbuf, c2w, c2b, W2, MR, DM, 4 * DM, false);                  // y2 -> W2
  k_ln<<<dim3(MR), 256, 0, stream>>>(W2, W1, g3, be3, outp);        // final -> d_out
}

// Round 2
// 1881.650 us; speedup vs baseline: 1.1668x; 1.1668x over previous
//
#include <hip/hip_runtime.h>
#include <hip/hip_bf16.h>
#include <cstdint>

constexpr int Bb  = 8;
constexpr int Ls  = 1024;
constexpr int DM  = 512;
constexpr int NH  = 8;
constexpr int DHd = 64;
constexpr int MR  = Bb * Ls;   // 8192 rows
constexpr int ZH  = Bb * NH;   // 64 (b,h) pairs
constexpr int CQ  = 128;       // q-chunk for full attention

typedef __attribute__((ext_vector_type(8))) short short8v;
typedef __attribute__((ext_vector_type(4))) short short4v;
typedef __attribute__((ext_vector_type(4))) float floatx4;

__device__ inline short f2bf(float x) {
  __hip_bfloat16 h = __float2bfloat16(x);
  return *reinterpret_cast<short*>(&h);
}

#define GLOAD_LDS16(g, l)                                                        \
  __builtin_amdgcn_global_load_lds(                                              \
      (const __attribute__((address_space(1))) void*)(g),                        \
      (__attribute__((address_space(3))) void*)(l), 16, 0, 0)

// ================= bf16 MFMA GEMM: C = act(A @ Wt^T + bias) =================
// A: MxK bf16 row-major. Wt: NxK bf16 row-major (pre-transposed weight).
// C: MxN (f32 or bf16). Tile 128x128, BK=32, 4 waves, 16x16x32 MFMA.
template<int OUT_BF16, int RELU>
__global__ __launch_bounds__(256) void k_gemm_mfma(
    const __hip_bfloat16* __restrict__ A, const __hip_bfloat16* __restrict__ Wt,
    const float* __restrict__ bias, void* __restrict__ Cout,
    int M, int N, int K)
{
  __shared__ __hip_bfloat16 As[128 * 32];
  __shared__ __hip_bfloat16 Bs[128 * 32];
  const int tid = threadIdx.x;
  const int w = tid >> 6, lane = tid & 63;
  const int wr = w >> 1, wc = w & 1;
  const int bm = blockIdx.x * 128, bn = blockIdx.y * 128;
  const int lrow = lane >> 2;            // 0..15 (staging row within chunk)
  const int lcol = (lane & 3) * 8;       // staging k-offset (elements)
  const int fr = lane & 15;              // fragment row/col
  const int fco = (lane >> 4) * 8;       // fragment k-offset (elements)
  const short* Ash = (const short*)As;
  const short* Bsh = (const short*)Bs;

  floatx4 acc[4][4] = {};
  for (int k0 = 0; k0 < K; k0 += 32) {
#pragma unroll
    for (int i = 0; i < 2; ++i) {
      const int chunk = w * 2 + i;       // 0..7, 16 rows each
      GLOAD_LDS16(A  + (size_t)(bm + chunk * 16 + lrow) * K + k0 + lcol,
                  As + chunk * 512);
      GLOAD_LDS16(Wt + (size_t)(bn + chunk * 16 + lrow) * K + k0 + lcol,
                  Bs + chunk * 512);
    }
    __syncthreads();
    short8v a[4], b[4];
#pragma unroll
    for (int mi = 0; mi < 4; ++mi)
      a[mi] = *(const short8v*)(Ash + (wr * 64 + mi * 16 + fr) * 32 + fco);
#pragma unroll
    for (int ni = 0; ni < 4; ++ni)
      b[ni] = *(const short8v*)(Bsh + (wc * 64 + ni * 16 + fr) * 32 + fco);
#pragma unroll
    for (int mi = 0; mi < 4; ++mi)
#pragma unroll
      for (int ni = 0; ni < 4; ++ni)
        acc[mi][ni] = __builtin_amdgcn_mfma_f32_16x16x32_bf16(
            a[mi], b[ni], acc[mi][ni], 0, 0, 0);
    __syncthreads();
  }
#pragma unroll
  for (int ni = 0; ni < 4; ++ni) {
    const int cn = bn + wc * 64 + ni * 16 + fr;
    const float bv = bias[cn];
#pragma unroll
    for (int mi = 0; mi < 4; ++mi) {
#pragma unroll
      for (int j = 0; j < 4; ++j) {
        const int rm = bm + wr * 64 + mi * 16 + (lane >> 4) * 4 + j;
        float v = acc[mi][ni][j] + bv;
        if (RELU) v = fmaxf(v, 0.f);
        if (OUT_BF16)
          ((__hip_bfloat16*)Cout)[(size_t)rm * N + cn] = __float2bfloat16(v);
        else
          ((float*)Cout)[(size_t)rm * N + cn] = v;
      }
    }
  }
}

// ---------------- f32 GEMM (kept for Q1/K1 selection fidelity) ----------------
template<int RELU>
__global__ __launch_bounds__(256) void k_gemm_bias(
    const float* __restrict__ A, const float* __restrict__ W,
    const float* __restrict__ bias, float* __restrict__ C,
    int M, int N, int K)
{
  constexpr int BM = 128, BN = 64, BK = 16;
  __shared__ float As[BK][BM + 4];
  __shared__ float Bs[BK][BN + 4];
  const int tid = threadIdx.x;
  const int bm = blockIdx.x * BM, bn = blockIdx.y * BN;
  const int arow = tid >> 2, acol = (tid & 3) << 2;
  const int brow = tid >> 4, bcol = (tid & 15) << 2;
  const int mB = (tid >> 4) << 3, nB = (tid & 15) << 2;
  float acc[8][4] = {};
  for (int k0 = 0; k0 < K; k0 += BK) {
#pragma unroll
    for (int i = 0; i < 2; ++i) {
      int r = arow + (i << 6);
      float4 a4 = *reinterpret_cast<const float4*>(A + (size_t)(bm + r) * K + k0 + acol);
      As[acol + 0][r] = a4.x; As[acol + 1][r] = a4.y;
      As[acol + 2][r] = a4.z; As[acol + 3][r] = a4.w;
    }
    *reinterpret_cast<float4*>(&Bs[brow][bcol]) =
        *reinterpret_cast<const float4*>(W + (size_t)(k0 + brow) * N + bn + bcol);
    __syncthreads();
#pragma unroll
    for (int kk = 0; kk < BK; ++kk) {
      float4 b4 = *reinterpret_cast<const float4*>(&Bs[kk][nB]);
      float4 a0 = *reinterpret_cast<const float4*>(&As[kk][mB]);
      float4 a1 = *reinterpret_cast<const float4*>(&As[kk][mB + 4]);
      const float av[8] = {a0.x, a0.y, a0.z, a0.w, a1.x, a1.y, a1.z, a1.w};
#pragma unroll
      for (int i = 0; i < 8; ++i) {
        acc[i][0] += av[i] * b4.x; acc[i][1] += av[i] * b4.y;
        acc[i][2] += av[i] * b4.z; acc[i][3] += av[i] * b4.w;
      }
    }
    __syncthreads();
  }
  float4 bi4 = *reinterpret_cast<const float4*>(bias + bn + nB);
#pragma unroll
  for (int i = 0; i < 8; ++i) {
    float4 o;
    o.x = acc[i][0] + bi4.x; o.y = acc[i][1] + bi4.y;
    o.z = acc[i][2] + bi4.z; o.w = acc[i][3] + bi4.w;
    if (RELU) {
      o.x = fmaxf(o.x, 0.f); o.y = fmaxf(o.y, 0.f);
      o.z = fmaxf(o.z, 0.f); o.w = fmaxf(o.w, 0.f);
    }
    *reinterpret_cast<float4*>(C + (size_t)(bm + mB + i) * N + bn + nB) = o;
  }
}

// ---------------- f32 -> bf16 elementwise ----------------
__global__ __launch_bounds__(256) void k_cvt(
    const float* __restrict__ in, __hip_bfloat16* __restrict__ out)
{
  const size_t i = ((size_t)blockIdx.x * 256 + threadIdx.x) * 4;
  float4 v = *reinterpret_cast<const float4*>(in + i);
  short4v o;
  o.x = f2bf(v.x); o.y = f2bf(v.y); o.z = f2bf(v.z); o.w = f2bf(v.w);
  *reinterpret_cast<short4v*>(out + i) = o;
}

// ---------------- weight convert+transpose: W(KxN f32) -> Wt(NxK bf16) ----------------
__global__ __launch_bounds__(256) void k_wt_cvt(
    const float* __restrict__ W, __hip_bfloat16* __restrict__ Wt, int K, int N)
{
  __shared__ float t[32][33];
  const int tid = threadIdx.x;
  const int k0 = blockIdx.x * 32, n0 = blockIdx.y * 32;
  const int r = tid >> 3, c = (tid & 7) * 4;
  float4 v = *reinterpret_cast<const float4*>(W + (size_t)(k0 + r) * N + n0 + c);
  t[r][c + 0] = v.x; t[r][c + 1] = v.y; t[r][c + 2] = v.z; t[r][c + 3] = v.w;
  __syncthreads();
  short4v o;
  o.x = f2bf(t[c + 0][r]); o.y = f2bf(t[c + 1][r]);
  o.z = f2bf(t[c + 2][r]); o.w = f2bf(t[c + 3][r]);
  *reinterpret_cast<short4v*>(Wt + (size_t)(n0 + r) * K + k0 + c) = o;
}

// ---------------- batched scores: S[z] = scale * Qrows @ K^T ----------------
__global__ __launch_bounds__(256) void k_qkT(
    const float* __restrict__ Qm, const float* __restrict__ Km,
    float* __restrict__ S, const int* __restrict__ top,
    int q0, int Mrows, int Mld, int topStride, float scale)
{
  __shared__ float Qs[DHd][64 + 4];
  __shared__ float Ks[DHd][64 + 4];
  const int tid = threadIdx.x;
  const int z = blockIdx.z, b = z >> 3, h = z & 7;
  const int m0 = blockIdx.x << 6, n0 = blockIdx.y << 6;
  const float* Kbase = Km + ((size_t)(b * Ls + n0)) * DM + h * DHd;
#pragma unroll
  for (int i = 0; i < 4; ++i) {
    int idx = tid + (i << 8);
    int r = idx >> 4, c4 = (idx & 15) << 2;
    int qr;
    if (top) { int u = m0 + r; if (u >= Mrows) u = Mrows - 1; qr = top[z * topStride + u]; }
    else qr = q0 + m0 + r;
    float4 q4 = *reinterpret_cast<const float4*>(Qm + ((size_t)(b * Ls + qr)) * DM + h * DHd + c4);
    Qs[c4 + 0][r] = q4.x; Qs[c4 + 1][r] = q4.y; Qs[c4 + 2][r] = q4.z; Qs[c4 + 3][r] = q4.w;
    float4 k4 = *reinterpret_cast<const float4*>(Kbase + (size_t)r * DM + c4);
    Ks[c4 + 0][r] = k4.x; Ks[c4 + 1][r] = k4.y; Ks[c4 + 2][r] = k4.z; Ks[c4 + 3][r] = k4.w;
  }
  __syncthreads();
  const int mB = (tid >> 4) << 2, nB = (tid & 15) << 2;
  float acc[4][4] = {};
#pragma unroll
  for (int kk = 0; kk < DHd; ++kk) {
    float4 a4 = *reinterpret_cast<const float4*>(&Qs[kk][mB]);
    float4 b4 = *reinterpret_cast<const float4*>(&Ks[kk][nB]);
    const float av[4] = {a4.x, a4.y, a4.z, a4.w};
#pragma unroll
    for (int i = 0; i < 4; ++i) {
      acc[i][0] += av[i] * b4.x; acc[i][1] += av[i] * b4.y;
      acc[i][2] += av[i] * b4.z; acc[i][3] += av[i] * b4.w;
    }
  }
#pragma unroll
  for (int i = 0; i < 4; ++i) {
    int m = m0 + mB + i;
    if (m < Mrows) {
      float4 o;
      o.x = acc[i][0] * scale; o.y = acc[i][1] * scale;
      o.z = acc[i][2] * scale; o.w = acc[i][3] * scale;
      *reinterpret_cast<float4*>(S + ((size_t)z * Mld + m) * Ls + n0 + nB) = o;
    }
  }
}

// ---------------- row softmax over length 1024 (in place) ----------------
__global__ __launch_bounds__(256) void k_softmax(float* __restrict__ S)
{
  __shared__ float red[4];
  const int row = blockIdx.x, tid = threadIdx.x;
  float* p = S + (size_t)row * Ls;
  float4 v = *reinterpret_cast<float4*>(p + (tid << 2));
  float mx = fmaxf(fmaxf(v.x, v.y), fmaxf(v.z, v.w));
#pragma unroll
  for (int off = 32; off; off >>= 1) mx = fmaxf(mx, __shfl_xor(mx, off));
  if ((tid & 63) == 0) red[tid >> 6] = mx;
  __syncthreads();
  mx = fmaxf(fmaxf(red[0], red[1]), fmaxf(red[2], red[3]));
  __syncthreads();
  v.x = __expf(v.x - mx); v.y = __expf(v.y - mx);
  v.z = __expf(v.z - mx); v.w = __expf(v.w - mx);
  float s = v.x + v.y + v.z + v.w;
#pragma unroll
  for (int off = 32; off; off >>= 1) s += __shfl_xor(s, off);
  if ((tid & 63) == 0) red[tid >> 6] = s;
  __syncthreads();
  s = red[0] + red[1] + red[2] + red[3];
  float inv = 1.0f / s;
  v.x *= inv; v.y *= inv; v.z *= inv; v.w *= inv;
  *reinterpret_cast<float4*>(p + (tid << 2)) = v;
}

// ---------------- PV: Out = P @ V (batched over z) ----------------
__global__ __launch_bounds__(256) void k_pv(
    const float* __restrict__ S, const float* __restrict__ Vm,
    float* __restrict__ Out, int q0, int Mrows, int Mld, int outStride, int probMode)
{
  __shared__ float Ps[16][64 + 4];
  __shared__ float Vs[16][64 + 4];
  const int tid = threadIdx.x;
  const int z = blockIdx.z, b = z >> 3, h = z & 7;
  const int m0 = blockIdx.x << 6;
  const int pr = tid >> 2, pc = (tid & 3) << 2;
  const int vr = tid >> 4, vc = (tid & 15) << 2;
  const int mB = (tid >> 4) << 2, nB = (tid & 15) << 2;
  float acc[4][4] = {};
  for (int k0 = 0; k0 < Ls; k0 += 16) {
    float4 p4 = *reinterpret_cast<const float4*>(S + ((size_t)z * Mld + m0 + pr) * Ls + k0 + pc);
    Ps[pc + 0][pr] = p4.x; Ps[pc + 1][pr] = p4.y; Ps[pc + 2][pr] = p4.z; Ps[pc + 3][pr] = p4.w;
    *reinterpret_cast<float4*>(&Vs[vr][vc]) =
        *reinterpret_cast<const float4*>(Vm + ((size_t)(b * Ls + k0 + vr)) * DM + h * DHd + vc);
    __syncthreads();
#pragma unroll
    for (int kk = 0; kk < 16; ++kk) {
      float4 a4 = *reinterpret_cast<const float4*>(&Ps[kk][mB]);
      float4 b4 = *reinterpret_cast<const float4*>(&Vs[kk][nB]);
      const float av[4] = {a4.x, a4.y, a4.z, a4.w};
#pragma unroll
      for (int i = 0; i < 4; ++i) {
        acc[i][0] += av[i] * b4.x; acc[i][1] += av[i] * b4.y;
        acc[i][2] += av[i] * b4.z; acc[i][3] += av[i] * b4.w;
      }
    }
    __syncthreads();
  }
#pragma unroll
  for (int i = 0; i < 4; ++i) {
    int m = m0 + mB + i;
    if (m < Mrows) {
      float4 o; o.x = acc[i][0]; o.y = acc[i][1]; o.z = acc[i][2]; o.w = acc[i][3];
      if (probMode)
        *reinterpret_cast<float4*>(Out + ((size_t)z * outStride + m) * DHd + nB) = o;
      else
        *reinterpret_cast<float4*>(Out + ((size_t)(b * Ls + q0 + m)) * DM + h * DHd + nB) = o;
    }
  }
}

// ---------------- ProbSparse sampled scores ----------------
__global__ __launch_bounds__(256) void k_mscore(
    const float* __restrict__ Qm, const float* __restrict__ Km,
    const int* __restrict__ smp, float* __restrict__ Ms, int U)
{
  const int gw = blockIdx.x * 4 + (threadIdx.x >> 6);
  const int lane = threadIdx.x & 63;
  const int l = gw & (Ls - 1);
  const int z = gw >> 10, b = z >> 3, h = z & 7;
  const float q = Qm[((size_t)(b * Ls + l)) * DM + h * DHd + lane];
  float mx = -1e30f, sm = 0.f;
  for (int u = 0; u < U; ++u) {
    int ki = smp[l * U + u];
    float p = q * Km[((size_t)(b * Ls + ki)) * DM + h * DHd + lane];
#pragma unroll
    for (int off = 32; off; off >>= 1) p += __shfl_xor(p, off);
    mx = fmaxf(mx, p); sm += p;
  }
  if (lane == 0) Ms[z * Ls + l] = mx - sm * (1.0f / Ls);
}

// ---------------- iterative top-U ----------------
__global__ __launch_bounds__(256) void k_topk(
    const float* __restrict__ Ms, int* __restrict__ top, int U)
{
  __shared__ float v[Ls];
  __shared__ float rv[256];
  __shared__ int   ri[256];
  const int z = blockIdx.x, tid = threadIdx.x;
  for (int i = tid; i < Ls; i += 256) v[i] = Ms[z * Ls + i];
  __syncthreads();
  for (int it = 0; it < U; ++it) {
    float bv = -1e30f; int bi = 0x7fffffff;
    for (int i = tid; i < Ls; i += 256) {
      float x = v[i];
      if (x > bv || (x == bv && i < bi)) { bv = x; bi = i; }
    }
    rv[tid] = bv; ri[tid] = bi;
    __syncthreads();
    for (int s = 128; s; s >>= 1) {
      if (tid < s) {
        float xv = rv[tid + s]; int xi = ri[tid + s];
        if (xv > rv[tid] || (xv == rv[tid] && xi < ri[tid])) { rv[tid] = xv; ri[tid] = xi; }
      }
      __syncthreads();
    }
    if (tid == 0) { top[z * U + it] = ri[0]; v[ri[0]] = -1e30f; }
    __syncthreads();
  }
}

// ---------------- mean of V over keys ----------------
__global__ __launch_bounds__(256) void k_meanv(
    const float* __restrict__ Vm, float* __restrict__ mv)
{
  __shared__ float ps[4][64];
  const int z = blockIdx.x, b = z >> 3, h = z & 7;
  const int d = threadIdx.x & 63, g = threadIdx.x >> 6;
  float s = 0.f;
  for (int k = g * 256; k < (g + 1) * 256; ++k)
    s += Vm[((size_t)(b * Ls + k)) * DM + h * DHd + d];
  ps[g][d] = s;
  __syncthreads();
  if (g == 0) mv[z * 64 + d] = (ps[0][d] + ps[1][d] + ps[2][d] + ps[3][d]) * (1.0f / Ls);
}

// ---------------- broadcast mean-V ----------------
__global__ __launch_bounds__(256) void k_ctxfill(
    const float* __restrict__ mv, float* __restrict__ ctx)
{
  const int i = blockIdx.x * 256 + threadIdx.x;
  const int c4 = (i & 127) << 2;
  const int row = i >> 7;
  const int b = row >> 10;
  const int h = c4 >> 6;
  float4 m4 = *reinterpret_cast<const float4*>(mv + ((b * 8 + h) * 64) + (c4 & 63));
  *reinterpret_cast<float4*>(ctx + (size_t)row * DM + c4) = m4;
}

// ---------------- scatter upd rows ----------------
__global__ __launch_bounds__(256) void k_scatter(
    const float* __restrict__ upd, const int* __restrict__ top,
    float* __restrict__ ctx, int U, int Uld)
{
  const int z = blockIdx.x, b = z >> 3, h = z & 7;
  const int d = threadIdx.x & 63;
  for (int u = threadIdx.x >> 6; u < U; u += 4) {
    int row = top[z * U + u];
    ctx[((size_t)(b * Ls + row)) * DM + h * DHd + d] =
        upd[((size_t)z * Uld + u) * DHd + d];
  }
}

// ---------------- fused (residual +) LayerNorm; optional f32 + bf16 outputs ----------------
__global__ __launch_bounds__(256) void k_ln(
    const float* __restrict__ x, const float* __restrict__ res,
    const float* __restrict__ g, const float* __restrict__ be,
    float* __restrict__ outf, __hip_bfloat16* __restrict__ outb)
{
  __shared__ float red[4];
  const int row = blockIdx.x, tid = threadIdx.x;
  const size_t base = (size_t)row * DM;
  float2 v = *reinterpret_cast<const float2*>(x + base + tid * 2);
  if (res) {
    float2 r2 = *reinterpret_cast<const float2*>(res + base + tid * 2);
    v.x += r2.x; v.y += r2.y;
  }
  float s = v.x + v.y;
#pragma unroll
  for (int off = 32; off; off >>= 1) s += __shfl_xor(s, off);
  if ((tid & 63) == 0) red[tid >> 6] = s;
  __syncthreads();
  s = red[0] + red[1] + red[2] + red[3];
  const float mean = s * (1.0f / DM);
  __syncthreads();
  float dx = v.x - mean, dy = v.y - mean;
  float q = dx * dx + dy * dy;
#pragma unroll
  for (int off = 32; off; off >>= 1) q += __shfl_xor(q, off);
  if ((tid & 63) == 0) red[tid >> 6] = q;
  __syncthreads();
  q = red[0] + red[1] + red[2] + red[3];
  const float inv = rsqrtf(q * (1.0f / DM) + 1e-5f);
  float2 gg = *reinterpret_cast<const float2*>(g + tid * 2);
  float2 bb = *reinterpret_cast<const float2*>(be + tid * 2);
  float ox = dx * inv * gg.x + bb.x;
  float oy = dy * inv * gg.y + bb.y;
  if (outf) {
    float2 o; o.x = ox; o.y = oy;
    *reinterpret_cast<float2*>(outf + base + tid * 2) = o;
  }
  if (outb) {
    short2 ob; ob.x = f2bf(ox); ob.y = f2bf(oy);
    *reinterpret_cast<short2*>(outb + base + tid * 2) = ob;
  }
}

extern "C" void kernel_launch(void* const* d_in, const int* in_sizes, int n_in,
                              void* d_out, int out_size, void* d_ws, size_t ws_size,
                              hipStream_t stream)
{
  const float* tgt = (const float*)d_in[0];
  const float* mem = (const float*)d_in[1];
  const int*   smp = (const int*)d_in[2];
  const float* wq1 = (const float*)d_in[3];  const float* bq1 = (const float*)d_in[4];
  const float* wk1 = (const float*)d_in[5];  const float* bk1 = (const float*)d_in[6];
  const float* wv1 = (const float*)d_in[7];  const float* bv1 = (const float*)d_in[8];
  const float* wo1 = (const float*)d_in[9];  const float* bo1 = (const float*)d_in[10];
  const float* wq2 = (const float*)d_in[11]; const float* bq2 = (const float*)d_in[12];
  const float* wk2 = (const float*)d_in[13]; const float* bk2 = (const float*)d_in[14];
  const float* wv2 = (const float*)d_in[15]; const float* bv2 = (const float*)d_in[16];
  const float* wo2 = (const float*)d_in[17]; const float* bo2 = (const float*)d_in[18];
  const float* c1w = (const float*)d_in[19]; const float* c1b = (const float*)d_in[20];
  const float* c2w = (const float*)d_in[21]; const float* c2b = (const float*)d_in[22];
  const float* g1  = (const float*)d_in[23]; const float* be1 = (const float*)d_in[24];
  const float* g2  = (const float*)d_in[25]; const float* be2 = (const float*)d_in[26];
  const float* g3  = (const float*)d_in[27]; const float* be3 = (const float*)d_in[28];
  float* outp = (float*)d_out;

  const int U   = in_sizes[2] / Ls;            // 35
  const int Uld = ((U + 63) / 64) * 64;        // 64

  char* ws = (char*)d_ws;
  const size_t SZ = (size_t)MR * DM * sizeof(float);       // 16.78 MB
  float* W0   = (float*)(ws);
  float* W1   = (float*)(ws + SZ);
  float* W2   = (float*)(ws + 2 * SZ);
  float* Sbuf = (float*)(ws + 3 * SZ);                     // 2*SZ: ZH*CQ*Ls f32 (also hb bf16)
  __hip_bfloat16* Tb = (__hip_bfloat16*)(ws + 5 * SZ);                 // SZ/2
  __hip_bfloat16* Mb = (__hip_bfloat16*)(ws + 5 * SZ + SZ / 2);        // SZ/2
  __hip_bfloat16* Xb = (__hip_bfloat16*)(ws + 6 * SZ);                 // SZ/2
  char* tail = ws + 6 * SZ + SZ / 2;
  __hip_bfloat16* wv1b = (__hip_bfloat16*)tail; tail += DM * DM * 2;
  __hip_bfloat16* wo1b = (__hip_bfloat16*)tail; tail += DM * DM * 2;
  __hip_bfloat16* wq2b = (__hip_bfloat16*)tail; tail += DM * DM * 2;
  __hip_bfloat16* wk2b = (__hip_bfloat16*)tail; tail += DM * DM * 2;
  __hip_bfloat16* wv2b = (__hip_bfloat16*)tail; tail += DM * DM * 2;
  __hip_bfloat16* wo2b = (__hip_bfloat16*)tail; tail += DM * DM * 2;
  __hip_bfloat16* c1wb = (__hip_bfloat16*)tail; tail += DM * 4 * DM * 2;
  __hip_bfloat16* c2wb = (__hip_bfloat16*)tail; tail += DM * 4 * DM * 2;
  float* Ms  = (float*)tail; tail += (size_t)ZH * Ls * 4;
  int*   top = (int*)tail;   tail += (size_t)ZH * Uld * 4;
  float* mv  = (float*)tail; tail += (size_t)ZH * DHd * 4;
  float* upd = (float*)tail; tail += (size_t)ZH * Uld * DHd * 4;
  float* W3  = outp;  // V2 parked in d_out (dead before final LN writes it)
  __hip_bfloat16* hb = (__hip_bfloat16*)Sbuf;

  auto gemmF = [&](const float* A, const float* Wm, const float* bi, float* C,
                   int M, int N, int K) {
    dim3 g(M / 128, N / 64);
    k_gemm_bias<0><<<g, 256, 0, stream>>>(A, Wm, bi, C, M, N, K);
  };
  auto gemmB = [&](const __hip_bfloat16* A, const __hip_bfloat16* Wt, const float* bi,
                   void* C, int M, int N, int K, bool relu, bool outbf) {
    dim3 g(M / 128, N / 128);
    if (relu) {
      if (outbf) k_gemm_mfma<1, 1><<<g, 256, 0, stream>>>(A, Wt, bi, C, M, N, K);
      else       k_gemm_mfma<0, 1><<<g, 256, 0, stream>>>(A, Wt, bi, C, M, N, K);
    } else {
      if (outbf) k_gemm_mfma<1, 0><<<g, 256, 0, stream>>>(A, Wt, bi, C, M, N, K);
      else       k_gemm_mfma<0, 0><<<g, 256, 0, stream>>>(A, Wt, bi, C, M, N, K);
    }
  };
  auto wcvt = [&](const float* Wm, __hip_bfloat16* Wt, int K, int N) {
    k_wt_cvt<<<dim3(K / 32, N / 32), 256, 0, stream>>>(Wm, Wt, K, N);
  };

  // ---- one-time converts ----
  k_cvt<<<dim3(MR * DM / 4 / 256), 256, 0, stream>>>(tgt, Tb);
  k_cvt<<<dim3(MR * DM / 4 / 256), 256, 0, stream>>>(mem, Mb);
  wcvt(wv1, wv1b, DM, DM); wcvt(wo1, wo1b, DM, DM);
  wcvt(wq2, wq2b, DM, DM); wcvt(wk2, wk2b, DM, DM);
  wcvt(wv2, wv2b, DM, DM); wcvt(wo2, wo2b, DM, DM);
  wcvt(c1w, c1wb, DM, 4 * DM); wcvt(c2w, c2wb, 4 * DM, DM);

  // ---- layer-1 projections: Q1,K1 in f32 (top-k fidelity), V1 bf16 MFMA ----
  gemmF(tgt, wq1, bq1, W0, MR, DM, DM);
  gemmF(tgt, wk1, bk1, W1, MR, DM, DM);
  gemmB(Tb, wv1b, bv1, W2, MR, DM, DM, false, false);

  // ---- ProbSparse ----
  k_mscore<<<dim3(ZH * Ls / 4), 256, 0, stream>>>(W0, W1, smp, Ms, U);
  k_topk<<<dim3(ZH), 256, 0, stream>>>(Ms, top, U);
  k_qkT<<<dim3(Uld / 64, Ls / 64, ZH), 256, 0, stream>>>(W0, W1, Sbuf, top, 0, U, Uld, U, 0.125f);
  k_softmax<<<dim3(ZH * Uld), 256, 0, stream>>>(Sbuf);
  k_pv<<<dim3(Uld / 64, 1, ZH), 256, 0, stream>>>(Sbuf, W2, upd, 0, U, Uld, Uld, 1);
  k_meanv<<<dim3(ZH), 256, 0, stream>>>(W2, mv);
  k_ctxfill<<<dim3(MR * DM / 4 / 256), 256, 0, stream>>>(mv, W1);   // ctx -> W1
  k_scatter<<<dim3(ZH), 256, 0, stream>>>(upd, top, W1, U, Uld);

  // ---- out-proj 1 + residual LN ----
  k_cvt<<<dim3(MR * DM / 4 / 256), 256, 0, stream>>>(W1, Xb);       // ctx -> bf16
  gemmB(Xb, wo1b, bo1, W0, MR, DM, DM, false, false);               // xn -> W0
  k_ln<<<dim3(MR), 256, 0, stream>>>(W0, tgt, g1, be1, nullptr, Xb); // x1 -> Xb (bf16 only)

  // ---- layer-2 projections ----
  gemmB(Xb, wq2b, bq2, W0, MR, DM, DM, false, false);               // Q2 -> W0 f32
  gemmB(Mb, wk2b, bk2, W1, MR, DM, DM, false, false);               // K2 -> W1 f32
  gemmB(Mb, wv2b, bv2, W3, MR, DM, DM, false, false);               // V2 -> W3(=d_out) f32

  // ---- full cross attention, chunked over q ----
  for (int q0 = 0; q0 < Ls; q0 += CQ) {
    k_qkT<<<dim3(CQ / 64, Ls / 64, ZH), 256, 0, stream>>>(W0, W1, Sbuf, nullptr, q0, CQ, CQ, U, 0.125f);
    k_softmax<<<dim3(ZH * CQ), 256, 0, stream>>>(Sbuf);
    k_pv<<<dim3(CQ / 64, 1, ZH), 256, 0, stream>>>(Sbuf, W3, W2, q0, CQ, CQ, 0, 0);  // attn -> W2
  }

  // ---- out-proj 2 + LN + FFN + final LN ----
  k_cvt<<<dim3(MR * DM / 4 / 256), 256, 0, stream>>>(W2, Xb);       // attn -> bf16
  gemmB(Xb, wo2b, bo2, W0, MR, DM, DM, false, false);               // x2 -> W0
  k_ln<<<dim3(MR), 256, 0, stream>>>(W0, nullptr, g2, be2, W1, Xb); // x2ln -> W1 (f32) + Xb (bf16)
  gemmB(Xb, c1wb, c1b, hb, MR, 4 * DM, DM, true, true);             // h -> hb (bf16, relu)
  gemmB(hb, c2wb, c2b, W2, MR, DM, 4 * DM, false, false);           // y2 -> W2
  k_ln<<<dim3(MR), 256, 0, stream>>>(W2, W1, g3, be3, outp, nullptr); // final -> d_out
}

// Round 3
// 663.072 us; speedup vs baseline: 3.3112x; 2.8378x over previous
//
#include <hip/hip_runtime.h>
#include <hip/hip_bf16.h>
#include <cstdint>

constexpr int Bb  = 8;
constexpr int Ls  = 1024;
constexpr int DM  = 512;
constexpr int NH  = 8;
constexpr int DHd = 64;
constexpr int MR  = Bb * Ls;   // 8192 rows
constexpr int ZH  = Bb * NH;   // 64 (b,h) pairs

typedef __attribute__((ext_vector_type(8))) short short8v;
typedef __attribute__((ext_vector_type(4))) short short4v;
typedef __attribute__((ext_vector_type(4))) float floatx4;

__device__ inline short f2bf(float x) {
  __hip_bfloat16 h = __float2bfloat16(x);
  return *reinterpret_cast<short*>(&h);
}

#define GLOAD_LDS16(g, l)                                                        \
  __builtin_amdgcn_global_load_lds(                                              \
      (const __attribute__((address_space(1))) void*)(g),                        \
      (__attribute__((address_space(3))) void*)(l), 16, 0, 0)

// ================= bf16 MFMA GEMM: C = act(A @ Wt^T + bias) =================
// A: MxK bf16 row-major. Wt: NxK bf16 row-major (pre-transposed weight).
// MODE: 0 = f32 out, 1 = bf16 out, 2 = bf16 out with per-row d-slot XOR swizzle
// (for flash K staging), 3 = bf16 transposed-per-head + key-slot swizzle
// (for flash V staging; assumes N==512, rows = b*1024+l).
template<int MODE, int RELU>
__global__ __launch_bounds__(256) void k_gemm_mfma(
    const __hip_bfloat16* __restrict__ A, const __hip_bfloat16* __restrict__ Wt,
    const float* __restrict__ bias, void* __restrict__ Cout,
    int M, int N, int K)
{
  __shared__ __hip_bfloat16 As[128 * 32];
  __shared__ __hip_bfloat16 Bs[128 * 32];
  const int tid = threadIdx.x;
  const int w = tid >> 6, lane = tid & 63;
  const int wr = w >> 1, wc = w & 1;
  const int bm = blockIdx.x * 128, bn = blockIdx.y * 128;
  const int lrow = lane >> 2;
  const int lcol = (lane & 3) * 8;
  const int fr = lane & 15;
  const int fco = (lane >> 4) * 8;
  const short* Ash = (const short*)As;
  const short* Bsh = (const short*)Bs;

  floatx4 acc[4][4] = {};
  for (int k0 = 0; k0 < K; k0 += 32) {
#pragma unroll
    for (int i = 0; i < 2; ++i) {
      const int chunk = w * 2 + i;
      GLOAD_LDS16(A  + (size_t)(bm + chunk * 16 + lrow) * K + k0 + lcol,
                  As + chunk * 512);
      GLOAD_LDS16(Wt + (size_t)(bn + chunk * 16 + lrow) * K + k0 + lcol,
                  Bs + chunk * 512);
    }
    __syncthreads();
    short8v a[4], b[4];
#pragma unroll
    for (int mi = 0; mi < 4; ++mi)
      a[mi] = *(const short8v*)(Ash + (wr * 64 + mi * 16 + fr) * 32 + fco);
#pragma unroll
    for (int ni = 0; ni < 4; ++ni)
      b[ni] = *(const short8v*)(Bsh + (wc * 64 + ni * 16 + fr) * 32 + fco);
#pragma unroll
    for (int mi = 0; mi < 4; ++mi)
#pragma unroll
      for (int ni = 0; ni < 4; ++ni)
        acc[mi][ni] = __builtin_amdgcn_mfma_f32_16x16x32_bf16(
            a[mi], b[ni], acc[mi][ni], 0, 0, 0);
    __syncthreads();
  }
#pragma unroll
  for (int ni = 0; ni < 4; ++ni) {
    const int cn = bn + wc * 64 + ni * 16 + fr;
    const float bv = bias[cn];
#pragma unroll
    for (int mi = 0; mi < 4; ++mi) {
#pragma unroll
      for (int j = 0; j < 4; ++j) {
        const int rm = bm + wr * 64 + mi * 16 + (lane >> 4) * 4 + j;
        float v = acc[mi][ni][j] + bv;
        if (RELU) v = fmaxf(v, 0.f);
        if (MODE == 0) {
          ((float*)Cout)[(size_t)rm * N + cn] = v;
        } else if (MODE == 1) {
          ((__hip_bfloat16*)Cout)[(size_t)rm * N + cn] = __float2bfloat16(v);
        } else if (MODE == 2) {
          const int cs = (cn & ~63) | ((cn & 63) ^ ((rm & 7) << 3));
          ((__hip_bfloat16*)Cout)[(size_t)rm * N + cs] = __float2bfloat16(v);
        } else {
          const int bb = rm >> 10, l = rm & 1023, hh = cn >> 6, dd = cn & 63;
          ((__hip_bfloat16*)Cout)[(size_t)((bb * 8 + hh) * 64 + dd) * 1024 +
                                  (l ^ ((dd & 7) << 3))] = __float2bfloat16(v);
        }
      }
    }
  }
}

// ---------------- f32 GEMM (Q1/K1 selection fidelity) ----------------
template<int RELU>
__global__ __launch_bounds__(256) void k_gemm_bias(
    const float* __restrict__ A, const float* __restrict__ W,
    const float* __restrict__ bias, float* __restrict__ C,
    int M, int N, int K)
{
  constexpr int BM = 128, BN = 64, BK = 16;
  __shared__ float As[BK][BM + 4];
  __shared__ float Bs[BK][BN + 4];
  const int tid = threadIdx.x;
  const int bm = blockIdx.x * BM, bn = blockIdx.y * BN;
  const int arow = tid >> 2, acol = (tid & 3) << 2;
  const int brow = tid >> 4, bcol = (tid & 15) << 2;
  const int mB = (tid >> 4) << 3, nB = (tid & 15) << 2;
  float acc[8][4] = {};
  for (int k0 = 0; k0 < K; k0 += BK) {
#pragma unroll
    for (int i = 0; i < 2; ++i) {
      int r = arow + (i << 6);
      float4 a4 = *reinterpret_cast<const float4*>(A + (size_t)(bm + r) * K + k0 + acol);
      As[acol + 0][r] = a4.x; As[acol + 1][r] = a4.y;
      As[acol + 2][r] = a4.z; As[acol + 3][r] = a4.w;
    }
    *reinterpret_cast<float4*>(&Bs[brow][bcol]) =
        *reinterpret_cast<const float4*>(W + (size_t)(k0 + brow) * N + bn + bcol);
    __syncthreads();
#pragma unroll
    for (int kk = 0; kk < BK; ++kk) {
      float4 b4 = *reinterpret_cast<const float4*>(&Bs[kk][nB]);
      float4 a0 = *reinterpret_cast<const float4*>(&As[kk][mB]);
      float4 a1 = *reinterpret_cast<const float4*>(&As[kk][mB + 4]);
      const float av[8] = {a0.x, a0.y, a0.z, a0.w, a1.x, a1.y, a1.z, a1.w};
#pragma unroll
      for (int i = 0; i < 8; ++i) {
        acc[i][0] += av[i] * b4.x; acc[i][1] += av[i] * b4.y;
        acc[i][2] += av[i] * b4.z; acc[i][3] += av[i] * b4.w;
      }
    }
    __syncthreads();
  }
  float4 bi4 = *reinterpret_cast<const float4*>(bias + bn + nB);
#pragma unroll
  for (int i = 0; i < 8; ++i) {
    float4 o;
    o.x = acc[i][0] + bi4.x; o.y = acc[i][1] + bi4.y;
    o.z = acc[i][2] + bi4.z; o.w = acc[i][3] + bi4.w;
    if (RELU) {
      o.x = fmaxf(o.x, 0.f); o.y = fmaxf(o.y, 0.f);
      o.z = fmaxf(o.z, 0.f); o.w = fmaxf(o.w, 0.f);
    }
    *reinterpret_cast<float4*>(C + (size_t)(bm + mB + i) * N + bn + nB) = o;
  }
}

// ================= fused flash cross-attention (bf16 MFMA) =================
// Qb: merged (MR x 512) bf16, plain. Kb: merged bf16, d-slots XOR-swizzled per
// row (slot s holds orig slot s^(row&7)). Vt: [z][64d][1024k] bf16, key-slots
// XOR-swizzled per d-row. O: merged bf16.
__global__ __launch_bounds__(256) void k_flash(
    const __hip_bfloat16* __restrict__ Qb,
    const __hip_bfloat16* __restrict__ Kb,
    const __hip_bfloat16* __restrict__ Vt,
    __hip_bfloat16* __restrict__ O)
{
  __shared__ __hip_bfloat16 Ks[64 * 64];
  __shared__ __hip_bfloat16 Vs[64 * 64];
  __shared__ __hip_bfloat16 Ps[4 * 16 * 72];
  const int tid = threadIdx.x, w = tid >> 6, lane = tid & 63;
  const int g = lane >> 4, r = lane & 15;
  const int z = blockIdx.y, b = z >> 3, h = z & 7;
  const int q0 = blockIdx.x * 64 + w * 16;
  __hip_bfloat16* Pw = Ps + w * 16 * 72;

  const short8v qf0 = *(const short8v*)(Qb + (size_t)(b * Ls + q0 + r) * DM + h * DHd + g * 8);
  const short8v qf1 = *(const short8v*)(Qb + (size_t)(b * Ls + q0 + r) * DM + h * DHd + 32 + g * 8);

  floatx4 oacc[4] = {};
  float m_run = -1e30f, l_run = 0.f;

  for (int t = 0; t < 16; ++t) {
    __syncthreads();
#pragma unroll
    for (int i = 0; i < 2; ++i) {
      const int sbase = (i * 4 + w) * 64;
      const int rowi = (sbase + lane) >> 3, ds = lane & 7;
      GLOAD_LDS16(Kb + (size_t)(b * Ls + t * 64 + rowi) * DM + h * DHd + ds * 8,
                  Ks + sbase * 8);
      GLOAD_LDS16(Vt + ((size_t)z * DHd + rowi) * Ls + t * 64 + ds * 8,
                  Vs + sbase * 8);
    }
    __syncthreads();
    // S^T tile: D = K(16x32) @ Q^T(32x16), 4 key-subtiles x 2 k-steps
    float sv[4][4];
    float tmax = -1e30f;
#pragma unroll
    for (int kt = 0; kt < 4; ++kt) {
      const int key = kt * 16 + r, sw = key & 7;
      short8v a0 = *(const short8v*)(Ks + key * 64 + ((g ^ sw) * 8));
      short8v a1 = *(const short8v*)(Ks + key * 64 + (((4 + g) ^ sw) * 8));
      floatx4 c = {};
      c = __builtin_amdgcn_mfma_f32_16x16x32_bf16(a0, qf0, c, 0, 0, 0);
      c = __builtin_amdgcn_mfma_f32_16x16x32_bf16(a1, qf1, c, 0, 0, 0);
#pragma unroll
      for (int j = 0; j < 4; ++j) {
        float x = c[j] * 0.125f;
        sv[kt][j] = x;
        tmax = fmaxf(tmax, x);
      }
    }
    tmax = fmaxf(tmax, __shfl_xor(tmax, 16));
    tmax = fmaxf(tmax, __shfl_xor(tmax, 32));
    const float m_new = fmaxf(m_run, tmax);
    const float fac = __expf(m_run - m_new);
    float psum = 0.f;
#pragma unroll
    for (int kt = 0; kt < 4; ++kt) {
      short4v pk;
#pragma unroll
      for (int j = 0; j < 4; ++j) {
        float p = __expf(sv[kt][j] - m_new);
        psum += p;
        pk[j] = f2bf(p);
      }
      *(short4v*)(Pw + r * 72 + kt * 16 + g * 4) = pk;   // P[q=r][key quad]
    }
    psum += __shfl_xor(psum, 16);
    psum += __shfl_xor(psum, 32);
    l_run = l_run * fac + psum;
    m_run = m_new;
    float fj[4];
#pragma unroll
    for (int j = 0; j < 4; ++j) fj[j] = __shfl(fac, (lane & 48) | (g * 4 + j));
#pragma unroll
    for (int ct = 0; ct < 4; ++ct)
#pragma unroll
      for (int j = 0; j < 4; ++j) oacc[ct][j] *= fj[j];
    // PV: O(16q x 64d) += P(16x64) @ V(64x64)
    const short8v pa0 = *(const short8v*)(Pw + r * 72 + g * 8);
    const short8v pa1 = *(const short8v*)(Pw + r * 72 + 32 + g * 8);
#pragma unroll
    for (int ct = 0; ct < 4; ++ct) {
      const int d = ct * 16 + r, sw = d & 7;
      short8v v0 = *(const short8v*)(Vs + d * 64 + ((g ^ sw) * 8));
      short8v v1 = *(const short8v*)(Vs + d * 64 + (((4 + g) ^ sw) * 8));
      oacc[ct] = __builtin_amdgcn_mfma_f32_16x16x32_bf16(pa0, v0, oacc[ct], 0, 0, 0);
      oacc[ct] = __builtin_amdgcn_mfma_f32_16x16x32_bf16(pa1, v1, oacc[ct], 0, 0, 0);
    }
  }
  float li[4];
#pragma unroll
  for (int j = 0; j < 4; ++j)
    li[j] = 1.0f / __shfl(l_run, (lane & 48) | (g * 4 + j));
#pragma unroll
  for (int ct = 0; ct < 4; ++ct)
#pragma unroll
    for (int j = 0; j < 4; ++j)
      O[(size_t)(b * Ls + q0 + g * 4 + j) * DM + h * DHd + ct * 16 + r] =
          __float2bfloat16(oacc[ct][j] * li[j]);
}

// ---------------- f32 -> bf16 elementwise ----------------
__global__ __launch_bounds__(256) void k_cvt(
    const float* __restrict__ in, __hip_bfloat16* __restrict__ out)
{
  const size_t i = ((size_t)blockIdx.x * 256 + threadIdx.x) * 4;
  float4 v = *reinterpret_cast<const float4*>(in + i);
  short4v o;
  o.x = f2bf(v.x); o.y = f2bf(v.y); o.z = f2bf(v.z); o.w = f2bf(v.w);
  *reinterpret_cast<short4v*>(out + i) = o;
}

// ---------------- weight convert+transpose: W(KxN f32) -> Wt(NxK bf16) ----------------
__global__ __launch_bounds__(256) void k_wt_cvt(
    const float* __restrict__ W, __hip_bfloat16* __restrict__ Wt, int K, int N)
{
  __shared__ float t[32][33];
  const int tid = threadIdx.x;
  const int k0 = blockIdx.x * 32, n0 = blockIdx.y * 32;
  const int r = tid >> 3, c = (tid & 7) * 4;
  float4 v = *reinterpret_cast<const float4*>(W + (size_t)(k0 + r) * N + n0 + c);
  t[r][c + 0] = v.x; t[r][c + 1] = v.y; t[r][c + 2] = v.z; t[r][c + 3] = v.w;
  __syncthreads();
  short4v o;
  o.x = f2bf(t[c + 0][r]); o.y = f2bf(t[c + 1][r]);
  o.z = f2bf(t[c + 2][r]); o.w = f2bf(t[c + 3][r]);
  *reinterpret_cast<short4v*>(Wt + (size_t)(n0 + r) * K + k0 + c) = o;
}

// ---------------- prob-path batched scores: S[z] = scale * Qrows @ K^T ----------------
__global__ __launch_bounds__(256) void k_qkT(
    const float* __restrict__ Qm, const float* __restrict__ Km,
    float* __restrict__ S, const int* __restrict__ top,
    int q0, int Mrows, int Mld, int topStride, float scale)
{
  __shared__ float Qs[DHd][64 + 4];
  __shared__ float Ks[DHd][64 + 4];
  const int tid = threadIdx.x;
  const int z = blockIdx.z, b = z >> 3, h = z & 7;
  const int m0 = blockIdx.x << 6, n0 = blockIdx.y << 6;
  const float* Kbase = Km + ((size_t)(b * Ls + n0)) * DM + h * DHd;
#pragma unroll
  for (int i = 0; i < 4; ++i) {
    int idx = tid + (i << 8);
    int r = idx >> 4, c4 = (idx & 15) << 2;
    int qr;
    if (top) { int u = m0 + r; if (u >= Mrows) u = Mrows - 1; qr = top[z * topStride + u]; }
    else qr = q0 + m0 + r;
    float4 q4 = *reinterpret_cast<const float4*>(Qm + ((size_t)(b * Ls + qr)) * DM + h * DHd + c4);
    Qs[c4 + 0][r] = q4.x; Qs[c4 + 1][r] = q4.y; Qs[c4 + 2][r] = q4.z; Qs[c4 + 3][r] = q4.w;
    float4 k4 = *reinterpret_cast<const float4*>(Kbase + (size_t)r * DM + c4);
    Ks[c4 + 0][r] = k4.x; Ks[c4 + 1][r] = k4.y; Ks[c4 + 2][r] = k4.z; Ks[c4 + 3][r] = k4.w;
  }
  __syncthreads();
  const int mB = (tid >> 4) << 2, nB = (tid & 15) << 2;
  float acc[4][4] = {};
#pragma unroll
  for (int kk = 0; kk < DHd; ++kk) {
    float4 a4 = *reinterpret_cast<const float4*>(&Qs[kk][mB]);
    float4 b4 = *reinterpret_cast<const float4*>(&Ks[kk][nB]);
    const float av[4] = {a4.x, a4.y, a4.z, a4.w};
#pragma unroll
    for (int i = 0; i < 4; ++i) {
      acc[i][0] += av[i] * b4.x; acc[i][1] += av[i] * b4.y;
      acc[i][2] += av[i] * b4.z; acc[i][3] += av[i] * b4.w;
    }
  }
#pragma unroll
  for (int i = 0; i < 4; ++i) {
    int m = m0 + mB + i;
    if (m < Mrows) {
      float4 o;
      o.x = acc[i][0] * scale; o.y = acc[i][1] * scale;
      o.z = acc[i][2] * scale; o.w = acc[i][3] * scale;
      *reinterpret_cast<float4*>(S + ((size_t)z * Mld + m) * Ls + n0 + nB) = o;
    }
  }
}

// ---------------- row softmax over length 1024 (in place) ----------------
__global__ __launch_bounds__(256) void k_softmax(float* __restrict__ S)
{
  __shared__ float red[4];
  const int row = blockIdx.x, tid = threadIdx.x;
  float* p = S + (size_t)row * Ls;
  float4 v = *reinterpret_cast<float4*>(p + (tid << 2));
  float mx = fmaxf(fmaxf(v.x, v.y), fmaxf(v.z, v.w));
#pragma unroll
  for (int off = 32; off; off >>= 1) mx = fmaxf(mx, __shfl_xor(mx, off));
  if ((tid & 63) == 0) red[tid >> 6] = mx;
  __syncthreads();
  mx = fmaxf(fmaxf(red[0], red[1]), fmaxf(red[2], red[3]));
  __syncthreads();
  v.x = __expf(v.x - mx); v.y = __expf(v.y - mx);
  v.z = __expf(v.z - mx); v.w = __expf(v.w - mx);
  float s = v.x + v.y + v.z + v.w;
#pragma unroll
  for (int off = 32; off; off >>= 1) s += __shfl_xor(s, off);
  if ((tid & 63) == 0) red[tid >> 6] = s;
  __syncthreads();
  s = red[0] + red[1] + red[2] + red[3];
  float inv = 1.0f / s;
  v.x *= inv; v.y *= inv; v.z *= inv; v.w *= inv;
  *reinterpret_cast<float4*>(p + (tid << 2)) = v;
}

// ---------------- prob-path PV ----------------
__global__ __launch_bounds__(256) void k_pv(
    const float* __restrict__ S, const float* __restrict__ Vm,
    float* __restrict__ Out, int q0, int Mrows, int Mld, int outStride, int probMode)
{
  __shared__ float Ps[16][64 + 4];
  __shared__ float Vs[16][64 + 4];
  const int tid = threadIdx.x;
  const int z = blockIdx.z, b = z >> 3, h = z & 7;
  const int m0 = blockIdx.x << 6;
  const int pr = tid >> 2, pc = (tid & 3) << 2;
  const int vr = tid >> 4, vc = (tid & 15) << 2;
  const int mB = (tid >> 4) << 2, nB = (tid & 15) << 2;
  float acc[4][4] = {};
  for (int k0 = 0; k0 < Ls; k0 += 16) {
    float4 p4 = *reinterpret_cast<const float4*>(S + ((size_t)z * Mld + m0 + pr) * Ls + k0 + pc);
    Ps[pc + 0][pr] = p4.x; Ps[pc + 1][pr] = p4.y; Ps[pc + 2][pr] = p4.z; Ps[pc + 3][pr] = p4.w;
    *reinterpret_cast<float4*>(&Vs[vr][vc]) =
        *reinterpret_cast<const float4*>(Vm + ((size_t)(b * Ls + k0 + vr)) * DM + h * DHd + vc);
    __syncthreads();
#pragma unroll
    for (int kk = 0; kk < 16; ++kk) {
      float4 a4 = *reinterpret_cast<const float4*>(&Ps[kk][mB]);
      float4 b4 = *reinterpret_cast<const float4*>(&Vs[kk][nB]);
      const float av[4] = {a4.x, a4.y, a4.z, a4.w};
#pragma unroll
      for (int i = 0; i < 4; ++i) {
        acc[i][0] += av[i] * b4.x; acc[i][1] += av[i] * b4.y;
        acc[i][2] += av[i] * b4.z; acc[i][3] += av[i] * b4.w;
      }
    }
    __syncthreads();
  }
#pragma unroll
  for (int i = 0; i < 4; ++i) {
    int m = m0 + mB + i;
    if (m < Mrows) {
      float4 o; o.x = acc[i][0]; o.y = acc[i][1]; o.z = acc[i][2]; o.w = acc[i][3];
      if (probMode)
        *reinterpret_cast<float4*>(Out + ((size_t)z * outStride + m) * DHd + nB) = o;
      else
        *reinterpret_cast<float4*>(Out + ((size_t)(b * Ls + q0 + m)) * DM + h * DHd + nB) = o;
    }
  }
}

// ---------------- ProbSparse sampled scores: 16 queries/wave, 4 lanes each ----------------
__global__ __launch_bounds__(256) void k_mscore2(
    const float* __restrict__ Qm, const float* __restrict__ Km,
    const int* __restrict__ smp, float* __restrict__ Ms, int U)
{
  const int gw = blockIdx.x * 4 + (threadIdx.x >> 6);   // wave over ZH*(Ls/16)
  const int lane = threadIdx.x & 63;
  const int li = lane >> 2, dp = (lane & 3) * 16;
  const int l = (gw & 63) * 16 + li;
  const int z = gw >> 6, b = z >> 3, h = z & 7;
  const float* qb = Qm + (size_t)(b * Ls + l) * DM + h * DHd + dp;
  const float4 q0 = *(const float4*)(qb);
  const float4 q1 = *(const float4*)(qb + 4);
  const float4 q2 = *(const float4*)(qb + 8);
  const float4 q3 = *(const float4*)(qb + 12);
  float mx = -1e30f, sm = 0.f;
  for (int u = 0; u < U; ++u) {
    const int ki = smp[l * U + u];
    const float* kb = Km + (size_t)(b * Ls + ki) * DM + h * DHd + dp;
    const float4 k0 = *(const float4*)(kb);
    const float4 k1 = *(const float4*)(kb + 4);
    const float4 k2 = *(const float4*)(kb + 8);
    const float4 k3 = *(const float4*)(kb + 12);
    float d = q0.x*k0.x + q0.y*k0.y + q0.z*k0.z + q0.w*k0.w
            + q1.x*k1.x + q1.y*k1.y + q1.z*k1.z + q1.w*k1.w
            + q2.x*k2.x + q2.y*k2.y + q2.z*k2.z + q2.w*k2.w
            + q3.x*k3.x + q3.y*k3.y + q3.z*k3.z + q3.w*k3.w;
    d += __shfl_xor(d, 1);
    d += __shfl_xor(d, 2);
    mx = fmaxf(mx, d);
    sm += d;
  }
  if ((lane & 3) == 0) Ms[z * Ls + l] = mx - sm * (1.0f / Ls);
}

// ---------------- iterative top-U ----------------
__global__ __launch_bounds__(256) void k_topk(
    const float* __restrict__ Ms, int* __restrict__ top, int U)
{
  __shared__ float v[Ls];
  __shared__ float rv[256];
  __shared__ int   ri[256];
  const int z = blockIdx.x, tid = threadIdx.x;
  for (int i = tid; i < Ls; i += 256) v[i] = Ms[z * Ls + i];
  __syncthreads();
  for (int it = 0; it < U; ++it) {
    float bv = -1e30f; int bi = 0x7fffffff;
    for (int i = tid; i < Ls; i += 256) {
      float x = v[i];
      if (x > bv || (x == bv && i < bi)) { bv = x; bi = i; }
    }
    rv[tid] = bv; ri[tid] = bi;
    __syncthreads();
    for (int s = 128; s; s >>= 1) {
      if (tid < s) {
        float xv = rv[tid + s]; int xi = ri[tid + s];
        if (xv > rv[tid] || (xv == rv[tid] && xi < ri[tid])) { rv[tid] = xv; ri[tid] = xi; }
      }
      __syncthreads();
    }
    if (tid == 0) { top[z * U + it] = ri[0]; v[ri[0]] = -1e30f; }
    __syncthreads();
  }
}

// ---------------- mean of V over keys ----------------
__global__ __launch_bounds__(256) void k_meanv(
    const float* __restrict__ Vm, float* __restrict__ mv)
{
  __shared__ float ps[4][64];
  const int z = blockIdx.x, b = z >> 3, h = z & 7;
  const int d = threadIdx.x & 63, g = threadIdx.x >> 6;
  float s = 0.f;
  for (int k = g * 256; k < (g + 1) * 256; ++k)
    s += Vm[((size_t)(b * Ls + k)) * DM + h * DHd + d];
  ps[g][d] = s;
  __syncthreads();
  if (g == 0) mv[z * 64 + d] = (ps[0][d] + ps[1][d] + ps[2][d] + ps[3][d]) * (1.0f / Ls);
}

// ---------------- broadcast mean-V ----------------
__global__ __launch_bounds__(256) void k_ctxfill(
    const float* __restrict__ mv, float* __restrict__ ctx)
{
  const int i = blockIdx.x * 256 + threadIdx.x;
  const int c4 = (i & 127) << 2;
  const int row = i >> 7;
  const int b = row >> 10;
  const int h = c4 >> 6;
  float4 m4 = *reinterpret_cast<const float4*>(mv + ((b * 8 + h) * 64) + (c4 & 63));
  *reinterpret_cast<float4*>(ctx + (size_t)row * DM + c4) = m4;
}

// ---------------- scatter upd rows ----------------
__global__ __launch_bounds__(256) void k_scatter(
    const float* __restrict__ upd, const int* __restrict__ top,
    float* __restrict__ ctx, int U, int Uld)
{
  const int z = blockIdx.x, b = z >> 3, h = z & 7;
  const int d = threadIdx.x & 63;
  for (int u = threadIdx.x >> 6; u < U; u += 4) {
    int row = top[z * U + u];
    ctx[((size_t)(b * Ls + row)) * DM + h * DHd + d] =
        upd[((size_t)z * Uld + u) * DHd + d];
  }
}

// ---------------- fused (residual +) LayerNorm; optional f32 + bf16 outputs ----------------
__global__ __launch_bounds__(256) void k_ln(
    const float* __restrict__ x, const float* __restrict__ res,
    const float* __restrict__ g, const float* __restrict__ be,
    float* __restrict__ outf, __hip_bfloat16* __restrict__ outb)
{
  __shared__ float red[4];
  const int row = blockIdx.x, tid = threadIdx.x;
  const size_t base = (size_t)row * DM;
  float2 v = *reinterpret_cast<const float2*>(x + base + tid * 2);
  if (res) {
    float2 r2 = *reinterpret_cast<const float2*>(res + base + tid * 2);
    v.x += r2.x; v.y += r2.y;
  }
  float s = v.x + v.y;
#pragma unroll
  for (int off = 32; off; off >>= 1) s += __shfl_xor(s, off);
  if ((tid & 63) == 0) red[tid >> 6] = s;
  __syncthreads();
  s = red[0] + red[1] + red[2] + red[3];
  const float mean = s * (1.0f / DM);
  __syncthreads();
  float dx = v.x - mean, dy = v.y - mean;
  float q = dx * dx + dy * dy;
#pragma unroll
  for (int off = 32; off; off >>= 1) q += __shfl_xor(q, off);
  if ((tid & 63) == 0) red[tid >> 6] = q;
  __syncthreads();
  q = red[0] + red[1] + red[2] + red[3];
  const float inv = rsqrtf(q * (1.0f / DM) + 1e-5f);
  float2 gg = *reinterpret_cast<const float2*>(g + tid * 2);
  float2 bb = *reinterpret_cast<const float2*>(be + tid * 2);
  float ox = dx * inv * gg.x + bb.x;
  float oy = dy * inv * gg.y + bb.y;
  if (outf) {
    float2 o; o.x = ox; o.y = oy;
    *reinterpret_cast<float2*>(outf + base + tid * 2) = o;
  }
  if (outb) {
    short2 ob; ob.x = f2bf(ox); ob.y = f2bf(oy);
    *reinterpret_cast<short2*>(outb + base + tid * 2) = ob;
  }
}

extern "C" void kernel_launch(void* const* d_in, const int* in_sizes, int n_in,
                              void* d_out, int out_size, void* d_ws, size_t ws_size,
                              hipStream_t stream)
{
  const float* tgt = (const float*)d_in[0];
  const float* mem = (const float*)d_in[1];
  const int*   smp = (const int*)d_in[2];
  const float* wq1 = (const float*)d_in[3];  const float* bq1 = (const float*)d_in[4];
  const float* wk1 = (const float*)d_in[5];  const float* bk1 = (const float*)d_in[6];
  const float* wv1 = (const float*)d_in[7];  const float* bv1 = (const float*)d_in[8];
  const float* wo1 = (const float*)d_in[9];  const float* bo1 = (const float*)d_in[10];
  const float* wq2 = (const float*)d_in[11]; const float* bq2 = (const float*)d_in[12];
  const float* wk2 = (const float*)d_in[13]; const float* bk2 = (const float*)d_in[14];
  const float* wv2 = (const float*)d_in[15]; const float* bv2 = (const float*)d_in[16];
  const float* wo2 = (const float*)d_in[17]; const float* bo2 = (const float*)d_in[18];
  const float* c1w = (const float*)d_in[19]; const float* c1b = (const float*)d_in[20];
  const float* c2w = (const float*)d_in[21]; const float* c2b = (const float*)d_in[22];
  const float* g1  = (const float*)d_in[23]; const float* be1 = (const float*)d_in[24];
  const float* g2  = (const float*)d_in[25]; const float* be2 = (const float*)d_in[26];
  const float* g3  = (const float*)d_in[27]; const float* be3 = (const float*)d_in[28];
  float* outp = (float*)d_out;

  const int U   = in_sizes[2] / Ls;            // 35
  const int Uld = ((U + 63) / 64) * 64;        // 64

  char* ws = (char*)d_ws;
  const size_t SZ = (size_t)MR * DM * sizeof(float);       // 16.78 MB
  float* W0   = (float*)(ws);
  float* W1   = (float*)(ws + SZ);
  float* W2   = (float*)(ws + 2 * SZ);
  float* Sbuf = (float*)(ws + 3 * SZ);                     // 2*SZ: prob scores / FFN hidden
  __hip_bfloat16* Tb  = (__hip_bfloat16*)(ws + 5 * SZ);    // tgt bf16; later reused as Kb
  __hip_bfloat16* Mb  = (__hip_bfloat16*)(ws + 5 * SZ + SZ / 2);
  __hip_bfloat16* Xb  = (__hip_bfloat16*)(ws + 6 * SZ);
  __hip_bfloat16* Vtb = (__hip_bfloat16*)(ws + 6 * SZ + SZ / 2);
  char* tail = ws + 7 * SZ;
  __hip_bfloat16* wv1b = (__hip_bfloat16*)tail; tail += DM * DM * 2;
  __hip_bfloat16* wo1b = (__hip_bfloat16*)tail; tail += DM * DM * 2;
  __hip_bfloat16* wq2b = (__hip_bfloat16*)tail; tail += DM * DM * 2;
  __hip_bfloat16* wk2b = (__hip_bfloat16*)tail; tail += DM * DM * 2;
  __hip_bfloat16* wv2b = (__hip_bfloat16*)tail; tail += DM * DM * 2;
  __hip_bfloat16* wo2b = (__hip_bfloat16*)tail; tail += DM * DM * 2;
  __hip_bfloat16* c1wb = (__hip_bfloat16*)tail; tail += DM * 4 * DM * 2;
  __hip_bfloat16* c2wb = (__hip_bfloat16*)tail; tail += DM * 4 * DM * 2;
  float* Ms  = (float*)tail; tail += (size_t)ZH * Ls * 4;
  int*   top = (int*)tail;   tail += (size_t)ZH * Uld * 4;
  float* mv  = (float*)tail; tail += (size_t)ZH * DHd * 4;
  float* upd = (float*)tail; tail += (size_t)ZH * Uld * DHd * 4;
  __hip_bfloat16* Kb = Tb;                 // alias: Tb dead after V1 GEMM
  __hip_bfloat16* Qb = (__hip_bfloat16*)d_out;  // parked in d_out until final LN
  __hip_bfloat16* hb = (__hip_bfloat16*)Sbuf;

  auto gemmF = [&](const float* A, const float* Wm, const float* bi, float* C,
                   int M, int N, int K) {
    dim3 g(M / 128, N / 64);
    k_gemm_bias<0><<<g, 256, 0, stream>>>(A, Wm, bi, C, M, N, K);
  };
  auto wcvt = [&](const float* Wm, __hip_bfloat16* Wt, int K, int N) {
    k_wt_cvt<<<dim3(K / 32, N / 32), 256, 0, stream>>>(Wm, Wt, K, N);
  };

  // ---- one-time converts ----
  k_cvt<<<dim3(MR * DM / 4 / 256), 256, 0, stream>>>(tgt, Tb);
  k_cvt<<<dim3(MR * DM / 4 / 256), 256, 0, stream>>>(mem, Mb);
  wcvt(wv1, wv1b, DM, DM); wcvt(wo1, wo1b, DM, DM);
  wcvt(wq2, wq2b, DM, DM); wcvt(wk2, wk2b, DM, DM);
  wcvt(wv2, wv2b, DM, DM); wcvt(wo2, wo2b, DM, DM);
  wcvt(c1w, c1wb, DM, 4 * DM); wcvt(c2w, c2wb, 4 * DM, DM);

  dim3 gsq(MR / 128, DM / 128);
  // ---- layer-1 projections: Q1,K1 f32 (top-k fidelity), V1 bf16 MFMA ----
  gemmF(tgt, wq1, bq1, W0, MR, DM, DM);
  gemmF(tgt, wk1, bk1, W1, MR, DM, DM);
  k_gemm_mfma<0, 0><<<gsq, 256, 0, stream>>>(Tb, wv1b, bv1, W2, MR, DM, DM);

  // ---- ProbSparse ----
  k_mscore2<<<dim3(ZH * (Ls / 16) / 4), 256, 0, stream>>>(W0, W1, smp, Ms, U);
  k_topk<<<dim3(ZH), 256, 0, stream>>>(Ms, top, U);
  k_qkT<<<dim3(Uld / 64, Ls / 64, ZH), 256, 0, stream>>>(W0, W1, Sbuf, top, 0, U, Uld, U, 0.125f);
  k_softmax<<<dim3(ZH * Uld), 256, 0, stream>>>(Sbuf);
  k_pv<<<dim3(Uld / 64, 1, ZH), 256, 0, stream>>>(Sbuf, W2, upd, 0, U, Uld, Uld, 1);
  k_meanv<<<dim3(ZH), 256, 0, stream>>>(W2, mv);
  k_ctxfill<<<dim3(MR * DM / 4 / 256), 256, 0, stream>>>(mv, W1);   // ctx -> W1
  k_scatter<<<dim3(ZH), 256, 0, stream>>>(upd, top, W1, U, Uld);

  // ---- out-proj 1 + residual LN ----
  k_cvt<<<dim3(MR * DM / 4 / 256), 256, 0, stream>>>(W1, Xb);       // ctx -> bf16
  k_gemm_mfma<0, 0><<<gsq, 256, 0, stream>>>(Xb, wo1b, bo1, W0, MR, DM, DM);
  k_ln<<<dim3(MR), 256, 0, stream>>>(W0, tgt, g1, be1, nullptr, Xb); // x1 -> Xb bf16

  // ---- layer-2 projections (bf16 outputs, flash-ready layouts) ----
  k_gemm_mfma<1, 0><<<gsq, 256, 0, stream>>>(Xb, wq2b, bq2, Qb,  MR, DM, DM);
  k_gemm_mfma<2, 0><<<gsq, 256, 0, stream>>>(Mb, wk2b, bk2, Kb,  MR, DM, DM);
  k_gemm_mfma<3, 0><<<gsq, 256, 0, stream>>>(Mb, wv2b, bv2, Vtb, MR, DM, DM);

  // ---- fused flash cross attention -> Xb (bf16) ----
  k_flash<<<dim3(Ls / 64, ZH), 256, 0, stream>>>(Qb, Kb, Vtb, Xb);

  // ---- out-proj 2 + LN + FFN + final LN ----
  k_gemm_mfma<0, 0><<<gsq, 256, 0, stream>>>(Xb, wo2b, bo2, W0, MR, DM, DM);
  k_ln<<<dim3(MR), 256, 0, stream>>>(W0, nullptr, g2, be2, W1, Xb); // x2ln -> W1 f32 + Xb bf16
  k_gemm_mfma<1, 1><<<dim3(MR / 128, 4 * DM / 128), 256, 0, stream>>>(
      Xb, c1wb, c1b, hb, MR, 4 * DM, DM);
  k_gemm_mfma<0, 0><<<dim3(MR / 128, DM / 128), 256, 0, stream>>>(
      hb, c2wb, c2b, W2, MR, DM, 4 * DM);
  k_ln<<<dim3(MR), 256, 0, stream>>>(W2, W1, g3, be3, outp, nullptr); // final -> d_out
}

// Round 4
// 559.213 us; speedup vs baseline: 3.9262x; 1.1857x over previous
//
#include <hip/hip_runtime.h>
#include <hip/hip_bf16.h>
#include <cstdint>

constexpr int Bb  = 8;
constexpr int Ls  = 1024;
constexpr int DM  = 512;
constexpr int NH  = 8;
constexpr int DHd = 64;
constexpr int MR  = Bb * Ls;   // 8192 rows
constexpr int ZH  = Bb * NH;   // 64 (b,h) pairs

typedef __attribute__((ext_vector_type(8))) short short8v;
typedef __attribute__((ext_vector_type(4))) short short4v;
typedef __attribute__((ext_vector_type(4))) float floatx4;

__device__ inline short f2bf(float x) {
  __hip_bfloat16 h = __float2bfloat16(x);
  return *reinterpret_cast<short*>(&h);
}

#define GLOAD_LDS16(g, l)                                                        \
  __builtin_amdgcn_global_load_lds(                                              \
      (const __attribute__((address_space(1))) void*)(g),                        \
      (__attribute__((address_space(3))) void*)(l), 16, 0, 0)

// ================= bf16 MFMA GEMM: C = act(A @ Wt^T + bias) =================
// A: MxK bf16 row-major. Wt: NxK bf16 row-major (pre-transposed weight).
// MODE: 0 = f32 out, 1 = bf16 out, 2 = bf16 out with per-row d-slot XOR swizzle
// (for flash K staging), 3 = bf16 transposed-per-head + key-slot swizzle
// (for flash V staging; assumes N==512, rows = b*1024+l).
template<int MODE, int RELU>
__global__ __launch_bounds__(256) void k_gemm_mfma(
    const __hip_bfloat16* __restrict__ A, const __hip_bfloat16* __restrict__ Wt,
    const float* __restrict__ bias, void* __restrict__ Cout,
    int M, int N, int K)
{
  __shared__ __hip_bfloat16 As[128 * 32];
  __shared__ __hip_bfloat16 Bs[128 * 32];
  const int tid = threadIdx.x;
  const int w = tid >> 6, lane = tid & 63;
  const int wr = w >> 1, wc = w & 1;
  const int bm = blockIdx.x * 128, bn = blockIdx.y * 128;
  const int lrow = lane >> 2;
  const int lcol = (lane & 3) * 8;
  const int fr = lane & 15;
  const int fco = (lane >> 4) * 8;
  const short* Ash = (const short*)As;
  const short* Bsh = (const short*)Bs;

  floatx4 acc[4][4] = {};
  for (int k0 = 0; k0 < K; k0 += 32) {
#pragma unroll
    for (int i = 0; i < 2; ++i) {
      const int chunk = w * 2 + i;
      GLOAD_LDS16(A  + (size_t)(bm + chunk * 16 + lrow) * K + k0 + lcol,
                  As + chunk * 512);
      GLOAD_LDS16(Wt + (size_t)(bn + chunk * 16 + lrow) * K + k0 + lcol,
                  Bs + chunk * 512);
    }
    __syncthreads();
    short8v a[4], b[4];
#pragma unroll
    for (int mi = 0; mi < 4; ++mi)
      a[mi] = *(const short8v*)(Ash + (wr * 64 + mi * 16 + fr) * 32 + fco);
#pragma unroll
    for (int ni = 0; ni < 4; ++ni)
      b[ni] = *(const short8v*)(Bsh + (wc * 64 + ni * 16 + fr) * 32 + fco);
#pragma unroll
    for (int mi = 0; mi < 4; ++mi)
#pragma unroll
      for (int ni = 0; ni < 4; ++ni)
        acc[mi][ni] = __builtin_amdgcn_mfma_f32_16x16x32_bf16(
            a[mi], b[ni], acc[mi][ni], 0, 0, 0);
    __syncthreads();
  }
#pragma unroll
  for (int ni = 0; ni < 4; ++ni) {
    const int cn = bn + wc * 64 + ni * 16 + fr;
    const float bv = bias[cn];
#pragma unroll
    for (int mi = 0; mi < 4; ++mi) {
#pragma unroll
      for (int j = 0; j < 4; ++j) {
        const int rm = bm + wr * 64 + mi * 16 + (lane >> 4) * 4 + j;
        float v = acc[mi][ni][j] + bv;
        if (RELU) v = fmaxf(v, 0.f);
        if (MODE == 0) {
          ((float*)Cout)[(size_t)rm * N + cn] = v;
        } else if (MODE == 1) {
          ((__hip_bfloat16*)Cout)[(size_t)rm * N + cn] = __float2bfloat16(v);
        } else if (MODE == 2) {
          const int cs = (cn & ~63) | ((cn & 63) ^ ((rm & 7) << 3));
          ((__hip_bfloat16*)Cout)[(size_t)rm * N + cs] = __float2bfloat16(v);
        } else {
          const int bb = rm >> 10, l = rm & 1023, hh = cn >> 6, dd = cn & 63;
          ((__hip_bfloat16*)Cout)[(size_t)((bb * 8 + hh) * 64 + dd) * 1024 +
                                  (l ^ ((dd & 7) << 3))] = __float2bfloat16(v);
        }
      }
    }
  }
}

// ================= fused flash cross-attention (bf16 MFMA) =================
__global__ __launch_bounds__(256) void k_flash(
    const __hip_bfloat16* __restrict__ Qb,
    const __hip_bfloat16* __restrict__ Kb,
    const __hip_bfloat16* __restrict__ Vt,
    __hip_bfloat16* __restrict__ O)
{
  __shared__ __hip_bfloat16 Ks[64 * 64];
  __shared__ __hip_bfloat16 Vs[64 * 64];
  __shared__ __hip_bfloat16 Ps[4 * 16 * 72];
  const int tid = threadIdx.x, w = tid >> 6, lane = tid & 63;
  const int g = lane >> 4, r = lane & 15;
  const int z = blockIdx.y, b = z >> 3, h = z & 7;
  const int q0 = blockIdx.x * 64 + w * 16;
  __hip_bfloat16* Pw = Ps + w * 16 * 72;

  const short8v qf0 = *(const short8v*)(Qb + (size_t)(b * Ls + q0 + r) * DM + h * DHd + g * 8);
  const short8v qf1 = *(const short8v*)(Qb + (size_t)(b * Ls + q0 + r) * DM + h * DHd + 32 + g * 8);

  floatx4 oacc[4] = {};
  float m_run = -1e30f, l_run = 0.f;

  for (int t = 0; t < 16; ++t) {
    __syncthreads();
#pragma unroll
    for (int i = 0; i < 2; ++i) {
      const int sbase = (i * 4 + w) * 64;
      const int rowi = (sbase + lane) >> 3, ds = lane & 7;
      GLOAD_LDS16(Kb + (size_t)(b * Ls + t * 64 + rowi) * DM + h * DHd + ds * 8,
                  Ks + sbase * 8);
      GLOAD_LDS16(Vt + ((size_t)z * DHd + rowi) * Ls + t * 64 + ds * 8,
                  Vs + sbase * 8);
    }
    __syncthreads();
    float sv[4][4];
    float tmax = -1e30f;
#pragma unroll
    for (int kt = 0; kt < 4; ++kt) {
      const int key = kt * 16 + r, sw = key & 7;
      short8v a0 = *(const short8v*)(Ks + key * 64 + ((g ^ sw) * 8));
      short8v a1 = *(const short8v*)(Ks + key * 64 + (((4 + g) ^ sw) * 8));
      floatx4 c = {};
      c = __builtin_amdgcn_mfma_f32_16x16x32_bf16(a0, qf0, c, 0, 0, 0);
      c = __builtin_amdgcn_mfma_f32_16x16x32_bf16(a1, qf1, c, 0, 0, 0);
#pragma unroll
      for (int j = 0; j < 4; ++j) {
        float x = c[j] * 0.125f;
        sv[kt][j] = x;
        tmax = fmaxf(tmax, x);
      }
    }
    tmax = fmaxf(tmax, __shfl_xor(tmax, 16));
    tmax = fmaxf(tmax, __shfl_xor(tmax, 32));
    const float m_new = fmaxf(m_run, tmax);
    const float fac = __expf(m_run - m_new);
    float psum = 0.f;
#pragma unroll
    for (int kt = 0; kt < 4; ++kt) {
      short4v pk;
#pragma unroll
      for (int j = 0; j < 4; ++j) {
        float p = __expf(sv[kt][j] - m_new);
        psum += p;
        pk[j] = f2bf(p);
      }
      *(short4v*)(Pw + r * 72 + kt * 16 + g * 4) = pk;
    }
    psum += __shfl_xor(psum, 16);
    psum += __shfl_xor(psum, 32);
    l_run = l_run * fac + psum;
    m_run = m_new;
    float fj[4];
#pragma unroll
    for (int j = 0; j < 4; ++j) fj[j] = __shfl(fac, (lane & 48) | (g * 4 + j));
#pragma unroll
    for (int ct = 0; ct < 4; ++ct)
#pragma unroll
      for (int j = 0; j < 4; ++j) oacc[ct][j] *= fj[j];
    const short8v pa0 = *(const short8v*)(Pw + r * 72 + g * 8);
    const short8v pa1 = *(const short8v*)(Pw + r * 72 + 32 + g * 8);
#pragma unroll
    for (int ct = 0; ct < 4; ++ct) {
      const int d = ct * 16 + r, sw = d & 7;
      short8v v0 = *(const short8v*)(Vs + d * 64 + ((g ^ sw) * 8));
      short8v v1 = *(const short8v*)(Vs + d * 64 + (((4 + g) ^ sw) * 8));
      oacc[ct] = __builtin_amdgcn_mfma_f32_16x16x32_bf16(pa0, v0, oacc[ct], 0, 0, 0);
      oacc[ct] = __builtin_amdgcn_mfma_f32_16x16x32_bf16(pa1, v1, oacc[ct], 0, 0, 0);
    }
  }
  float li[4];
#pragma unroll
  for (int j = 0; j < 4; ++j)
    li[j] = 1.0f / __shfl(l_run, (lane & 48) | (g * 4 + j));
#pragma unroll
  for (int ct = 0; ct < 4; ++ct)
#pragma unroll
    for (int j = 0; j < 4; ++j)
      O[(size_t)(b * Ls + q0 + g * 4 + j) * DM + h * DHd + ct * 16 + r] =
          __float2bfloat16(oacc[ct][j] * li[j]);
}

// ---------------- f32 -> bf16 elementwise ----------------
__global__ __launch_bounds__(256) void k_cvt(
    const float* __restrict__ in, __hip_bfloat16* __restrict__ out)
{
  const size_t i = ((size_t)blockIdx.x * 256 + threadIdx.x) * 4;
  float4 v = *reinterpret_cast<const float4*>(in + i);
  short4v o;
  o.x = f2bf(v.x); o.y = f2bf(v.y); o.z = f2bf(v.z); o.w = f2bf(v.w);
  *reinterpret_cast<short4v*>(out + i) = o;
}

// ---------------- weight convert+transpose: W(KxN f32) -> Wt(NxK bf16) ----------------
__global__ __launch_bounds__(256) void k_wt_cvt(
    const float* __restrict__ W, __hip_bfloat16* __restrict__ Wt, int K, int N)
{
  __shared__ float t[32][33];
  const int tid = threadIdx.x;
  const int k0 = blockIdx.x * 32, n0 = blockIdx.y * 32;
  const int r = tid >> 3, c = (tid & 7) * 4;
  float4 v = *reinterpret_cast<const float4*>(W + (size_t)(k0 + r) * N + n0 + c);
  t[r][c + 0] = v.x; t[r][c + 1] = v.y; t[r][c + 2] = v.z; t[r][c + 3] = v.w;
  __syncthreads();
  short4v o;
  o.x = f2bf(t[c + 0][r]); o.y = f2bf(t[c + 1][r]);
  o.z = f2bf(t[c + 2][r]); o.w = f2bf(t[c + 3][r]);
  *reinterpret_cast<short4v*>(Wt + (size_t)(n0 + r) * K + k0 + c) = o;
}

// ---------------- prob-path batched scores: S[z] = scale * Qrows @ K^T ----------------
__global__ __launch_bounds__(256) void k_qkT(
    const float* __restrict__ Qm, const float* __restrict__ Km,
    float* __restrict__ S, const int* __restrict__ top,
    int q0, int Mrows, int Mld, int topStride, float scale)
{
  __shared__ float Qs[DHd][64 + 4];
  __shared__ float Ks[DHd][64 + 4];
  const int tid = threadIdx.x;
  const int z = blockIdx.z, b = z >> 3, h = z & 7;
  const int m0 = blockIdx.x << 6, n0 = blockIdx.y << 6;
  const float* Kbase = Km + ((size_t)(b * Ls + n0)) * DM + h * DHd;
#pragma unroll
  for (int i = 0; i < 4; ++i) {
    int idx = tid + (i << 8);
    int r = idx >> 4, c4 = (idx & 15) << 2;
    int qr;
    if (top) { int u = m0 + r; if (u >= Mrows) u = Mrows - 1; qr = top[z * topStride + u]; }
    else qr = q0 + m0 + r;
    float4 q4 = *reinterpret_cast<const float4*>(Qm + ((size_t)(b * Ls + qr)) * DM + h * DHd + c4);
    Qs[c4 + 0][r] = q4.x; Qs[c4 + 1][r] = q4.y; Qs[c4 + 2][r] = q4.z; Qs[c4 + 3][r] = q4.w;
    float4 k4 = *reinterpret_cast<const float4*>(Kbase + (size_t)r * DM + c4);
    Ks[c4 + 0][r] = k4.x; Ks[c4 + 1][r] = k4.y; Ks[c4 + 2][r] = k4.z; Ks[c4 + 3][r] = k4.w;
  }
  __syncthreads();
  const int mB = (tid >> 4) << 2, nB = (tid & 15) << 2;
  float acc[4][4] = {};
#pragma unroll
  for (int kk = 0; kk < DHd; ++kk) {
    float4 a4 = *reinterpret_cast<const float4*>(&Qs[kk][mB]);
    float4 b4 = *reinterpret_cast<const float4*>(&Ks[kk][nB]);
    const float av[4] = {a4.x, a4.y, a4.z, a4.w};
#pragma unroll
    for (int i = 0; i < 4; ++i) {
      acc[i][0] += av[i] * b4.x; acc[i][1] += av[i] * b4.y;
      acc[i][2] += av[i] * b4.z; acc[i][3] += av[i] * b4.w;
    }
  }
#pragma unroll
  for (int i = 0; i < 4; ++i) {
    int m = m0 + mB + i;
    if (m < Mrows) {
      float4 o;
      o.x = acc[i][0] * scale; o.y = acc[i][1] * scale;
      o.z = acc[i][2] * scale; o.w = acc[i][3] * scale;
      *reinterpret_cast<float4*>(S + ((size_t)z * Mld + m) * Ls + n0 + nB) = o;
    }
  }
}

// ---------------- row softmax over length 1024 (in place) ----------------
__global__ __launch_bounds__(256) void k_softmax(float* __restrict__ S)
{
  __shared__ float red[4];
  const int row = blockIdx.x, tid = threadIdx.x;
  float* p = S + (size_t)row * Ls;
  float4 v = *reinterpret_cast<float4*>(p + (tid << 2));
  float mx = fmaxf(fmaxf(v.x, v.y), fmaxf(v.z, v.w));
#pragma unroll
  for (int off = 32; off; off >>= 1) mx = fmaxf(mx, __shfl_xor(mx, off));
  if ((tid & 63) == 0) red[tid >> 6] = mx;
  __syncthreads();
  mx = fmaxf(fmaxf(red[0], red[1]), fmaxf(red[2], red[3]));
  __syncthreads();
  v.x = __expf(v.x - mx); v.y = __expf(v.y - mx);
  v.z = __expf(v.z - mx); v.w = __expf(v.w - mx);
  float s = v.x + v.y + v.z + v.w;
#pragma unroll
  for (int off = 32; off; off >>= 1) s += __shfl_xor(s, off);
  if ((tid & 63) == 0) red[tid >> 6] = s;
  __syncthreads();
  s = red[0] + red[1] + red[2] + red[3];
  float inv = 1.0f / s;
  v.x *= inv; v.y *= inv; v.z *= inv; v.w *= inv;
  *reinterpret_cast<float4*>(p + (tid << 2)) = v;
}

// ---------------- prob-path PV ----------------
__global__ __launch_bounds__(256) void k_pv(
    const float* __restrict__ S, const float* __restrict__ Vm,
    float* __restrict__ Out, int q0, int Mrows, int Mld, int outStride, int probMode)
{
  __shared__ float Ps[16][64 + 4];
  __shared__ float Vs[16][64 + 4];
  const int tid = threadIdx.x;
  const int z = blockIdx.z, b = z >> 3, h = z & 7;
  const int m0 = blockIdx.x << 6;
  const int pr = tid >> 2, pc = (tid & 3) << 2;
  const int vr = tid >> 4, vc = (tid & 15) << 2;
  const int mB = (tid >> 4) << 2, nB = (tid & 15) << 2;
  float acc[4][4] = {};
  for (int k0 = 0; k0 < Ls; k0 += 16) {
    float4 p4 = *reinterpret_cast<const float4*>(S + ((size_t)z * Mld + m0 + pr) * Ls + k0 + pc);
    Ps[pc + 0][pr] = p4.x; Ps[pc + 1][pr] = p4.y; Ps[pc + 2][pr] = p4.z; Ps[pc + 3][pr] = p4.w;
    *reinterpret_cast<float4*>(&Vs[vr][vc]) =
        *reinterpret_cast<const float4*>(Vm + ((size_t)(b * Ls + k0 + vr)) * DM + h * DHd + vc);
    __syncthreads();
#pragma unroll
    for (int kk = 0; kk < 16; ++kk) {
      float4 a4 = *reinterpret_cast<const float4*>(&Ps[kk][mB]);
      float4 b4 = *reinterpret_cast<const float4*>(&Vs[kk][nB]);
      const float av[4] = {a4.x, a4.y, a4.z, a4.w};
#pragma unroll
      for (int i = 0; i < 4; ++i) {
        acc[i][0] += av[i] * b4.x; acc[i][1] += av[i] * b4.y;
        acc[i][2] += av[i] * b4.z; acc[i][3] += av[i] * b4.w;
      }
    }
    __syncthreads();
  }
#pragma unroll
  for (int i = 0; i < 4; ++i) {
    int m = m0 + mB + i;
    if (m < Mrows) {
      float4 o; o.x = acc[i][0]; o.y = acc[i][1]; o.z = acc[i][2]; o.w = acc[i][3];
      if (probMode)
        *reinterpret_cast<float4*>(Out + ((size_t)z * outStride + m) * DHd + nB) = o;
      else
        *reinterpret_cast<float4*>(Out + ((size_t)(b * Ls + q0 + m)) * DM + h * DHd + nB) = o;
    }
  }
}

// ---------------- ProbSparse sampled scores: 16 queries/wave, 4 lanes each ----------------
__global__ __launch_bounds__(256) void k_mscore2(
    const float* __restrict__ Qm, const float* __restrict__ Km,
    const int* __restrict__ smp, float* __restrict__ Ms, int U)
{
  const int gw = blockIdx.x * 4 + (threadIdx.x >> 6);
  const int lane = threadIdx.x & 63;
  const int li = lane >> 2, dp = (lane & 3) * 16;
  const int l = (gw & 63) * 16 + li;
  const int z = gw >> 6, b = z >> 3, h = z & 7;
  const float* qb = Qm + (size_t)(b * Ls + l) * DM + h * DHd + dp;
  const float4 q0 = *(const float4*)(qb);
  const float4 q1 = *(const float4*)(qb + 4);
  const float4 q2 = *(const float4*)(qb + 8);
  const float4 q3 = *(const float4*)(qb + 12);
  float mx = -1e30f, sm = 0.f;
  for (int u = 0; u < U; ++u) {
    const int ki = smp[l * U + u];
    const float* kb = Km + (size_t)(b * Ls + ki) * DM + h * DHd + dp;
    const float4 k0 = *(const float4*)(kb);
    const float4 k1 = *(const float4*)(kb + 4);
    const float4 k2 = *(const float4*)(kb + 8);
    const float4 k3 = *(const float4*)(kb + 12);
    float d = q0.x*k0.x + q0.y*k0.y + q0.z*k0.z + q0.w*k0.w
            + q1.x*k1.x + q1.y*k1.y + q1.z*k1.z + q1.w*k1.w
            + q2.x*k2.x + q2.y*k2.y + q2.z*k2.z + q2.w*k2.w
            + q3.x*k3.x + q3.y*k3.y + q3.z*k3.z + q3.w*k3.w;
    d += __shfl_xor(d, 1);
    d += __shfl_xor(d, 2);
    mx = fmaxf(mx, d);
    sm += d;
  }
  if ((lane & 3) == 0) Ms[z * Ls + l] = mx - sm * (1.0f / Ls);
}

// ---------------- iterative top-U ----------------
__global__ __launch_bounds__(256) void k_topk(
    const float* __restrict__ Ms, int* __restrict__ top, int U)
{
  __shared__ float v[Ls];
  __shared__ float rv[256];
  __shared__ int   ri[256];
  const int z = blockIdx.x, tid = threadIdx.x;
  for (int i = tid; i < Ls; i += 256) v[i] = Ms[z * Ls + i];
  __syncthreads();
  for (int it = 0; it < U; ++it) {
    float bv = -1e30f; int bi = 0x7fffffff;
    for (int i = tid; i < Ls; i += 256) {
      float x = v[i];
      if (x > bv || (x == bv && i < bi)) { bv = x; bi = i; }
    }
    rv[tid] = bv; ri[tid] = bi;
    __syncthreads();
    for (int s = 128; s; s >>= 1) {
      if (tid < s) {
        float xv = rv[tid + s]; int xi = ri[tid + s];
        if (xv > rv[tid] || (xv == rv[tid] && xi < ri[tid])) { rv[tid] = xv; ri[tid] = xi; }
      }
      __syncthreads();
    }
    if (tid == 0) { top[z * U + it] = ri[0]; v[ri[0]] = -1e30f; }
    __syncthreads();
  }
}

// ---------------- mean of V over keys ----------------
__global__ __launch_bounds__(256) void k_meanv(
    const float* __restrict__ Vm, float* __restrict__ mv)
{
  __shared__ float ps[4][64];
  const int z = blockIdx.x, b = z >> 3, h = z & 7;
  const int d = threadIdx.x & 63, g = threadIdx.x >> 6;
  float s = 0.f;
  for (int k = g * 256; k < (g + 1) * 256; ++k)
    s += Vm[((size_t)(b * Ls + k)) * DM + h * DHd + d];
  ps[g][d] = s;
  __syncthreads();
  if (g == 0) mv[z * 64 + d] = (ps[0][d] + ps[1][d] + ps[2][d] + ps[3][d]) * (1.0f / Ls);
}

// ---------------- broadcast mean-V into bf16 ctx ----------------
__global__ __launch_bounds__(256) void k_ctxfillb(
    const float* __restrict__ mv, __hip_bfloat16* __restrict__ ctx)
{
  const int i = blockIdx.x * 256 + threadIdx.x;
  const int c4 = (i & 127) << 2;
  const int row = i >> 7;
  const int b = row >> 10;
  const int h = c4 >> 6;
  float4 m4 = *reinterpret_cast<const float4*>(mv + ((b * 8 + h) * 64) + (c4 & 63));
  short4v o;
  o.x = f2bf(m4.x); o.y = f2bf(m4.y); o.z = f2bf(m4.z); o.w = f2bf(m4.w);
  *reinterpret_cast<short4v*>(ctx + (size_t)row * DM + c4) = o;
}

// ---------------- scatter upd rows into bf16 ctx ----------------
__global__ __launch_bounds__(256) void k_scatterb(
    const float* __restrict__ upd, const int* __restrict__ top,
    __hip_bfloat16* __restrict__ ctx, int U, int Uld)
{
  const int z = blockIdx.x, b = z >> 3, h = z & 7;
  const int d = threadIdx.x & 63;
  for (int u = threadIdx.x >> 6; u < U; u += 4) {
    int row = top[z * U + u];
    ctx[((size_t)(b * Ls + row)) * DM + h * DHd + d] =
        __float2bfloat16(upd[((size_t)z * Uld + u) * DHd + d]);
  }
}

// ---------------- fused (residual +) LayerNorm; optional f32 + bf16 outputs ----------------
__global__ __launch_bounds__(256) void k_ln(
    const float* __restrict__ x, const float* __restrict__ res,
    const float* __restrict__ g, const float* __restrict__ be,
    float* __restrict__ outf, __hip_bfloat16* __restrict__ outb)
{
  __shared__ float red[4];
  const int row = blockIdx.x, tid = threadIdx.x;
  const size_t base = (size_t)row * DM;
  float2 v = *reinterpret_cast<const float2*>(x + base + tid * 2);
  if (res) {
    float2 r2 = *reinterpret_cast<const float2*>(res + base + tid * 2);
    v.x += r2.x; v.y += r2.y;
  }
  float s = v.x + v.y;
#pragma unroll
  for (int off = 32; off; off >>= 1) s += __shfl_xor(s, off);
  if ((tid & 63) == 0) red[tid >> 6] = s;
  __syncthreads();
  s = red[0] + red[1] + red[2] + red[3];
  const float mean = s * (1.0f / DM);
  __syncthreads();
  float dx = v.x - mean, dy = v.y - mean;
  float q = dx * dx + dy * dy;
#pragma unroll
  for (int off = 32; off; off >>= 1) q += __shfl_xor(q, off);
  if ((tid & 63) == 0) red[tid >> 6] = q;
  __syncthreads();
  q = red[0] + red[1] + red[2] + red[3];
  const float inv = rsqrtf(q * (1.0f / DM) + 1e-5f);
  float2 gg = *reinterpret_cast<const float2*>(g + tid * 2);
  float2 bb = *reinterpret_cast<const float2*>(be + tid * 2);
  float ox = dx * inv * gg.x + bb.x;
  float oy = dy * inv * gg.y + bb.y;
  if (outf) {
    float2 o; o.x = ox; o.y = oy;
    *reinterpret_cast<float2*>(outf + base + tid * 2) = o;
  }
  if (outb) {
    short2 ob; ob.x = f2bf(ox); ob.y = f2bf(oy);
    *reinterpret_cast<short2*>(outb + base + tid * 2) = ob;
  }
}

extern "C" void kernel_launch(void* const* d_in, const int* in_sizes, int n_in,
                              void* d_out, int out_size, void* d_ws, size_t ws_size,
                              hipStream_t stream)
{
  const float* tgt = (const float*)d_in[0];
  const float* mem = (const float*)d_in[1];
  const int*   smp = (const int*)d_in[2];
  const float* wq1 = (const float*)d_in[3];  const float* bq1 = (const float*)d_in[4];
  const float* wk1 = (const float*)d_in[5];  const float* bk1 = (const float*)d_in[6];
  const float* wv1 = (const float*)d_in[7];  const float* bv1 = (const float*)d_in[8];
  const float* wo1 = (const float*)d_in[9];  const float* bo1 = (const float*)d_in[10];
  const float* wq2 = (const float*)d_in[11]; const float* bq2 = (const float*)d_in[12];
  const float* wk2 = (const float*)d_in[13]; const float* bk2 = (const float*)d_in[14];
  const float* wv2 = (const float*)d_in[15]; const float* bv2 = (const float*)d_in[16];
  const float* wo2 = (const float*)d_in[17]; const float* bo2 = (const float*)d_in[18];
  const float* c1w = (const float*)d_in[19]; const float* c1b = (const float*)d_in[20];
  const float* c2w = (const float*)d_in[21]; const float* c2b = (const float*)d_in[22];
  const float* g1  = (const float*)d_in[23]; const float* be1 = (const float*)d_in[24];
  const float* g2  = (const float*)d_in[25]; const float* be2 = (const float*)d_in[26];
  const float* g3  = (const float*)d_in[27]; const float* be3 = (const float*)d_in[28];
  float* outp = (float*)d_out;

  const int U   = in_sizes[2] / Ls;            // 35
  const int Uld = ((U + 63) / 64) * 64;        // 64

  char* ws = (char*)d_ws;
  const size_t SZ = (size_t)MR * DM * sizeof(float);       // 16.78 MB
  float* W0   = (float*)(ws);
  float* W1   = (float*)(ws + SZ);
  float* W2   = (float*)(ws + 2 * SZ);
  float* Sbuf = (float*)(ws + 3 * SZ);                     // 2*SZ: prob scores / FFN hidden
  __hip_bfloat16* Tb  = (__hip_bfloat16*)(ws + 5 * SZ);    // tgt bf16; later reused as Kb
  __hip_bfloat16* Mb  = (__hip_bfloat16*)(ws + 5 * SZ + SZ / 2);
  __hip_bfloat16* Xb  = (__hip_bfloat16*)(ws + 6 * SZ);
  __hip_bfloat16* Vtb = (__hip_bfloat16*)(ws + 6 * SZ + SZ / 2);
  // wq1b/wk1b alias the Vtb region: they are dead before V2 GEMM writes Vtb.
  __hip_bfloat16* wq1b = Vtb;
  __hip_bfloat16* wk1b = Vtb + DM * DM;
  char* tail = ws + 7 * SZ;
  __hip_bfloat16* wv1b = (__hip_bfloat16*)tail; tail += DM * DM * 2;
  __hip_bfloat16* wo1b = (__hip_bfloat16*)tail; tail += DM * DM * 2;
  __hip_bfloat16* wq2b = (__hip_bfloat16*)tail; tail += DM * DM * 2;
  __hip_bfloat16* wk2b = (__hip_bfloat16*)tail; tail += DM * DM * 2;
  __hip_bfloat16* wv2b = (__hip_bfloat16*)tail; tail += DM * DM * 2;
  __hip_bfloat16* wo2b = (__hip_bfloat16*)tail; tail += DM * DM * 2;
  __hip_bfloat16* c1wb = (__hip_bfloat16*)tail; tail += DM * 4 * DM * 2;
  __hip_bfloat16* c2wb = (__hip_bfloat16*)tail; tail += DM * 4 * DM * 2;
  float* Ms  = (float*)tail; tail += (size_t)ZH * Ls * 4;
  int*   top = (int*)tail;   tail += (size_t)ZH * Uld * 4;
  float* mv  = (float*)tail; tail += (size_t)ZH * DHd * 4;
  float* upd = (float*)tail; tail += (size_t)ZH * Uld * DHd * 4;
  __hip_bfloat16* Kb = Tb;                 // alias: Tb dead after K1 GEMM
  __hip_bfloat16* Qb = (__hip_bfloat16*)d_out;  // parked in d_out until final LN
  __hip_bfloat16* hb = (__hip_bfloat16*)Sbuf;

  auto wcvt = [&](const float* Wm, __hip_bfloat16* Wt, int K, int N) {
    k_wt_cvt<<<dim3(K / 32, N / 32), 256, 0, stream>>>(Wm, Wt, K, N);
  };

  // ---- one-time converts ----
  k_cvt<<<dim3(MR * DM / 4 / 256), 256, 0, stream>>>(tgt, Tb);
  k_cvt<<<dim3(MR * DM / 4 / 256), 256, 0, stream>>>(mem, Mb);
  wcvt(wq1, wq1b, DM, DM); wcvt(wk1, wk1b, DM, DM);
  wcvt(wv1, wv1b, DM, DM); wcvt(wo1, wo1b, DM, DM);
  wcvt(wq2, wq2b, DM, DM); wcvt(wk2, wk2b, DM, DM);
  wcvt(wv2, wv2b, DM, DM); wcvt(wo2, wo2b, DM, DM);
  wcvt(c1w, c1wb, DM, 4 * DM); wcvt(c2w, c2wb, 4 * DM, DM);

  dim3 gsq(MR / 128, DM / 128);
  // ---- layer-1 projections (all bf16 MFMA, f32 outputs for prob path) ----
  k_gemm_mfma<0, 0><<<gsq, 256, 0, stream>>>(Tb, wq1b, bq1, W0, MR, DM, DM);
  k_gemm_mfma<0, 0><<<gsq, 256, 0, stream>>>(Tb, wk1b, bk1, W1, MR, DM, DM);
  k_gemm_mfma<0, 0><<<gsq, 256, 0, stream>>>(Tb, wv1b, bv1, W2, MR, DM, DM);

  // ---- ProbSparse ----
  k_mscore2<<<dim3(ZH * (Ls / 16) / 4), 256, 0, stream>>>(W0, W1, smp, Ms, U);
  k_topk<<<dim3(ZH), 256, 0, stream>>>(Ms, top, U);
  k_qkT<<<dim3(Uld / 64, Ls / 64, ZH), 256, 0, stream>>>(W0, W1, Sbuf, top, 0, U, Uld, U, 0.125f);
  k_softmax<<<dim3(ZH * Uld), 256, 0, stream>>>(Sbuf);
  k_pv<<<dim3(Uld / 64, 1, ZH), 256, 0, stream>>>(Sbuf, W2, upd, 0, U, Uld, Uld, 1);
  k_meanv<<<dim3(ZH), 256, 0, stream>>>(W2, mv);
  k_ctxfillb<<<dim3(MR * DM / 4 / 256), 256, 0, stream>>>(mv, Xb);  // ctx -> Xb bf16
  k_scatterb<<<dim3(ZH), 256, 0, stream>>>(upd, top, Xb, U, Uld);

  // ---- out-proj 1 + residual LN ----
  k_gemm_mfma<0, 0><<<gsq, 256, 0, stream>>>(Xb, wo1b, bo1, W0, MR, DM, DM);
  k_ln<<<dim3(MR), 256, 0, stream>>>(W0, tgt, g1, be1, nullptr, Xb); // x1 -> Xb bf16

  // ---- layer-2 projections (bf16 outputs, flash-ready layouts) ----
  k_gemm_mfma<1, 0><<<gsq, 256, 0, stream>>>(Xb, wq2b, bq2, Qb,  MR, DM, DM);
  k_gemm_mfma<2, 0><<<gsq, 256, 0, stream>>>(Mb, wk2b, bk2, Kb,  MR, DM, DM);
  k_gemm_mfma<3, 0><<<gsq, 256, 0, stream>>>(Mb, wv2b, bv2, Vtb, MR, DM, DM);

  // ---- fused flash cross attention -> Xb (bf16) ----
  k_flash<<<dim3(Ls / 64, ZH), 256, 0, stream>>>(Qb, Kb, Vtb, Xb);

  // ---- out-proj 2 + LN + FFN + final LN ----
  k_gemm_mfma<0, 0><<<gsq, 256, 0, stream>>>(Xb, wo2b, bo2, W0, MR, DM, DM);
  k_ln<<<dim3(MR), 256, 0, stream>>>(W0, nullptr, g2, be2, W1, Xb); // x2ln -> W1 f32 + Xb bf16
  k_gemm_mfma<1, 1><<<dim3(MR / 128, 4 * DM / 128), 256, 0, stream>>>(
      Xb, c1wb, c1b, hb, MR, 4 * DM, DM);
  k_gemm_mfma<0, 0><<<dim3(MR / 128, DM / 128), 256, 0, stream>>>(
      hb, c2wb, c2b, W2, MR, DM, 4 * DM);
  k_ln<<<dim3(MR), 256, 0, stream>>>(W2, W1, g3, be3, outp, nullptr); // final -> d_out
}

// Round 5
// 489.596 us; speedup vs baseline: 4.4845x; 1.1422x over previous
//
#include <hip/hip_runtime.h>
#include <hip/hip_bf16.h>
#include <cstdint>

constexpr int Bb  = 8;
constexpr int Ls  = 1024;
constexpr int DM  = 512;
constexpr int NH  = 8;
constexpr int DHd = 64;
constexpr int MR  = Bb * Ls;   // 8192 rows
constexpr int ZH  = Bb * NH;   // 64 (b,h) pairs

typedef __attribute__((ext_vector_type(8))) short short8v;
typedef __attribute__((ext_vector_type(4))) short short4v;
typedef __attribute__((ext_vector_type(4))) float floatx4;

__device__ inline short f2bf(float x) {
  __hip_bfloat16 h = __float2bfloat16(x);
  return *reinterpret_cast<short*>(&h);
}

#define GLOAD_LDS16(g, l)                                                        \
  __builtin_amdgcn_global_load_lds(                                              \
      (const __attribute__((address_space(1))) void*)(g),                        \
      (__attribute__((address_space(3))) void*)(l), 16, 0, 0)

// ================= bf16 MFMA GEMM: C = act(A @ Wt^T + bias) =================
// MODE: 0 = f32 out, 1 = bf16 out, 2 = bf16 + per-row d-slot XOR swizzle (flash K),
// 3 = bf16 transposed-per-head + key-slot swizzle (flash V).
template<int MODE, int RELU>
__global__ __launch_bounds__(256) void k_gemm_mfma(
    const __hip_bfloat16* __restrict__ A, const __hip_bfloat16* __restrict__ Wt,
    const float* __restrict__ bias, void* __restrict__ Cout,
    int M, int N, int K)
{
  __shared__ __hip_bfloat16 As[128 * 32];
  __shared__ __hip_bfloat16 Bs[128 * 32];
  const int tid = threadIdx.x;
  const int w = tid >> 6, lane = tid & 63;
  const int wr = w >> 1, wc = w & 1;
  const int bm = blockIdx.x * 128, bn = blockIdx.y * 128;
  const int lrow = lane >> 2;
  const int lcol = (lane & 3) * 8;
  const int fr = lane & 15;
  const int fco = (lane >> 4) * 8;
  const short* Ash = (const short*)As;
  const short* Bsh = (const short*)Bs;

  floatx4 acc[4][4] = {};
  for (int k0 = 0; k0 < K; k0 += 32) {
#pragma unroll
    for (int i = 0; i < 2; ++i) {
      const int chunk = w * 2 + i;
      GLOAD_LDS16(A  + (size_t)(bm + chunk * 16 + lrow) * K + k0 + lcol,
                  As + chunk * 512);
      GLOAD_LDS16(Wt + (size_t)(bn + chunk * 16 + lrow) * K + k0 + lcol,
                  Bs + chunk * 512);
    }
    __syncthreads();
    short8v a[4], b[4];
#pragma unroll
    for (int mi = 0; mi < 4; ++mi)
      a[mi] = *(const short8v*)(Ash + (wr * 64 + mi * 16 + fr) * 32 + fco);
#pragma unroll
    for (int ni = 0; ni < 4; ++ni)
      b[ni] = *(const short8v*)(Bsh + (wc * 64 + ni * 16 + fr) * 32 + fco);
#pragma unroll
    for (int mi = 0; mi < 4; ++mi)
#pragma unroll
      for (int ni = 0; ni < 4; ++ni)
        acc[mi][ni] = __builtin_amdgcn_mfma_f32_16x16x32_bf16(
            a[mi], b[ni], acc[mi][ni], 0, 0, 0);
    __syncthreads();
  }
#pragma unroll
  for (int ni = 0; ni < 4; ++ni) {
    const int cn = bn + wc * 64 + ni * 16 + fr;
    const float bv = bias[cn];
#pragma unroll
    for (int mi = 0; mi < 4; ++mi) {
#pragma unroll
      for (int j = 0; j < 4; ++j) {
        const int rm = bm + wr * 64 + mi * 16 + (lane >> 4) * 4 + j;
        float v = acc[mi][ni][j] + bv;
        if (RELU) v = fmaxf(v, 0.f);
        if (MODE == 0) {
          ((float*)Cout)[(size_t)rm * N + cn] = v;
        } else if (MODE == 1) {
          ((__hip_bfloat16*)Cout)[(size_t)rm * N + cn] = __float2bfloat16(v);
        } else if (MODE == 2) {
          const int cs = (cn & ~63) | ((cn & 63) ^ ((rm & 7) << 3));
          ((__hip_bfloat16*)Cout)[(size_t)rm * N + cs] = __float2bfloat16(v);
        } else {
          const int bb = rm >> 10, l = rm & 1023, hh = cn >> 6, dd = cn & 63;
          ((__hip_bfloat16*)Cout)[(size_t)((bb * 8 + hh) * 64 + dd) * 1024 +
                                  (l ^ ((dd & 7) << 3))] = __float2bfloat16(v);
        }
      }
    }
  }
}

// ================= fused flash cross-attention (bf16 MFMA) =================
__global__ __launch_bounds__(256) void k_flash(
    const __hip_bfloat16* __restrict__ Qb,
    const __hip_bfloat16* __restrict__ Kb,
    const __hip_bfloat16* __restrict__ Vt,
    __hip_bfloat16* __restrict__ O)
{
  __shared__ __hip_bfloat16 Ks[64 * 64];
  __shared__ __hip_bfloat16 Vs[64 * 64];
  __shared__ __hip_bfloat16 Ps[4 * 16 * 72];
  const int tid = threadIdx.x, w = tid >> 6, lane = tid & 63;
  const int g = lane >> 4, r = lane & 15;
  const int z = blockIdx.y, b = z >> 3, h = z & 7;
  const int q0 = blockIdx.x * 64 + w * 16;
  __hip_bfloat16* Pw = Ps + w * 16 * 72;

  const short8v qf0 = *(const short8v*)(Qb + (size_t)(b * Ls + q0 + r) * DM + h * DHd + g * 8);
  const short8v qf1 = *(const short8v*)(Qb + (size_t)(b * Ls + q0 + r) * DM + h * DHd + 32 + g * 8);

  floatx4 oacc[4] = {};
  float m_run = -1e30f, l_run = 0.f;

  for (int t = 0; t < 16; ++t) {
    __syncthreads();
#pragma unroll
    for (int i = 0; i < 2; ++i) {
      const int sbase = (i * 4 + w) * 64;
      const int rowi = (sbase + lane) >> 3, ds = lane & 7;
      GLOAD_LDS16(Kb + (size_t)(b * Ls + t * 64 + rowi) * DM + h * DHd + ds * 8,
                  Ks + sbase * 8);
      GLOAD_LDS16(Vt + ((size_t)z * DHd + rowi) * Ls + t * 64 + ds * 8,
                  Vs + sbase * 8);
    }
    __syncthreads();
    float sv[4][4];
    float tmax = -1e30f;
#pragma unroll
    for (int kt = 0; kt < 4; ++kt) {
      const int key = kt * 16 + r, sw = key & 7;
      short8v a0 = *(const short8v*)(Ks + key * 64 + ((g ^ sw) * 8));
      short8v a1 = *(const short8v*)(Ks + key * 64 + (((4 + g) ^ sw) * 8));
      floatx4 c = {};
      c = __builtin_amdgcn_mfma_f32_16x16x32_bf16(a0, qf0, c, 0, 0, 0);
      c = __builtin_amdgcn_mfma_f32_16x16x32_bf16(a1, qf1, c, 0, 0, 0);
#pragma unroll
      for (int j = 0; j < 4; ++j) {
        float x = c[j] * 0.125f;
        sv[kt][j] = x;
        tmax = fmaxf(tmax, x);
      }
    }
    tmax = fmaxf(tmax, __shfl_xor(tmax, 16));
    tmax = fmaxf(tmax, __shfl_xor(tmax, 32));
    const float m_new = fmaxf(m_run, tmax);
    const float fac = __expf(m_run - m_new);
    float psum = 0.f;
#pragma unroll
    for (int kt = 0; kt < 4; ++kt) {
      short4v pk;
#pragma unroll
      for (int j = 0; j < 4; ++j) {
        float p = __expf(sv[kt][j] - m_new);
        psum += p;
        pk[j] = f2bf(p);
      }
      *(short4v*)(Pw + r * 72 + kt * 16 + g * 4) = pk;
    }
    psum += __shfl_xor(psum, 16);
    psum += __shfl_xor(psum, 32);
    l_run = l_run * fac + psum;
    m_run = m_new;
    float fj[4];
#pragma unroll
    for (int j = 0; j < 4; ++j) fj[j] = __shfl(fac, (lane & 48) | (g * 4 + j));
#pragma unroll
    for (int ct = 0; ct < 4; ++ct)
#pragma unroll
      for (int j = 0; j < 4; ++j) oacc[ct][j] *= fj[j];
    const short8v pa0 = *(const short8v*)(Pw + r * 72 + g * 8);
    const short8v pa1 = *(const short8v*)(Pw + r * 72 + 32 + g * 8);
#pragma unroll
    for (int ct = 0; ct < 4; ++ct) {
      const int d = ct * 16 + r, sw = d & 7;
      short8v v0 = *(const short8v*)(Vs + d * 64 + ((g ^ sw) * 8));
      short8v v1 = *(const short8v*)(Vs + d * 64 + (((4 + g) ^ sw) * 8));
      oacc[ct] = __builtin_amdgcn_mfma_f32_16x16x32_bf16(pa0, v0, oacc[ct], 0, 0, 0);
      oacc[ct] = __builtin_amdgcn_mfma_f32_16x16x32_bf16(pa1, v1, oacc[ct], 0, 0, 0);
    }
  }
  float li[4];
#pragma unroll
  for (int j = 0; j < 4; ++j)
    li[j] = 1.0f / __shfl(l_run, (lane & 48) | (g * 4 + j));
#pragma unroll
  for (int ct = 0; ct < 4; ++ct)
#pragma unroll
    for (int j = 0; j < 4; ++j)
      O[(size_t)(b * Ls + q0 + g * 4 + j) * DM + h * DHd + ct * 16 + r] =
          __float2bfloat16(oacc[ct][j] * li[j]);
}

// ---------------- f32 -> bf16 elementwise ----------------
__global__ __launch_bounds__(256) void k_cvt(
    const float* __restrict__ in, __hip_bfloat16* __restrict__ out)
{
  const size_t i = ((size_t)blockIdx.x * 256 + threadIdx.x) * 4;
  float4 v = *reinterpret_cast<const float4*>(in + i);
  short4v o;
  o.x = f2bf(v.x); o.y = f2bf(v.y); o.z = f2bf(v.z); o.w = f2bf(v.w);
  *reinterpret_cast<short4v*>(out + i) = o;
}

// ---------------- weight convert+transpose ----------------
__global__ __launch_bounds__(256) void k_wt_cvt(
    const float* __restrict__ W, __hip_bfloat16* __restrict__ Wt, int K, int N)
{
  __shared__ float t[32][33];
  const int tid = threadIdx.x;
  const int k0 = blockIdx.x * 32, n0 = blockIdx.y * 32;
  const int r = tid >> 3, c = (tid & 7) * 4;
  float4 v = *reinterpret_cast<const float4*>(W + (size_t)(k0 + r) * N + n0 + c);
  t[r][c + 0] = v.x; t[r][c + 1] = v.y; t[r][c + 2] = v.z; t[r][c + 3] = v.w;
  __syncthreads();
  short4v o;
  o.x = f2bf(t[c + 0][r]); o.y = f2bf(t[c + 1][r]);
  o.z = f2bf(t[c + 2][r]); o.w = f2bf(t[c + 3][r]);
  *reinterpret_cast<short4v*>(Wt + (size_t)(n0 + r) * K + k0 + c) = o;
}

// ---------------- prob-path scores: S[z] = scale * Q[top] @ K^T ----------------
__global__ __launch_bounds__(256) void k_qkT(
    const float* __restrict__ Qm, const float* __restrict__ Km,
    float* __restrict__ S, const int* __restrict__ top,
    int q0, int Mrows, int Mld, int topStride, float scale)
{
  __shared__ float Qs[DHd][64 + 4];
  __shared__ float Ks[DHd][64 + 4];
  const int tid = threadIdx.x;
  const int z = blockIdx.z, b = z >> 3, h = z & 7;
  const int m0 = blockIdx.x << 6, n0 = blockIdx.y << 6;
  const float* Kbase = Km + ((size_t)(b * Ls + n0)) * DM + h * DHd;
#pragma unroll
  for (int i = 0; i < 4; ++i) {
    int idx = tid + (i << 8);
    int r = idx >> 4, c4 = (idx & 15) << 2;
    int qr;
    if (top) { int u = m0 + r; if (u >= Mrows) u = Mrows - 1; qr = top[z * topStride + u]; }
    else qr = q0 + m0 + r;
    float4 q4 = *reinterpret_cast<const float4*>(Qm + ((size_t)(b * Ls + qr)) * DM + h * DHd + c4);
    Qs[c4 + 0][r] = q4.x; Qs[c4 + 1][r] = q4.y; Qs[c4 + 2][r] = q4.z; Qs[c4 + 3][r] = q4.w;
    float4 k4 = *reinterpret_cast<const float4*>(Kbase + (size_t)r * DM + c4);
    Ks[c4 + 0][r] = k4.x; Ks[c4 + 1][r] = k4.y; Ks[c4 + 2][r] = k4.z; Ks[c4 + 3][r] = k4.w;
  }
  __syncthreads();
  const int mB = (tid >> 4) << 2, nB = (tid & 15) << 2;
  float acc[4][4] = {};
#pragma unroll
  for (int kk = 0; kk < DHd; ++kk) {
    float4 a4 = *reinterpret_cast<const float4*>(&Qs[kk][mB]);
    float4 b4 = *reinterpret_cast<const float4*>(&Ks[kk][nB]);
    const float av[4] = {a4.x, a4.y, a4.z, a4.w};
#pragma unroll
    for (int i = 0; i < 4; ++i) {
      acc[i][0] += av[i] * b4.x; acc[i][1] += av[i] * b4.y;
      acc[i][2] += av[i] * b4.z; acc[i][3] += av[i] * b4.w;
    }
  }
#pragma unroll
  for (int i = 0; i < 4; ++i) {
    int m = m0 + mB + i;
    if (m < Mrows) {
      float4 o;
      o.x = acc[i][0] * scale; o.y = acc[i][1] * scale;
      o.z = acc[i][2] * scale; o.w = acc[i][3] * scale;
      *reinterpret_cast<float4*>(S + ((size_t)z * Mld + m) * Ls + n0 + nB) = o;
    }
  }
}

// ---------------- row softmax over length 1024 (in place) ----------------
__global__ __launch_bounds__(256) void k_softmax(float* __restrict__ S)
{
  __shared__ float red[4];
  const int row = blockIdx.x, tid = threadIdx.x;
  float* p = S + (size_t)row * Ls;
  float4 v = *reinterpret_cast<float4*>(p + (tid << 2));
  float mx = fmaxf(fmaxf(v.x, v.y), fmaxf(v.z, v.w));
#pragma unroll
  for (int off = 32; off; off >>= 1) mx = fmaxf(mx, __shfl_xor(mx, off));
  if ((tid & 63) == 0) red[tid >> 6] = mx;
  __syncthreads();
  mx = fmaxf(fmaxf(red[0], red[1]), fmaxf(red[2], red[3]));
  __syncthreads();
  v.x = __expf(v.x - mx); v.y = __expf(v.y - mx);
  v.z = __expf(v.z - mx); v.w = __expf(v.w - mx);
  float s = v.x + v.y + v.z + v.w;
#pragma unroll
  for (int off = 32; off; off >>= 1) s += __shfl_xor(s, off);
  if ((tid & 63) == 0) red[tid >> 6] = s;
  __syncthreads();
  s = red[0] + red[1] + red[2] + red[3];
  float inv = 1.0f / s;
  v.x *= inv; v.y *= inv; v.z *= inv; v.w *= inv;
  *reinterpret_cast<float4*>(p + (tid << 2)) = v;
}

// ---------------- prob-path PV, K-split: partial[ks][z] = S[:,ks] @ V[ks] ----------------
// grid (16, ZH). Each block: 64 keys x (64u x 64d) partial.
__global__ __launch_bounds__(256) void k_pv_split(
    const float* __restrict__ S, const float* __restrict__ Vm,
    float* __restrict__ Pp)
{
  __shared__ float Ss[64][64];
  __shared__ float Vs[64][64];
  const int tid = threadIdx.x;
  const int ks = blockIdx.x, z = blockIdx.y, b = z >> 3, h = z & 7;
  const int k0 = ks * 64;
#pragma unroll
  for (int i = 0; i < 4; ++i) {
    const int idx = tid + (i << 8);
    const int row = idx >> 4, c4 = (idx & 15) << 2;
    *reinterpret_cast<float4*>(&Ss[row][c4]) =
        *reinterpret_cast<const float4*>(S + ((size_t)z * 64 + row) * Ls + k0 + c4);
    *reinterpret_cast<float4*>(&Vs[row][c4]) =
        *reinterpret_cast<const float4*>(Vm + ((size_t)(b * Ls + k0 + row)) * DM + h * DHd + c4);
  }
  __syncthreads();
  const int d = tid & 63, w = tid >> 6;
  float acc[16] = {};
  for (int k = 0; k < 64; ++k) {
    const float vk = Vs[k][d];
#pragma unroll
    for (int i = 0; i < 16; ++i)
      acc[i] += Ss[w * 16 + i][k] * vk;
  }
  float* outb = Pp + ((size_t)ks * ZH + z) * 4096;
#pragma unroll
  for (int i = 0; i < 16; ++i)
    outb[(w * 16 + i) * 64 + d] = acc[i];
}

// ---------------- reduce 16 PV partials -> upd ----------------
__global__ __launch_bounds__(256) void k_pv_red(
    const float* __restrict__ Pp, float* __restrict__ upd)
{
  const int z = blockIdx.x, tid = threadIdx.x;
#pragma unroll
  for (int e = tid; e < 4096; e += 256) {
    float s = 0.f;
#pragma unroll
    for (int ks = 0; ks < 16; ++ks)
      s += Pp[((size_t)ks * ZH + z) * 4096 + e];
    upd[(size_t)z * 4096 + e] = s;
  }
}

// ---------------- ProbSparse sampled scores: 16 queries/wave ----------------
__global__ __launch_bounds__(256) void k_mscore2(
    const float* __restrict__ Qm, const float* __restrict__ Km,
    const int* __restrict__ smp, float* __restrict__ Ms, int U)
{
  const int gw = blockIdx.x * 4 + (threadIdx.x >> 6);
  const int lane = threadIdx.x & 63;
  const int li = lane >> 2, dp = (lane & 3) * 16;
  const int l = (gw & 63) * 16 + li;
  const int z = gw >> 6, b = z >> 3, h = z & 7;
  const float* qb = Qm + (size_t)(b * Ls + l) * DM + h * DHd + dp;
  const float4 q0 = *(const float4*)(qb);
  const float4 q1 = *(const float4*)(qb + 4);
  const float4 q2 = *(const float4*)(qb + 8);
  const float4 q3 = *(const float4*)(qb + 12);
  float mx = -1e30f, sm = 0.f;
  for (int u = 0; u < U; ++u) {
    const int ki = smp[l * U + u];
    const float* kb = Km + (size_t)(b * Ls + ki) * DM + h * DHd + dp;
    const float4 k0 = *(const float4*)(kb);
    const float4 k1 = *(const float4*)(kb + 4);
    const float4 k2 = *(const float4*)(kb + 8);
    const float4 k3 = *(const float4*)(kb + 12);
    float d = q0.x*k0.x + q0.y*k0.y + q0.z*k0.z + q0.w*k0.w
            + q1.x*k1.x + q1.y*k1.y + q1.z*k1.z + q1.w*k1.w
            + q2.x*k2.x + q2.y*k2.y + q2.z*k2.z + q2.w*k2.w
            + q3.x*k3.x + q3.y*k3.y + q3.z*k3.z + q3.w*k3.w;
    d += __shfl_xor(d, 1);
    d += __shfl_xor(d, 2);
    mx = fmaxf(mx, d);
    sm += d;
  }
  if ((lane & 3) == 0) Ms[z * Ls + l] = mx - sm * (1.0f / Ls);
}

// ---------------- wave-parallel top-U (1 wave per z, no barriers) ----------------
// Semantics match lax.top_k: values desc, exact-equality ties -> lowest index.
__global__ __launch_bounds__(64) void k_topk_w(
    const float* __restrict__ Ms, int* __restrict__ top, int U)
{
  const int z = blockIdx.x, lane = threadIdx.x;
  float v[16];
#pragma unroll
  for (int j = 0; j < 16; ++j) v[j] = Ms[z * Ls + j * 64 + lane];
  for (int it = 0; it < U; ++it) {
    float bv = -1e30f; int bi = 0x7fffffff;
#pragma unroll
    for (int j = 0; j < 16; ++j) {
      const int idx = j * 64 + lane;
      if (v[j] > bv) { bv = v[j]; bi = idx; }   // j ascending => idx ascending; ties keep first
    }
#pragma unroll
    for (int off = 1; off < 64; off <<= 1) {
      const float ov = __shfl_xor(bv, off);
      const int   oi = __shfl_xor(bi, off);
      if (ov > bv || (ov == bv && oi < bi)) { bv = ov; bi = oi; }
    }
    if (lane == 0) top[z * U + it] = bi;
    if ((bi & 63) == lane) v[bi >> 6] = -1e30f;
  }
}

// ---------------- mean of V over keys ----------------
__global__ __launch_bounds__(256) void k_meanv(
    const float* __restrict__ Vm, float* __restrict__ mv)
{
  __shared__ float ps[4][64];
  const int z = blockIdx.x, b = z >> 3, h = z & 7;
  const int d = threadIdx.x & 63, g = threadIdx.x >> 6;
  float s = 0.f;
  for (int k = g * 256; k < (g + 1) * 256; ++k)
    s += Vm[((size_t)(b * Ls + k)) * DM + h * DHd + d];
  ps[g][d] = s;
  __syncthreads();
  if (g == 0) mv[z * 64 + d] = (ps[0][d] + ps[1][d] + ps[2][d] + ps[3][d]) * (1.0f / Ls);
}

// ---------------- broadcast mean-V into bf16 ctx ----------------
__global__ __launch_bounds__(256) void k_ctxfillb(
    const float* __restrict__ mv, __hip_bfloat16* __restrict__ ctx)
{
  const int i = blockIdx.x * 256 + threadIdx.x;
  const int c4 = (i & 127) << 2;
  const int row = i >> 7;
  const int b = row >> 10;
  const int h = c4 >> 6;
  float4 m4 = *reinterpret_cast<const float4*>(mv + ((b * 8 + h) * 64) + (c4 & 63));
  short4v o;
  o.x = f2bf(m4.x); o.y = f2bf(m4.y); o.z = f2bf(m4.z); o.w = f2bf(m4.w);
  *reinterpret_cast<short4v*>(ctx + (size_t)row * DM + c4) = o;
}

// ---------------- scatter upd rows into bf16 ctx ----------------
__global__ __launch_bounds__(256) void k_scatterb(
    const float* __restrict__ upd, const int* __restrict__ top,
    __hip_bfloat16* __restrict__ ctx, int U, int Uld)
{
  const int z = blockIdx.x, b = z >> 3, h = z & 7;
  const int d = threadIdx.x & 63;
  for (int u = threadIdx.x >> 6; u < U; u += 4) {
    int row = top[z * U + u];
    ctx[((size_t)(b * Ls + row)) * DM + h * DHd + d] =
        __float2bfloat16(upd[((size_t)z * Uld + u) * DHd + d]);
  }
}

// ---------------- fused (residual +) LayerNorm; f32 and/or bf16 outputs ----------------
__global__ __launch_bounds__(256) void k_ln(
    const float* __restrict__ x, const float* __restrict__ res,
    const float* __restrict__ g, const float* __restrict__ be,
    float* __restrict__ outf, __hip_bfloat16* __restrict__ outb)
{
  __shared__ float red[4];
  const int row = blockIdx.x, tid = threadIdx.x;
  const size_t base = (size_t)row * DM;
  float2 v = *reinterpret_cast<const float2*>(x + base + tid * 2);
  if (res) {
    float2 r2 = *reinterpret_cast<const float2*>(res + base + tid * 2);
    v.x += r2.x; v.y += r2.y;
  }
  float s = v.x + v.y;
#pragma unroll
  for (int off = 32; off; off >>= 1) s += __shfl_xor(s, off);
  if ((tid & 63) == 0) red[tid >> 6] = s;
  __syncthreads();
  s = red[0] + red[1] + red[2] + red[3];
  const float mean = s * (1.0f / DM);
  __syncthreads();
  float dx = v.x - mean, dy = v.y - mean;
  float q = dx * dx + dy * dy;
#pragma unroll
  for (int off = 32; off; off >>= 1) q += __shfl_xor(q, off);
  if ((tid & 63) == 0) red[tid >> 6] = q;
  __syncthreads();
  q = red[0] + red[1] + red[2] + red[3];
  const float inv = rsqrtf(q * (1.0f / DM) + 1e-5f);
  float2 gg = *reinterpret_cast<const float2*>(g + tid * 2);
  float2 bb = *reinterpret_cast<const float2*>(be + tid * 2);
  float ox = dx * inv * gg.x + bb.x;
  float oy = dy * inv * gg.y + bb.y;
  if (outf) {
    float2 o; o.x = ox; o.y = oy;
    *reinterpret_cast<float2*>(outf + base + tid * 2) = o;
  }
  if (outb) {
    short2 ob; ob.x = f2bf(ox); ob.y = f2bf(oy);
    *reinterpret_cast<short2*>(outb + base + tid * 2) = ob;
  }
}

extern "C" void kernel_launch(void* const* d_in, const int* in_sizes, int n_in,
                              void* d_out, int out_size, void* d_ws, size_t ws_size,
                              hipStream_t stream)
{
  const float* tgt = (const float*)d_in[0];
  const float* mem = (const float*)d_in[1];
  const int*   smp = (const int*)d_in[2];
  const float* wq1 = (const float*)d_in[3];  const float* bq1 = (const float*)d_in[4];
  const float* wk1 = (const float*)d_in[5];  const float* bk1 = (const float*)d_in[6];
  const float* wv1 = (const float*)d_in[7];  const float* bv1 = (const float*)d_in[8];
  const float* wo1 = (const float*)d_in[9];  const float* bo1 = (const float*)d_in[10];
  const float* wq2 = (const float*)d_in[11]; const float* bq2 = (const float*)d_in[12];
  const float* wk2 = (const float*)d_in[13]; const float* bk2 = (const float*)d_in[14];
  const float* wv2 = (const float*)d_in[15]; const float* bv2 = (const float*)d_in[16];
  const float* wo2 = (const float*)d_in[17]; const float* bo2 = (const float*)d_in[18];
  const float* c1w = (const float*)d_in[19]; const float* c1b = (const float*)d_in[20];
  const float* c2w = (const float*)d_in[21]; const float* c2b = (const float*)d_in[22];
  const float* g1  = (const float*)d_in[23]; const float* be1 = (const float*)d_in[24];
  const float* g2  = (const float*)d_in[25]; const float* be2 = (const float*)d_in[26];
  const float* g3  = (const float*)d_in[27]; const float* be3 = (const float*)d_in[28];
  float* outp = (float*)d_out;

  const int U   = in_sizes[2] / Ls;            // 35
  const int Uld = ((U + 63) / 64) * 64;        // 64

  char* ws = (char*)d_ws;
  const size_t SZ = (size_t)MR * DM * sizeof(float);       // 16.78 MB
  float* W0   = (float*)(ws);
  float* W1   = (float*)(ws + SZ);
  float* W2   = (float*)(ws + 2 * SZ);
  float* Sbuf = (float*)(ws + 3 * SZ);                     // 2*SZ: prob scores+partials / FFN hidden
  float* Pp   = Sbuf + (size_t)ZH * 64 * Ls;               // PV partials (16.8 MB)
  __hip_bfloat16* Tb  = (__hip_bfloat16*)(ws + 5 * SZ);    // tgt bf16; later reused as Kb
  __hip_bfloat16* Mb  = (__hip_bfloat16*)(ws + 5 * SZ + SZ / 2);
  __hip_bfloat16* Xb  = (__hip_bfloat16*)(ws + 6 * SZ);
  __hip_bfloat16* Vtb = (__hip_bfloat16*)(ws + 6 * SZ + SZ / 2);
  __hip_bfloat16* wq1b = Vtb;                // alias: dead before V2 GEMM writes Vtb
  __hip_bfloat16* wk1b = Vtb + DM * DM;
  char* tail = ws + 7 * SZ;
  __hip_bfloat16* wv1b = (__hip_bfloat16*)tail; tail += DM * DM * 2;
  __hip_bfloat16* wo1b = (__hip_bfloat16*)tail; tail += DM * DM * 2;
  __hip_bfloat16* wq2b = (__hip_bfloat16*)tail; tail += DM * DM * 2;
  __hip_bfloat16* wk2b = (__hip_bfloat16*)tail; tail += DM * DM * 2;
  __hip_bfloat16* wv2b = (__hip_bfloat16*)tail; tail += DM * DM * 2;
  __hip_bfloat16* wo2b = (__hip_bfloat16*)tail; tail += DM * DM * 2;
  __hip_bfloat16* c1wb = (__hip_bfloat16*)tail; tail += DM * 4 * DM * 2;
  __hip_bfloat16* c2wb = (__hip_bfloat16*)tail; tail += DM * 4 * DM * 2;
  float* Ms  = (float*)tail; tail += (size_t)ZH * Ls * 4;
  int*   top = (int*)tail;   tail += (size_t)ZH * Uld * 4;
  float* mv  = (float*)tail; tail += (size_t)ZH * DHd * 4;
  float* upd = (float*)tail; tail += (size_t)ZH * Uld * DHd * 4;
  __hip_bfloat16* Kb = Tb;
  __hip_bfloat16* Qb = (__hip_bfloat16*)d_out;  // parked in d_out until final LN
  __hip_bfloat16* hb = (__hip_bfloat16*)Sbuf;

  auto wcvt = [&](const float* Wm, __hip_bfloat16* Wt, int K, int N) {
    k_wt_cvt<<<dim3(K / 32, N / 32), 256, 0, stream>>>(Wm, Wt, K, N);
  };

  // ---- one-time converts ----
  k_cvt<<<dim3(MR * DM / 4 / 256), 256, 0, stream>>>(tgt, Tb);
  k_cvt<<<dim3(MR * DM / 4 / 256), 256, 0, stream>>>(mem, Mb);
  wcvt(wq1, wq1b, DM, DM); wcvt(wk1, wk1b, DM, DM);
  wcvt(wv1, wv1b, DM, DM); wcvt(wo1, wo1b, DM, DM);
  wcvt(wq2, wq2b, DM, DM); wcvt(wk2, wk2b, DM, DM);
  wcvt(wv2, wv2b, DM, DM); wcvt(wo2, wo2b, DM, DM);
  wcvt(c1w, c1wb, DM, 4 * DM); wcvt(c2w, c2wb, 4 * DM, DM);

  dim3 gsq(MR / 128, DM / 128);
  // ---- layer-1 projections (bf16 MFMA, f32 outputs for prob path) ----
  k_gemm_mfma<0, 0><<<gsq, 256, 0, stream>>>(Tb, wq1b, bq1, W0, MR, DM, DM);
  k_gemm_mfma<0, 0><<<gsq, 256, 0, stream>>>(Tb, wk1b, bk1, W1, MR, DM, DM);
  k_gemm_mfma<0, 0><<<gsq, 256, 0, stream>>>(Tb, wv1b, bv1, W2, MR, DM, DM);

  // ---- ProbSparse ----
  k_mscore2<<<dim3(ZH * (Ls / 16) / 4), 256, 0, stream>>>(W0, W1, smp, Ms, U);
  k_topk_w<<<dim3(ZH), 64, 0, stream>>>(Ms, top, U);
  k_qkT<<<dim3(Uld / 64, Ls / 64, ZH), 256, 0, stream>>>(W0, W1, Sbuf, top, 0, U, Uld, U, 0.125f);
  k_softmax<<<dim3(ZH * Uld), 256, 0, stream>>>(Sbuf);
  k_pv_split<<<dim3(16, ZH), 256, 0, stream>>>(Sbuf, W2, Pp);
  k_pv_red<<<dim3(ZH), 256, 0, stream>>>(Pp, upd);
  k_meanv<<<dim3(ZH), 256, 0, stream>>>(W2, mv);
  k_ctxfillb<<<dim3(MR * DM / 4 / 256), 256, 0, stream>>>(mv, Xb);  // ctx -> Xb bf16
  k_scatterb<<<dim3(ZH), 256, 0, stream>>>(upd, top, Xb, U, Uld);

  // ---- out-proj 1 + residual LN ----
  k_gemm_mfma<0, 0><<<gsq, 256, 0, stream>>>(Xb, wo1b, bo1, W0, MR, DM, DM);
  k_ln<<<dim3(MR), 256, 0, stream>>>(W0, tgt, g1, be1, nullptr, Xb); // x1 -> Xb bf16

  // ---- layer-2 projections (bf16 outputs, flash-ready layouts) ----
  k_gemm_mfma<1, 0><<<gsq, 256, 0, stream>>>(Xb, wq2b, bq2, Qb,  MR, DM, DM);
  k_gemm_mfma<2, 0><<<gsq, 256, 0, stream>>>(Mb, wk2b, bk2, Kb,  MR, DM, DM);
  k_gemm_mfma<3, 0><<<gsq, 256, 0, stream>>>(Mb, wv2b, bv2, Vtb, MR, DM, DM);

  // ---- fused flash cross attention -> Xb (bf16) ----
  k_flash<<<dim3(Ls / 64, ZH), 256, 0, stream>>>(Qb, Kb, Vtb, Xb);

  // ---- out-proj 2 + LN + FFN + final LN ----
  k_gemm_mfma<0, 0><<<gsq, 256, 0, stream>>>(Xb, wo2b, bo2, W0, MR, DM, DM);
  k_ln<<<dim3(MR), 256, 0, stream>>>(W0, nullptr, g2, be2, W1, Xb); // x2ln -> W1 f32 + Xb bf16
  k_gemm_mfma<1, 1><<<dim3(MR / 128, 4 * DM / 128), 256, 0, stream>>>(
      Xb, c1wb, c1b, hb, MR, 4 * DM, DM);
  k_gemm_mfma<0, 0><<<dim3(MR / 128, DM / 128), 256, 0, stream>>>(
      hb, c2wb, c2b, W2, MR, DM, 4 * DM);
  k_ln<<<dim3(MR), 256, 0, stream>>>(W2, W1, g3, be3, outp, nullptr); // final -> d_out
}

// Round 6
// 419.593 us; speedup vs baseline: 5.2326x; 1.1668x over previous
//
#include <hip/hip_runtime.h>
#include <hip/hip_bf16.h>
#include <cstdint>

constexpr int Bb  = 8;
constexpr int Ls  = 1024;
constexpr int DM  = 512;
constexpr int NH  = 8;
constexpr int DHd = 64;
constexpr int MR  = Bb * Ls;   // 8192 rows
constexpr int ZH  = Bb * NH;   // 64 (b,h) pairs

typedef __attribute__((ext_vector_type(8))) short short8v;
typedef __attribute__((ext_vector_type(4))) short short4v;
typedef __attribute__((ext_vector_type(4))) float floatx4;

__device__ inline short f2bf(float x) {
  __hip_bfloat16 h = __float2bfloat16(x);
  return *reinterpret_cast<short*>(&h);
}

#define GLOAD_LDS16(g, l)                                                        \
  __builtin_amdgcn_global_load_lds(                                              \
      (const __attribute__((address_space(1))) void*)(g),                        \
      (__attribute__((address_space(3))) void*)(l), 16, 0, 0)

// ================= bf16 MFMA GEMM: C = act(A @ Wt^T + bias) =================
// MODE: 0 f32 out | 1 bf16 out | 2 bf16 K-swizzle | 3 bf16 V-transpose |
// 10 L1 triple (N=1536: Q->Qz compact, K->Kz compact, V->merged f32) |
// 11 L2 KV pair (N=1024: K->Kb swizzled, V->Vt transposed)
template<int MODE, int RELU>
__global__ __launch_bounds__(256) void k_gemm_mfma(
    const __hip_bfloat16* __restrict__ A, const __hip_bfloat16* __restrict__ Wt,
    const float* __restrict__ bias, const float* __restrict__ bias1,
    const float* __restrict__ bias2,
    void* __restrict__ Cout, void* __restrict__ aux1, void* __restrict__ aux2,
    int M, int N, int K)
{
  __shared__ __hip_bfloat16 As[128 * 32];
  __shared__ __hip_bfloat16 Bs[128 * 32];
  const int tid = threadIdx.x;
  const int w = tid >> 6, lane = tid & 63;
  const int wr = w >> 1, wc = w & 1;
  const int bm = blockIdx.x * 128, bn = blockIdx.y * 128;
  const int lrow = lane >> 2;
  const int lcol = (lane & 3) * 8;
  const int fr = lane & 15;
  const int fco = (lane >> 4) * 8;
  const short* Ash = (const short*)As;
  const short* Bsh = (const short*)Bs;

  floatx4 acc[4][4] = {};
  for (int k0 = 0; k0 < K; k0 += 32) {
#pragma unroll
    for (int i = 0; i < 2; ++i) {
      const int chunk = w * 2 + i;
      GLOAD_LDS16(A  + (size_t)(bm + chunk * 16 + lrow) * K + k0 + lcol,
                  As + chunk * 512);
      GLOAD_LDS16(Wt + (size_t)(bn + chunk * 16 + lrow) * K + k0 + lcol,
                  Bs + chunk * 512);
    }
    __syncthreads();
    short8v a[4], b[4];
#pragma unroll
    for (int mi = 0; mi < 4; ++mi)
      a[mi] = *(const short8v*)(Ash + (wr * 64 + mi * 16 + fr) * 32 + fco);
#pragma unroll
    for (int ni = 0; ni < 4; ++ni)
      b[ni] = *(const short8v*)(Bsh + (wc * 64 + ni * 16 + fr) * 32 + fco);
#pragma unroll
    for (int mi = 0; mi < 4; ++mi)
#pragma unroll
      for (int ni = 0; ni < 4; ++ni)
        acc[mi][ni] = __builtin_amdgcn_mfma_f32_16x16x32_bf16(
            a[mi], b[ni], acc[mi][ni], 0, 0, 0);
    __syncthreads();
  }
#pragma unroll
  for (int ni = 0; ni < 4; ++ni) {
    const int cn = bn + wc * 64 + ni * 16 + fr;
    float bv;
    if (MODE == 10) {
      const float* bp = (cn < 512) ? bias : (cn < 1024 ? bias1 : bias2);
      bv = bp[cn & 511];
    } else if (MODE == 11) {
      bv = (cn < 512 ? bias : bias1)[cn & 511];
    } else {
      bv = bias[cn];
    }
#pragma unroll
    for (int mi = 0; mi < 4; ++mi) {
#pragma unroll
      for (int j = 0; j < 4; ++j) {
        const int rm = bm + wr * 64 + mi * 16 + (lane >> 4) * 4 + j;
        float v = acc[mi][ni][j] + bv;
        if (RELU) v = fmaxf(v, 0.f);
        if (MODE == 0) {
          ((float*)Cout)[(size_t)rm * N + cn] = v;
        } else if (MODE == 1) {
          ((__hip_bfloat16*)Cout)[(size_t)rm * N + cn] = __float2bfloat16(v);
        } else if (MODE == 2) {
          const int cs = (cn & ~63) | ((cn & 63) ^ ((rm & 7) << 3));
          ((__hip_bfloat16*)Cout)[(size_t)rm * N + cs] = __float2bfloat16(v);
        } else if (MODE == 3) {
          const int bb = rm >> 10, l = rm & 1023, hh = cn >> 6, dd = cn & 63;
          ((__hip_bfloat16*)Cout)[(size_t)((bb * 8 + hh) * 64 + dd) * 1024 +
                                  (l ^ ((dd & 7) << 3))] = __float2bfloat16(v);
        } else if (MODE == 10) {
          const int sel = cn >> 9, c = cn & 511;
          if (sel == 2) {
            ((float*)aux2)[(size_t)rm * 512 + c] = v;
          } else {
            float* base = sel ? (float*)aux1 : (float*)Cout;
            const int bb = rm >> 10, l = rm & 1023, hh = c >> 6, dd = c & 63;
            base[(((size_t)(bb * 8 + hh)) * 1024 + l) * 64 + dd] = v;
          }
        } else if (MODE == 11) {
          const int c = cn & 511;
          if (cn < 512) {
            const int cs = (c & ~63) | ((c & 63) ^ ((rm & 7) << 3));
            ((__hip_bfloat16*)Cout)[(size_t)rm * 512 + cs] = __float2bfloat16(v);
          } else {
            const int bb = rm >> 10, l = rm & 1023, hh = c >> 6, dd = c & 63;
            ((__hip_bfloat16*)aux1)[(size_t)((bb * 8 + hh) * 64 + dd) * 1024 +
                                    (l ^ ((dd & 7) << 3))] = __float2bfloat16(v);
          }
        }
      }
    }
  }
}

// ================= fused flash cross-attention (bf16 MFMA) =================
__global__ __launch_bounds__(256) void k_flash(
    const __hip_bfloat16* __restrict__ Qb,
    const __hip_bfloat16* __restrict__ Kb,
    const __hip_bfloat16* __restrict__ Vt,
    __hip_bfloat16* __restrict__ O)
{
  __shared__ __hip_bfloat16 Ks[64 * 64];
  __shared__ __hip_bfloat16 Vs[64 * 64];
  __shared__ __hip_bfloat16 Ps[4 * 16 * 72];
  const int tid = threadIdx.x, w = tid >> 6, lane = tid & 63;
  const int g = lane >> 4, r = lane & 15;
  const int z = blockIdx.y, b = z >> 3, h = z & 7;
  const int q0 = blockIdx.x * 64 + w * 16;
  __hip_bfloat16* Pw = Ps + w * 16 * 72;

  const short8v qf0 = *(const short8v*)(Qb + (size_t)(b * Ls + q0 + r) * DM + h * DHd + g * 8);
  const short8v qf1 = *(const short8v*)(Qb + (size_t)(b * Ls + q0 + r) * DM + h * DHd + 32 + g * 8);

  floatx4 oacc[4] = {};
  float m_run = -1e30f, l_run = 0.f;

  for (int t = 0; t < 16; ++t) {
    __syncthreads();
#pragma unroll
    for (int i = 0; i < 2; ++i) {
      const int sbase = (i * 4 + w) * 64;
      const int rowi = (sbase + lane) >> 3, ds = lane & 7;
      GLOAD_LDS16(Kb + (size_t)(b * Ls + t * 64 + rowi) * DM + h * DHd + ds * 8,
                  Ks + sbase * 8);
      GLOAD_LDS16(Vt + ((size_t)z * DHd + rowi) * Ls + t * 64 + ds * 8,
                  Vs + sbase * 8);
    }
    __syncthreads();
    float sv[4][4];
    float tmax = -1e30f;
#pragma unroll
    for (int kt = 0; kt < 4; ++kt) {
      const int key = kt * 16 + r, sw = key & 7;
      short8v a0 = *(const short8v*)(Ks + key * 64 + ((g ^ sw) * 8));
      short8v a1 = *(const short8v*)(Ks + key * 64 + (((4 + g) ^ sw) * 8));
      floatx4 c = {};
      c = __builtin_amdgcn_mfma_f32_16x16x32_bf16(a0, qf0, c, 0, 0, 0);
      c = __builtin_amdgcn_mfma_f32_16x16x32_bf16(a1, qf1, c, 0, 0, 0);
#pragma unroll
      for (int j = 0; j < 4; ++j) {
        float x = c[j] * 0.125f;
        sv[kt][j] = x;
        tmax = fmaxf(tmax, x);
      }
    }
    tmax = fmaxf(tmax, __shfl_xor(tmax, 16));
    tmax = fmaxf(tmax, __shfl_xor(tmax, 32));
    const float m_new = fmaxf(m_run, tmax);
    const float fac = __expf(m_run - m_new);
    float psum = 0.f;
#pragma unroll
    for (int kt = 0; kt < 4; ++kt) {
      short4v pk;
#pragma unroll
      for (int j = 0; j < 4; ++j) {
        float p = __expf(sv[kt][j] - m_new);
        psum += p;
        pk[j] = f2bf(p);
      }
      *(short4v*)(Pw + r * 72 + kt * 16 + g * 4) = pk;
    }
    psum += __shfl_xor(psum, 16);
    psum += __shfl_xor(psum, 32);
    l_run = l_run * fac + psum;
    m_run = m_new;
    float fj[4];
#pragma unroll
    for (int j = 0; j < 4; ++j) fj[j] = __shfl(fac, (lane & 48) | (g * 4 + j));
#pragma unroll
    for (int ct = 0; ct < 4; ++ct)
#pragma unroll
      for (int j = 0; j < 4; ++j) oacc[ct][j] *= fj[j];
    const short8v pa0 = *(const short8v*)(Pw + r * 72 + g * 8);
    const short8v pa1 = *(const short8v*)(Pw + r * 72 + 32 + g * 8);
#pragma unroll
    for (int ct = 0; ct < 4; ++ct) {
      const int d = ct * 16 + r, sw = d & 7;
      short8v v0 = *(const short8v*)(Vs + d * 64 + ((g ^ sw) * 8));
      short8v v1 = *(const short8v*)(Vs + d * 64 + (((4 + g) ^ sw) * 8));
      oacc[ct] = __builtin_amdgcn_mfma_f32_16x16x32_bf16(pa0, v0, oacc[ct], 0, 0, 0);
      oacc[ct] = __builtin_amdgcn_mfma_f32_16x16x32_bf16(pa1, v1, oacc[ct], 0, 0, 0);
    }
  }
  float li[4];
#pragma unroll
  for (int j = 0; j < 4; ++j)
    li[j] = 1.0f / __shfl(l_run, (lane & 48) | (g * 4 + j));
#pragma unroll
  for (int ct = 0; ct < 4; ++ct)
#pragma unroll
    for (int j = 0; j < 4; ++j)
      O[(size_t)(b * Ls + q0 + g * 4 + j) * DM + h * DHd + ct * 16 + r] =
          __float2bfloat16(oacc[ct][j] * li[j]);
}

// ---------------- f32 -> bf16 elementwise ----------------
__global__ __launch_bounds__(256) void k_cvt(
    const float* __restrict__ in, __hip_bfloat16* __restrict__ out)
{
  const size_t i = ((size_t)blockIdx.x * 256 + threadIdx.x) * 4;
  float4 v = *reinterpret_cast<const float4*>(in + i);
  short4v o;
  o.x = f2bf(v.x); o.y = f2bf(v.y); o.z = f2bf(v.z); o.w = f2bf(v.w);
  *reinterpret_cast<short4v*>(out + i) = o;
}

// ---------------- weight convert+transpose ----------------
__global__ __launch_bounds__(256) void k_wt_cvt(
    const float* __restrict__ W, __hip_bfloat16* __restrict__ Wt, int K, int N)
{
  __shared__ float t[32][33];
  const int tid = threadIdx.x;
  const int k0 = blockIdx.x * 32, n0 = blockIdx.y * 32;
  const int r = tid >> 3, c = (tid & 7) * 4;
  float4 v = *reinterpret_cast<const float4*>(W + (size_t)(k0 + r) * N + n0 + c);
  t[r][c + 0] = v.x; t[r][c + 1] = v.y; t[r][c + 2] = v.z; t[r][c + 3] = v.w;
  __syncthreads();
  short4v o;
  o.x = f2bf(t[c + 0][r]); o.y = f2bf(t[c + 1][r]);
  o.z = f2bf(t[c + 2][r]); o.w = f2bf(t[c + 3][r]);
  *reinterpret_cast<short4v*>(Wt + (size_t)(n0 + r) * K + k0 + c) = o;
}

// ---------------- prob-path scores (compact per-z Q/K, XCD-swizzled grid) ----------------
// grid: 16*ZH 1-D. S[z][u][1024] = scale * Qz[top[u]] . Kz[key]
__global__ __launch_bounds__(256) void k_qkT(
    const float* __restrict__ Qz, const float* __restrict__ Kz,
    float* __restrict__ S, const int* __restrict__ top,
    int Mrows, int topStride, float scale)
{
  __shared__ float Qs[DHd][64 + 4];
  __shared__ float Ks[DHd][64 + 4];
  const int bid = blockIdx.x;
  const int swz = (bid & 7) * ((16 * ZH) >> 3) + (bid >> 3);
  const int z = swz >> 4, n0 = (swz & 15) << 6;
  const int tid = threadIdx.x;
#pragma unroll
  for (int i = 0; i < 4; ++i) {
    int idx = tid + (i << 8);
    int r = idx >> 4, c4 = (idx & 15) << 2;
    int u = r; if (u >= Mrows) u = Mrows - 1;
    const int qr = top[z * topStride + u];
    float4 q4 = *reinterpret_cast<const float4*>(Qz + ((size_t)z * Ls + qr) * 64 + c4);
    Qs[c4 + 0][r] = q4.x; Qs[c4 + 1][r] = q4.y; Qs[c4 + 2][r] = q4.z; Qs[c4 + 3][r] = q4.w;
    float4 k4 = *reinterpret_cast<const float4*>(Kz + ((size_t)z * Ls + n0 + r) * 64 + c4);
    Ks[c4 + 0][r] = k4.x; Ks[c4 + 1][r] = k4.y; Ks[c4 + 2][r] = k4.z; Ks[c4 + 3][r] = k4.w;
  }
  __syncthreads();
  const int mB = (tid >> 4) << 2, nB = (tid & 15) << 2;
  float acc[4][4] = {};
#pragma unroll
  for (int kk = 0; kk < DHd; ++kk) {
    float4 a4 = *reinterpret_cast<const float4*>(&Qs[kk][mB]);
    float4 b4 = *reinterpret_cast<const float4*>(&Ks[kk][nB]);
    const float av[4] = {a4.x, a4.y, a4.z, a4.w};
#pragma unroll
    for (int i = 0; i < 4; ++i) {
      acc[i][0] += av[i] * b4.x; acc[i][1] += av[i] * b4.y;
      acc[i][2] += av[i] * b4.z; acc[i][3] += av[i] * b4.w;
    }
  }
#pragma unroll
  for (int i = 0; i < 4; ++i) {
    int m = mB + i;
    if (m < Mrows) {
      float4 o;
      o.x = acc[i][0] * scale; o.y = acc[i][1] * scale;
      o.z = acc[i][2] * scale; o.w = acc[i][3] * scale;
      *reinterpret_cast<float4*>(S + ((size_t)z * 64 + m) * Ls + n0 + nB) = o;
    }
  }
}

// ---------------- row softmax over length 1024 (in place) ----------------
__global__ __launch_bounds__(256) void k_softmax(float* __restrict__ S)
{
  __shared__ float red[4];
  const int row = blockIdx.x, tid = threadIdx.x;
  float* p = S + (size_t)row * Ls;
  float4 v = *reinterpret_cast<float4*>(p + (tid << 2));
  float mx = fmaxf(fmaxf(v.x, v.y), fmaxf(v.z, v.w));
#pragma unroll
  for (int off = 32; off; off >>= 1) mx = fmaxf(mx, __shfl_xor(mx, off));
  if ((tid & 63) == 0) red[tid >> 6] = mx;
  __syncthreads();
  mx = fmaxf(fmaxf(red[0], red[1]), fmaxf(red[2], red[3]));
  __syncthreads();
  v.x = __expf(v.x - mx); v.y = __expf(v.y - mx);
  v.z = __expf(v.z - mx); v.w = __expf(v.w - mx);
  float s = v.x + v.y + v.z + v.w;
#pragma unroll
  for (int off = 32; off; off >>= 1) s += __shfl_xor(s, off);
  if ((tid & 63) == 0) red[tid >> 6] = s;
  __syncthreads();
  s = red[0] + red[1] + red[2] + red[3];
  float inv = 1.0f / s;
  v.x *= inv; v.y *= inv; v.z *= inv; v.w *= inv;
  *reinterpret_cast<float4*>(p + (tid << 2)) = v;
}

// ---------------- prob-path PV, K-split (XCD-swizzled 1-D grid) ----------------
__global__ __launch_bounds__(256) void k_pv_split(
    const float* __restrict__ S, const float* __restrict__ Vm,
    float* __restrict__ Pp)
{
  __shared__ float Ss[64][64];
  __shared__ float Vs[64][64];
  const int bid = blockIdx.x;
  const int swz = (bid & 7) * ((16 * ZH) >> 3) + (bid >> 3);
  const int ks = swz & 15, z = swz >> 4, b = z >> 3, h = z & 7;
  const int tid = threadIdx.x;
  const int k0 = ks * 64;
#pragma unroll
  for (int i = 0; i < 4; ++i) {
    const int idx = tid + (i << 8);
    const int row = idx >> 4, c4 = (idx & 15) << 2;
    *reinterpret_cast<float4*>(&Ss[row][c4]) =
        *reinterpret_cast<const float4*>(S + ((size_t)z * 64 + row) * Ls + k0 + c4);
    *reinterpret_cast<float4*>(&Vs[row][c4]) =
        *reinterpret_cast<const float4*>(Vm + ((size_t)(b * Ls + k0 + row)) * DM + h * DHd + c4);
  }
  __syncthreads();
  const int d = tid & 63, w = tid >> 6;
  float acc[16] = {};
  for (int k = 0; k < 64; ++k) {
    const float vk = Vs[k][d];
#pragma unroll
    for (int i = 0; i < 16; ++i)
      acc[i] += Ss[w * 16 + i][k] * vk;
  }
  float* outb = Pp + ((size_t)ks * ZH + z) * 4096;
#pragma unroll
  for (int i = 0; i < 16; ++i)
    outb[(w * 16 + i) * 64 + d] = acc[i];
}

// ---------------- reduce 16 PV partials -> upd ----------------
__global__ __launch_bounds__(256) void k_pv_red(
    const float* __restrict__ Pp, float* __restrict__ upd)
{
  const int z = blockIdx.x, tid = threadIdx.x;
#pragma unroll
  for (int e = tid; e < 4096; e += 256) {
    float s = 0.f;
#pragma unroll
    for (int ks = 0; ks < 16; ++ks)
      s += Pp[((size_t)ks * ZH + z) * 4096 + e];
    upd[(size_t)z * 4096 + e] = s;
  }
}

// ---------------- ProbSparse sampled scores, compact layout, full unroll ----------------
// 16 queries/wave, 4 lanes each. grid 1024 1-D, XCD-swizzled.
template<int UU>
__global__ __launch_bounds__(256) void k_mscore3(
    const float* __restrict__ Qz, const float* __restrict__ Kz,
    const int* __restrict__ smp, float* __restrict__ Ms)
{
  const int bid = blockIdx.x;
  const int swz = (bid & 7) * 128 + (bid >> 3);
  const int gw = swz * 4 + (threadIdx.x >> 6);
  const int lane = threadIdx.x & 63;
  const int li = lane >> 2, dp = (lane & 3) * 16;
  const int l = (gw & 63) * 16 + li;
  const int z = gw >> 6;
  const float* qb = Qz + ((size_t)z * Ls + l) * 64 + dp;
  const float4 q0 = *(const float4*)(qb);
  const float4 q1 = *(const float4*)(qb + 4);
  const float4 q2 = *(const float4*)(qb + 8);
  const float4 q3 = *(const float4*)(qb + 12);
  int kidx[UU];
#pragma unroll
  for (int u = 0; u < UU; ++u) kidx[u] = smp[l * UU + u];
  const float* kzb = Kz + (size_t)z * Ls * 64 + dp;
  float mx = -1e30f, sm = 0.f;
#pragma unroll
  for (int u = 0; u < UU; ++u) {
    const float* kb = kzb + (size_t)kidx[u] * 64;
    const float4 k0 = *(const float4*)(kb);
    const float4 k1 = *(const float4*)(kb + 4);
    const float4 k2 = *(const float4*)(kb + 8);
    const float4 k3 = *(const float4*)(kb + 12);
    float d = q0.x*k0.x + q0.y*k0.y + q0.z*k0.z + q0.w*k0.w
            + q1.x*k1.x + q1.y*k1.y + q1.z*k1.z + q1.w*k1.w
            + q2.x*k2.x + q2.y*k2.y + q2.z*k2.z + q2.w*k2.w
            + q3.x*k3.x + q3.y*k3.y + q3.z*k3.z + q3.w*k3.w;
    d += __shfl_xor(d, 1);
    d += __shfl_xor(d, 2);
    mx = fmaxf(mx, d);
    sm += d;
  }
  if ((lane & 3) == 0) Ms[z * Ls + l] = mx - sm * (1.0f / Ls);
}

// runtime-U fallback (same math)
__global__ __launch_bounds__(256) void k_mscore3g(
    const float* __restrict__ Qz, const float* __restrict__ Kz,
    const int* __restrict__ smp, float* __restrict__ Ms, int U)
{
  const int bid = blockIdx.x;
  const int swz = (bid & 7) * 128 + (bid >> 3);
  const int gw = swz * 4 + (threadIdx.x >> 6);
  const int lane = threadIdx.x & 63;
  const int li = lane >> 2, dp = (lane & 3) * 16;
  const int l = (gw & 63) * 16 + li;
  const int z = gw >> 6;
  const float* qb = Qz + ((size_t)z * Ls + l) * 64 + dp;
  const float4 q0 = *(const float4*)(qb);
  const float4 q1 = *(const float4*)(qb + 4);
  const float4 q2 = *(const float4*)(qb + 8);
  const float4 q3 = *(const float4*)(qb + 12);
  const float* kzb = Kz + (size_t)z * Ls * 64 + dp;
  float mx = -1e30f, sm = 0.f;
  for (int u = 0; u < U; ++u) {
    const float* kb = kzb + (size_t)smp[l * U + u] * 64;
    const float4 k0 = *(const float4*)(kb);
    const float4 k1 = *(const float4*)(kb + 4);
    const float4 k2 = *(const float4*)(kb + 8);
    const float4 k3 = *(const float4*)(kb + 12);
    float d = q0.x*k0.x + q0.y*k0.y + q0.z*k0.z + q0.w*k0.w
            + q1.x*k1.x + q1.y*k1.y + q1.z*k1.z + q1.w*k1.w
            + q2.x*k2.x + q2.y*k2.y + q2.z*k2.z + q2.w*k2.w
            + q3.x*k3.x + q3.y*k3.y + q3.z*k3.z + q3.w*k3.w;
    d += __shfl_xor(d, 1);
    d += __shfl_xor(d, 2);
    mx = fmaxf(mx, d);
    sm += d;
  }
  if ((lane & 3) == 0) Ms[z * Ls + l] = mx - sm * (1.0f / Ls);
}

// ---------------- wave-parallel top-U (1 wave per z) ----------------
__global__ __launch_bounds__(64) void k_topk_w(
    const float* __restrict__ Ms, int* __restrict__ top, int U)
{
  const int z = blockIdx.x, lane = threadIdx.x;
  float v[16];
#pragma unroll
  for (int j = 0; j < 16; ++j) v[j] = Ms[z * Ls + j * 64 + lane];
  for (int it = 0; it < U; ++it) {
    float bv = -1e30f; int bi = 0x7fffffff;
#pragma unroll
    for (int j = 0; j < 16; ++j) {
      const int idx = j * 64 + lane;
      if (v[j] > bv) { bv = v[j]; bi = idx; }
    }
#pragma unroll
    for (int off = 1; off < 64; off <<= 1) {
      const float ov = __shfl_xor(bv, off);
      const int   oi = __shfl_xor(bi, off);
      if (ov > bv || (ov == bv && oi < bi)) { bv = ov; bi = oi; }
    }
    if (lane == 0) top[z * U + it] = bi;
    if ((bi & 63) == lane) v[bi >> 6] = -1e30f;
  }
}

// ---------------- mean of V: stage 1 (grid ZH*8, 128 keys each) ----------------
__global__ __launch_bounds__(256) void k_meanv1(
    const float* __restrict__ Vm, float* __restrict__ mvp)
{
  __shared__ float ps[4][64];
  const int gid = blockIdx.x, z = gid >> 3, c = gid & 7, b = z >> 3, h = z & 7;
  const int d = threadIdx.x & 63, g = threadIdx.x >> 6;
  float s = 0.f;
  const int kb = c * 128 + g * 32;
  for (int k = kb; k < kb + 32; ++k)
    s += Vm[((size_t)(b * Ls + k)) * DM + h * DHd + d];
  ps[g][d] = s;
  __syncthreads();
  if (g == 0) mvp[(z * 8 + c) * 64 + d] = ps[0][d] + ps[1][d] + ps[2][d] + ps[3][d];
}

// ---------------- broadcast mean-V into bf16 ctx (folds stage-2 reduce) ----------------
__global__ __launch_bounds__(256) void k_ctxfillb(
    const float* __restrict__ mvp, __hip_bfloat16* __restrict__ ctx)
{
  const int i = blockIdx.x * 256 + threadIdx.x;
  const int c4 = (i & 127) << 2;
  const int row = i >> 7;
  const int b = row >> 10;
  const int h = c4 >> 6;
  const float* base = mvp + ((b * 8 + h) * 8) * 64 + (c4 & 63);
  float4 a = {0.f, 0.f, 0.f, 0.f};
#pragma unroll
  for (int c = 0; c < 8; ++c) {
    float4 m4 = *reinterpret_cast<const float4*>(base + c * 64);
    a.x += m4.x; a.y += m4.y; a.z += m4.z; a.w += m4.w;
  }
  const float inv = 1.0f / Ls;
  short4v o;
  o.x = f2bf(a.x * inv); o.y = f2bf(a.y * inv);
  o.z = f2bf(a.z * inv); o.w = f2bf(a.w * inv);
  *reinterpret_cast<short4v*>(ctx + (size_t)row * DM + c4) = o;
}

// ---------------- scatter upd rows into bf16 ctx ----------------
__global__ __launch_bounds__(256) void k_scatterb(
    const float* __restrict__ upd, const int* __restrict__ top,
    __hip_bfloat16* __restrict__ ctx, int U, int Uld)
{
  const int z = blockIdx.x, b = z >> 3, h = z & 7;
  const int d = threadIdx.x & 63;
  for (int u = threadIdx.x >> 6; u < U; u += 4) {
    int row = top[z * U + u];
    ctx[((size_t)(b * Ls + row)) * DM + h * DHd + d] =
        __float2bfloat16(upd[((size_t)z * Uld + u) * DHd + d]);
  }
}

// ---------------- fused (residual +) LayerNorm; f32 and/or bf16 outputs ----------------
__global__ __launch_bounds__(256) void k_ln(
    const float* __restrict__ x, const float* __restrict__ res,
    const float* __restrict__ g, const float* __restrict__ be,
    float* __restrict__ outf, __hip_bfloat16* __restrict__ outb)
{
  __shared__ float red[4];
  const int row = blockIdx.x, tid = threadIdx.x;
  const size_t base = (size_t)row * DM;
  float2 v = *reinterpret_cast<const float2*>(x + base + tid * 2);
  if (res) {
    float2 r2 = *reinterpret_cast<const float2*>(res + base + tid * 2);
    v.x += r2.x; v.y += r2.y;
  }
  float s = v.x + v.y;
#pragma unroll
  for (int off = 32; off; off >>= 1) s += __shfl_xor(s, off);
  if ((tid & 63) == 0) red[tid >> 6] = s;
  __syncthreads();
  s = red[0] + red[1] + red[2] + red[3];
  const float mean = s * (1.0f / DM);
  __syncthreads();
  float dx = v.x - mean, dy = v.y - mean;
  float q = dx * dx + dy * dy;
#pragma unroll
  for (int off = 32; off; off >>= 1) q += __shfl_xor(q, off);
  if ((tid & 63) == 0) red[tid >> 6] = q;
  __syncthreads();
  q = red[0] + red[1] + red[2] + red[3];
  const float inv = rsqrtf(q * (1.0f / DM) + 1e-5f);
  float2 gg = *reinterpret_cast<const float2*>(g + tid * 2);
  float2 bb = *reinterpret_cast<const float2*>(be + tid * 2);
  float ox = dx * inv * gg.x + bb.x;
  float oy = dy * inv * gg.y + bb.y;
  if (outf) {
    float2 o; o.x = ox; o.y = oy;
    *reinterpret_cast<float2*>(outf + base + tid * 2) = o;
  }
  if (outb) {
    short2 ob; ob.x = f2bf(ox); ob.y = f2bf(oy);
    *reinterpret_cast<short2*>(outb + base + tid * 2) = ob;
  }
}

extern "C" void kernel_launch(void* const* d_in, const int* in_sizes, int n_in,
                              void* d_out, int out_size, void* d_ws, size_t ws_size,
                              hipStream_t stream)
{
  const float* tgt = (const float*)d_in[0];
  const float* mem = (const float*)d_in[1];
  const int*   smp = (const int*)d_in[2];
  const float* wq1 = (const float*)d_in[3];  const float* bq1 = (const float*)d_in[4];
  const float* wk1 = (const float*)d_in[5];  const float* bk1 = (const float*)d_in[6];
  const float* wv1 = (const float*)d_in[7];  const float* bv1 = (const float*)d_in[8];
  const float* wo1 = (const float*)d_in[9];  const float* bo1 = (const float*)d_in[10];
  const float* wq2 = (const float*)d_in[11]; const float* bq2 = (const float*)d_in[12];
  const float* wk2 = (const float*)d_in[13]; const float* bk2 = (const float*)d_in[14];
  const float* wv2 = (const float*)d_in[15]; const float* bv2 = (const float*)d_in[16];
  const float* wo2 = (const float*)d_in[17]; const float* bo2 = (const float*)d_in[18];
  const float* c1w = (const float*)d_in[19]; const float* c1b = (const float*)d_in[20];
  const float* c2w = (const float*)d_in[21]; const float* c2b = (const float*)d_in[22];
  const float* g1  = (const float*)d_in[23]; const float* be1 = (const float*)d_in[24];
  const float* g2  = (const float*)d_in[25]; const float* be2 = (const float*)d_in[26];
  const float* g3  = (const float*)d_in[27]; const float* be3 = (const float*)d_in[28];
  float* outp = (float*)d_out;

  const int U   = in_sizes[2] / Ls;            // 35
  const int Uld = ((U + 63) / 64) * 64;        // 64

  char* ws = (char*)d_ws;
  const size_t SZ = (size_t)MR * DM * sizeof(float);       // 16.78 MB
  float* Qz   = (float*)(ws);                              // compact per-z Q1 (W0 region)
  float* Kz   = (float*)(ws + SZ);                         // compact per-z K1 (W1 region)
  float* W0   = Qz;                                        // reused after prob path
  float* W1   = Kz;
  float* W2   = (float*)(ws + 2 * SZ);
  float* Sbuf = (float*)(ws + 3 * SZ);                     // prob scores + PV partials / FFN hidden
  float* Pp   = Sbuf + (size_t)ZH * 64 * Ls;               // PV partials (16.8 MB)
  __hip_bfloat16* Tb  = (__hip_bfloat16*)(ws + 5 * SZ);    // tgt bf16; later reused as Kb
  __hip_bfloat16* Mb  = (__hip_bfloat16*)(ws + 5 * SZ + SZ / 2);
  __hip_bfloat16* Xb  = (__hip_bfloat16*)(ws + 6 * SZ);
  __hip_bfloat16* Vtb = (__hip_bfloat16*)(ws + 6 * SZ + SZ / 2);
  __hip_bfloat16* Wt3 = Vtb;                 // concat [wq1b;wk1b;wv1b] (dead before Vtb written)
  char* tail = ws + 7 * SZ;
  __hip_bfloat16* wo1b = (__hip_bfloat16*)tail; tail += DM * DM * 2;
  __hip_bfloat16* wq2b = (__hip_bfloat16*)tail; tail += DM * DM * 2;
  __hip_bfloat16* wk2b = (__hip_bfloat16*)tail; tail += DM * DM * 2;   // contiguous with wv2b
  __hip_bfloat16* wv2b = (__hip_bfloat16*)tail; tail += DM * DM * 2;
  __hip_bfloat16* wo2b = (__hip_bfloat16*)tail; tail += DM * DM * 2;
  __hip_bfloat16* c1wb = (__hip_bfloat16*)tail; tail += DM * 4 * DM * 2;
  __hip_bfloat16* c2wb = (__hip_bfloat16*)tail; tail += DM * 4 * DM * 2;
  float* Ms  = (float*)tail; tail += (size_t)ZH * Ls * 4;
  int*   top = (int*)tail;   tail += (size_t)ZH * Uld * 4;
  float* mvp = (float*)tail; tail += (size_t)ZH * 8 * DHd * 4;
  float* upd = (float*)tail; tail += (size_t)ZH * Uld * DHd * 4;
  __hip_bfloat16* Kb = Tb;
  __hip_bfloat16* Qb = (__hip_bfloat16*)d_out;  // parked in d_out until final LN
  __hip_bfloat16* hb = (__hip_bfloat16*)Sbuf;

  auto wcvt = [&](const float* Wm, __hip_bfloat16* Wt, int K, int N) {
    k_wt_cvt<<<dim3(K / 32, N / 32), 256, 0, stream>>>(Wm, Wt, K, N);
  };

  // ---- one-time converts ----
  k_cvt<<<dim3(MR * DM / 4 / 256), 256, 0, stream>>>(tgt, Tb);
  k_cvt<<<dim3(MR * DM / 4 / 256), 256, 0, stream>>>(mem, Mb);
  wcvt(wq1, Wt3, DM, DM); wcvt(wk1, Wt3 + DM * DM, DM, DM);
  wcvt(wv1, Wt3 + 2 * DM * DM, DM, DM);
  wcvt(wo1, wo1b, DM, DM);
  wcvt(wq2, wq2b, DM, DM); wcvt(wk2, wk2b, DM, DM);
  wcvt(wv2, wv2b, DM, DM); wcvt(wo2, wo2b, DM, DM);
  wcvt(c1w, c1wb, DM, 4 * DM); wcvt(c2w, c2wb, 4 * DM, DM);

  // ---- layer-1 projections: ONE batched GEMM (Q->Qz, K->Kz, V->W2) ----
  k_gemm_mfma<10, 0><<<dim3(MR / 128, 12), 256, 0, stream>>>(
      Tb, Wt3, bq1, bk1, bv1, Qz, Kz, W2, MR, 1536, DM);

  // ---- ProbSparse ----
  if (U == 35)
    k_mscore3<35><<<dim3(1024), 256, 0, stream>>>(Qz, Kz, smp, Ms);
  else
    k_mscore3g<<<dim3(1024), 256, 0, stream>>>(Qz, Kz, smp, Ms, U);
  k_topk_w<<<dim3(ZH), 64, 0, stream>>>(Ms, top, U);
  k_qkT<<<dim3(16 * ZH), 256, 0, stream>>>(Qz, Kz, Sbuf, top, U, U, 0.125f);
  k_softmax<<<dim3(ZH * Uld), 256, 0, stream>>>(Sbuf);
  k_pv_split<<<dim3(16 * ZH), 256, 0, stream>>>(Sbuf, W2, Pp);
  k_pv_red<<<dim3(ZH), 256, 0, stream>>>(Pp, upd);
  k_meanv1<<<dim3(ZH * 8), 256, 0, stream>>>(W2, mvp);
  k_ctxfillb<<<dim3(MR * DM / 4 / 256), 256, 0, stream>>>(mvp, Xb);  // ctx -> Xb bf16
  k_scatterb<<<dim3(ZH), 256, 0, stream>>>(upd, top, Xb, U, Uld);

  dim3 gsq(MR / 128, DM / 128);
  // ---- out-proj 1 + residual LN ----
  k_gemm_mfma<0, 0><<<gsq, 256, 0, stream>>>(
      Xb, wo1b, bo1, nullptr, nullptr, W0, nullptr, nullptr, MR, DM, DM);
  k_ln<<<dim3(MR), 256, 0, stream>>>(W0, tgt, g1, be1, nullptr, Xb); // x1 -> Xb bf16

  // ---- layer-2 projections ----
  k_gemm_mfma<1, 0><<<gsq, 256, 0, stream>>>(
      Xb, wq2b, bq2, nullptr, nullptr, Qb, nullptr, nullptr, MR, DM, DM);
  k_gemm_mfma<11, 0><<<dim3(MR / 128, 8), 256, 0, stream>>>(
      Mb, wk2b, bk2, bv2, nullptr, Kb, Vtb, nullptr, MR, 1024, DM);

  // ---- fused flash cross attention -> Xb (bf16) ----
  k_flash<<<dim3(Ls / 64, ZH), 256, 0, stream>>>(Qb, Kb, Vtb, Xb);

  // ---- out-proj 2 + LN + FFN + final LN ----
  k_gemm_mfma<0, 0><<<gsq, 256, 0, stream>>>(
      Xb, wo2b, bo2, nullptr, nullptr, W0, nullptr, nullptr, MR, DM, DM);
  k_ln<<<dim3(MR), 256, 0, stream>>>(W0, nullptr, g2, be2, W1, Xb); // x2ln -> W1 f32 + Xb bf16
  k_gemm_mfma<1, 1><<<dim3(MR / 128, 4 * DM / 128), 256, 0, stream>>>(
      Xb, c1wb, c1b, nullptr, nullptr, hb, nullptr, nullptr, MR, 4 * DM, DM);
  k_gemm_mfma<0, 0><<<dim3(MR / 128, DM / 128), 256, 0, stream>>>(
      hb, c2wb, c2b, nullptr, nullptr, W2, nullptr, nullptr, MR, DM, 4 * DM);
  k_ln<<<dim3(MR), 256, 0, stream>>>(W2, W1, g3, be3, outp, nullptr); // final -> d_out
}

// Round 7
// 417.100 us; speedup vs baseline: 5.2639x; 1.0060x over previous
//
#include <hip/hip_runtime.h>
#include <hip/hip_bf16.h>
#include <cstdint>

constexpr int Bb  = 8;
constexpr int Ls  = 1024;
constexpr int DM  = 512;
constexpr int NH  = 8;
constexpr int DHd = 64;
constexpr int MR  = Bb * Ls;   // 8192 rows
constexpr int ZH  = Bb * NH;   // 64 (b,h) pairs

typedef __attribute__((ext_vector_type(8))) short short8v;
typedef __attribute__((ext_vector_type(4))) short short4v;
typedef __attribute__((ext_vector_type(4))) float floatx4;

__device__ inline short f2bf(float x) {
  __hip_bfloat16 h = __float2bfloat16(x);
  return *reinterpret_cast<short*>(&h);
}

#define GLOAD_LDS16(g, l)                                                        \
  __builtin_amdgcn_global_load_lds(                                              \
      (const __attribute__((address_space(1))) void*)(g),                        \
      (__attribute__((address_space(3))) void*)(l), 16, 0, 0)

// ================= bf16 MFMA GEMM: C = act(A @ Wt^T + bias) =================
// MODE: 0 f32 out | 1 bf16 out | 2 bf16 K-swizzle | 3 bf16 V-transpose |
// 10 L1 triple (N=1536: Q->Qz, K->Kz, V->merged f32) |
// 11 L2 KV pair (N=1024: K->Kb swizzled, V->Vt transposed) |
// 20 split-K raw f32 partial (no bias; partial z -> Cout/aux1/aux2/aux3)
template<int MODE, int RELU>
__global__ __launch_bounds__(256) void k_gemm_mfma(
    const __hip_bfloat16* __restrict__ A, const __hip_bfloat16* __restrict__ Wt,
    const float* __restrict__ bias, const float* __restrict__ bias1,
    const float* __restrict__ bias2,
    void* __restrict__ Cout, void* __restrict__ aux1, void* __restrict__ aux2,
    void* __restrict__ aux3,
    int M, int N, int K)
{
  __shared__ __hip_bfloat16 As[128 * 32];
  __shared__ __hip_bfloat16 Bs[128 * 32];
  const int tid = threadIdx.x;
  const int w = tid >> 6, lane = tid & 63;
  const int wr = w >> 1, wc = w & 1;
  const int bm = blockIdx.x * 128, bn = blockIdx.y * 128;
  const int lrow = lane >> 2;
  const int lcol = (lane & 3) * 8;
  const int fr = lane & 15;
  const int fco = (lane >> 4) * 8;
  const short* Ash = (const short*)As;
  const short* Bsh = (const short*)Bs;

  const int ksl = K / gridDim.z;
  const int kb0 = blockIdx.z * ksl;

  floatx4 acc[4][4] = {};
  for (int k0 = kb0; k0 < kb0 + ksl; k0 += 32) {
#pragma unroll
    for (int i = 0; i < 2; ++i) {
      const int chunk = w * 2 + i;
      GLOAD_LDS16(A  + (size_t)(bm + chunk * 16 + lrow) * K + k0 + lcol,
                  As + chunk * 512);
      GLOAD_LDS16(Wt + (size_t)(bn + chunk * 16 + lrow) * K + k0 + lcol,
                  Bs + chunk * 512);
    }
    __syncthreads();
    short8v a[4], b[4];
#pragma unroll
    for (int mi = 0; mi < 4; ++mi)
      a[mi] = *(const short8v*)(Ash + (wr * 64 + mi * 16 + fr) * 32 + fco);
#pragma unroll
    for (int ni = 0; ni < 4; ++ni)
      b[ni] = *(const short8v*)(Bsh + (wc * 64 + ni * 16 + fr) * 32 + fco);
#pragma unroll
    for (int mi = 0; mi < 4; ++mi)
#pragma unroll
      for (int ni = 0; ni < 4; ++ni)
        acc[mi][ni] = __builtin_amdgcn_mfma_f32_16x16x32_bf16(
            a[mi], b[ni], acc[mi][ni], 0, 0, 0);
    __syncthreads();
  }
#pragma unroll
  for (int ni = 0; ni < 4; ++ni) {
    const int cn = bn + wc * 64 + ni * 16 + fr;
    float bv = 0.f;
    if (MODE == 10) {
      const float* bp = (cn < 512) ? bias : (cn < 1024 ? bias1 : bias2);
      bv = bp[cn & 511];
    } else if (MODE == 11) {
      bv = (cn < 512 ? bias : bias1)[cn & 511];
    } else if (MODE != 20) {
      bv = bias[cn];
    }
#pragma unroll
    for (int mi = 0; mi < 4; ++mi) {
#pragma unroll
      for (int j = 0; j < 4; ++j) {
        const int rm = bm + wr * 64 + mi * 16 + (lane >> 4) * 4 + j;
        float v = acc[mi][ni][j] + bv;
        if (RELU) v = fmaxf(v, 0.f);
        if (MODE == 0) {
          ((float*)Cout)[(size_t)rm * N + cn] = v;
        } else if (MODE == 1) {
          ((__hip_bfloat16*)Cout)[(size_t)rm * N + cn] = __float2bfloat16(v);
        } else if (MODE == 2) {
          const int cs = (cn & ~63) | ((cn & 63) ^ ((rm & 7) << 3));
          ((__hip_bfloat16*)Cout)[(size_t)rm * N + cs] = __float2bfloat16(v);
        } else if (MODE == 3) {
          const int bb = rm >> 10, l = rm & 1023, hh = cn >> 6, dd = cn & 63;
          ((__hip_bfloat16*)Cout)[(size_t)((bb * 8 + hh) * 64 + dd) * 1024 +
                                  (l ^ ((dd & 7) << 3))] = __float2bfloat16(v);
        } else if (MODE == 10) {
          const int sel = cn >> 9, c = cn & 511;
          if (sel == 2) {
            ((float*)aux2)[(size_t)rm * 512 + c] = v;
          } else {
            float* base = sel ? (float*)aux1 : (float*)Cout;
            const int bb = rm >> 10, l = rm & 1023, hh = c >> 6, dd = c & 63;
            base[(((size_t)(bb * 8 + hh)) * 1024 + l) * 64 + dd] = v;
          }
        } else if (MODE == 11) {
          const int c = cn & 511;
          if (cn < 512) {
            const int cs = (c & ~63) | ((c & 63) ^ ((rm & 7) << 3));
            ((__hip_bfloat16*)Cout)[(size_t)rm * 512 + cs] = __float2bfloat16(v);
          } else {
            const int bb = rm >> 10, l = rm & 1023, hh = c >> 6, dd = c & 63;
            ((__hip_bfloat16*)aux1)[(size_t)((bb * 8 + hh) * 64 + dd) * 1024 +
                                    (l ^ ((dd & 7) << 3))] = __float2bfloat16(v);
          }
        } else if (MODE == 20) {
          float* pz = (float*)(blockIdx.z == 0 ? Cout :
                      blockIdx.z == 1 ? aux1 :
                      blockIdx.z == 2 ? aux2 : aux3);
          pz[(size_t)rm * N + cn] = v;
        }
      }
    }
  }
}

// ============ fused flash cross-attention v2: 512 thr, dbuf K/V ============
__global__ __launch_bounds__(512) void k_flash2(
    const __hip_bfloat16* __restrict__ Qb,
    const __hip_bfloat16* __restrict__ Kb,
    const __hip_bfloat16* __restrict__ Vt,
    __hip_bfloat16* __restrict__ O)
{
  __shared__ __hip_bfloat16 Ks[2][64 * 64];
  __shared__ __hip_bfloat16 Vs[2][64 * 64];
  __shared__ __hip_bfloat16 Ps[8 * 16 * 72];
  const int tid = threadIdx.x, w = tid >> 6, lane = tid & 63;
  const int g = lane >> 4, r = lane & 15;
  const int z = blockIdx.y, b = z >> 3, h = z & 7;
  const int q0 = blockIdx.x * 128 + w * 16;
  __hip_bfloat16* Pw = Ps + w * 16 * 72;

  const int srow = w * 8 + (lane >> 3);   // K/V row staged by this thread
  const int sseg = lane & 7;

  const short8v qf0 = *(const short8v*)(Qb + (size_t)(b * Ls + q0 + r) * DM + h * DHd + g * 8);
  const short8v qf1 = *(const short8v*)(Qb + (size_t)(b * Ls + q0 + r) * DM + h * DHd + 32 + g * 8);

  floatx4 oacc[4] = {};
  float m_run = -1e30f, l_run = 0.f;

  // prologue: stage tile 0 into buffer 0
  GLOAD_LDS16(Kb + (size_t)(b * Ls + srow) * DM + h * DHd + sseg * 8, &Ks[0][w * 512]);
  GLOAD_LDS16(Vt + ((size_t)z * DHd + srow) * Ls + sseg * 8, &Vs[0][w * 512]);
  asm volatile("s_waitcnt vmcnt(0)" ::: "memory");
  __builtin_amdgcn_s_barrier();

  int cur = 0;
  for (int t = 0; t < 16; ++t) {
    if (t + 1 < 16) {   // issue next tile's loads; they overlap this compute
      GLOAD_LDS16(Kb + (size_t)(b * Ls + (t + 1) * 64 + srow) * DM + h * DHd + sseg * 8,
                  &Ks[cur ^ 1][w * 512]);
      GLOAD_LDS16(Vt + ((size_t)z * DHd + srow) * Ls + (t + 1) * 64 + sseg * 8,
                  &Vs[cur ^ 1][w * 512]);
    }
    const __hip_bfloat16* Kc = Ks[cur];
    const __hip_bfloat16* Vc = Vs[cur];
    float sv[4][4];
    float tmax = -1e30f;
#pragma unroll
    for (int kt = 0; kt < 4; ++kt) {
      const int key = kt * 16 + r, sw = key & 7;
      short8v a0 = *(const short8v*)(Kc + key * 64 + ((g ^ sw) * 8));
      short8v a1 = *(const short8v*)(Kc + key * 64 + (((4 + g) ^ sw) * 8));
      floatx4 c = {};
      c = __builtin_amdgcn_mfma_f32_16x16x32_bf16(a0, qf0, c, 0, 0, 0);
      c = __builtin_amdgcn_mfma_f32_16x16x32_bf16(a1, qf1, c, 0, 0, 0);
#pragma unroll
      for (int j = 0; j < 4; ++j) {
        float x = c[j] * 0.125f;
        sv[kt][j] = x;
        tmax = fmaxf(tmax, x);
      }
    }
    tmax = fmaxf(tmax, __shfl_xor(tmax, 16));
    tmax = fmaxf(tmax, __shfl_xor(tmax, 32));
    const float m_new = fmaxf(m_run, tmax);
    const float fac = __expf(m_run - m_new);
    float psum = 0.f;
#pragma unroll
    for (int kt = 0; kt < 4; ++kt) {
      short4v pk;
#pragma unroll
      for (int j = 0; j < 4; ++j) {
        float p = __expf(sv[kt][j] - m_new);
        psum += p;
        pk[j] = f2bf(p);
      }
      *(short4v*)(Pw + r * 72 + kt * 16 + g * 4) = pk;
    }
    psum += __shfl_xor(psum, 16);
    psum += __shfl_xor(psum, 32);
    l_run = l_run * fac + psum;
    m_run = m_new;
    float fj[4];
#pragma unroll
    for (int j = 0; j < 4; ++j) fj[j] = __shfl(fac, (lane & 48) | (g * 4 + j));
#pragma unroll
    for (int ct = 0; ct < 4; ++ct)
#pragma unroll
      for (int j = 0; j < 4; ++j) oacc[ct][j] *= fj[j];
    const short8v pa0 = *(const short8v*)(Pw + r * 72 + g * 8);
    const short8v pa1 = *(const short8v*)(Pw + r * 72 + 32 + g * 8);
#pragma unroll
    for (int ct = 0; ct < 4; ++ct) {
      const int d = ct * 16 + r, sw = d & 7;
      short8v v0 = *(const short8v*)(Vc + d * 64 + ((g ^ sw) * 8));
      short8v v1 = *(const short8v*)(Vc + d * 64 + (((4 + g) ^ sw) * 8));
      oacc[ct] = __builtin_amdgcn_mfma_f32_16x16x32_bf16(pa0, v0, oacc[ct], 0, 0, 0);
      oacc[ct] = __builtin_amdgcn_mfma_f32_16x16x32_bf16(pa1, v1, oacc[ct], 0, 0, 0);
    }
    asm volatile("s_waitcnt vmcnt(0)" ::: "memory");  // next tile landed
    __builtin_amdgcn_s_barrier();                     // all waves done with cur
    cur ^= 1;
  }
  float li[4];
#pragma unroll
  for (int j = 0; j < 4; ++j)
    li[j] = 1.0f / __shfl(l_run, (lane & 48) | (g * 4 + j));
#pragma unroll
  for (int ct = 0; ct < 4; ++ct)
#pragma unroll
    for (int j = 0; j < 4; ++j)
      O[(size_t)(b * Ls + q0 + g * 4 + j) * DM + h * DHd + ct * 16 + r] =
          __float2bfloat16(oacc[ct][j] * li[j]);
}

// ---------------- f32 -> bf16 elementwise ----------------
__global__ __launch_bounds__(256) void k_cvt(
    const float* __restrict__ in, __hip_bfloat16* __restrict__ out)
{
  const size_t i = ((size_t)blockIdx.x * 256 + threadIdx.x) * 4;
  float4 v = *reinterpret_cast<const float4*>(in + i);
  short4v o;
  o.x = f2bf(v.x); o.y = f2bf(v.y); o.z = f2bf(v.z); o.w = f2bf(v.w);
  *reinterpret_cast<short4v*>(out + i) = o;
}

// ---------------- weight convert+transpose ----------------
__global__ __launch_bounds__(256) void k_wt_cvt(
    const float* __restrict__ W, __hip_bfloat16* __restrict__ Wt, int K, int N)
{
  __shared__ float t[32][33];
  const int tid = threadIdx.x;
  const int k0 = blockIdx.x * 32, n0 = blockIdx.y * 32;
  const int r = tid >> 3, c = (tid & 7) * 4;
  float4 v = *reinterpret_cast<const float4*>(W + (size_t)(k0 + r) * N + n0 + c);
  t[r][c + 0] = v.x; t[r][c + 1] = v.y; t[r][c + 2] = v.z; t[r][c + 3] = v.w;
  __syncthreads();
  short4v o;
  o.x = f2bf(t[c + 0][r]); o.y = f2bf(t[c + 1][r]);
  o.z = f2bf(t[c + 2][r]); o.w = f2bf(t[c + 3][r]);
  *reinterpret_cast<short4v*>(Wt + (size_t)(n0 + r) * K + k0 + c) = o;
}

// ---------------- prob-path scores (compact per-z Q/K, XCD-swizzled) ----------------
__global__ __launch_bounds__(256) void k_qkT(
    const float* __restrict__ Qz, const float* __restrict__ Kz,
    float* __restrict__ S, const int* __restrict__ top,
    int Mrows, int topStride, float scale)
{
  __shared__ float Qs[DHd][64 + 4];
  __shared__ float Ks[DHd][64 + 4];
  const int bid = blockIdx.x;
  const int swz = (bid & 7) * ((16 * ZH) >> 3) + (bid >> 3);
  const int z = swz >> 4, n0 = (swz & 15) << 6;
  const int tid = threadIdx.x;
#pragma unroll
  for (int i = 0; i < 4; ++i) {
    int idx = tid + (i << 8);
    int r = idx >> 4, c4 = (idx & 15) << 2;
    int u = r; if (u >= Mrows) u = Mrows - 1;
    const int qr = top[z * topStride + u];
    float4 q4 = *reinterpret_cast<const float4*>(Qz + ((size_t)z * Ls + qr) * 64 + c4);
    Qs[c4 + 0][r] = q4.x; Qs[c4 + 1][r] = q4.y; Qs[c4 + 2][r] = q4.z; Qs[c4 + 3][r] = q4.w;
    float4 k4 = *reinterpret_cast<const float4*>(Kz + ((size_t)z * Ls + n0 + r) * 64 + c4);
    Ks[c4 + 0][r] = k4.x; Ks[c4 + 1][r] = k4.y; Ks[c4 + 2][r] = k4.z; Ks[c4 + 3][r] = k4.w;
  }
  __syncthreads();
  const int mB = (tid >> 4) << 2, nB = (tid & 15) << 2;
  float acc[4][4] = {};
#pragma unroll
  for (int kk = 0; kk < DHd; ++kk) {
    float4 a4 = *reinterpret_cast<const float4*>(&Qs[kk][mB]);
    float4 b4 = *reinterpret_cast<const float4*>(&Ks[kk][nB]);
    const float av[4] = {a4.x, a4.y, a4.z, a4.w};
#pragma unroll
    for (int i = 0; i < 4; ++i) {
      acc[i][0] += av[i] * b4.x; acc[i][1] += av[i] * b4.y;
      acc[i][2] += av[i] * b4.z; acc[i][3] += av[i] * b4.w;
    }
  }
#pragma unroll
  for (int i = 0; i < 4; ++i) {
    int m = mB + i;
    if (m < Mrows) {
      float4 o;
      o.x = acc[i][0] * scale; o.y = acc[i][1] * scale;
      o.z = acc[i][2] * scale; o.w = acc[i][3] * scale;
      *reinterpret_cast<float4*>(S + ((size_t)z * 64 + m) * Ls + n0 + nB) = o;
    }
  }
}

// ---------------- row softmax over length 1024 (in place) ----------------
__global__ __launch_bounds__(256) void k_softmax(float* __restrict__ S)
{
  __shared__ float red[4];
  const int row = blockIdx.x, tid = threadIdx.x;
  float* p = S + (size_t)row * Ls;
  float4 v = *reinterpret_cast<float4*>(p + (tid << 2));
  float mx = fmaxf(fmaxf(v.x, v.y), fmaxf(v.z, v.w));
#pragma unroll
  for (int off = 32; off; off >>= 1) mx = fmaxf(mx, __shfl_xor(mx, off));
  if ((tid & 63) == 0) red[tid >> 6] = mx;
  __syncthreads();
  mx = fmaxf(fmaxf(red[0], red[1]), fmaxf(red[2], red[3]));
  __syncthreads();
  v.x = __expf(v.x - mx); v.y = __expf(v.y - mx);
  v.z = __expf(v.z - mx); v.w = __expf(v.w - mx);
  float s = v.x + v.y + v.z + v.w;
#pragma unroll
  for (int off = 32; off; off >>= 1) s += __shfl_xor(s, off);
  if ((tid & 63) == 0) red[tid >> 6] = s;
  __syncthreads();
  s = red[0] + red[1] + red[2] + red[3];
  float inv = 1.0f / s;
  v.x *= inv; v.y *= inv; v.z *= inv; v.w *= inv;
  *reinterpret_cast<float4*>(p + (tid << 2)) = v;
}

// ---------------- prob-path PV, K-split (XCD-swizzled) ----------------
__global__ __launch_bounds__(256) void k_pv_split(
    const float* __restrict__ S, const float* __restrict__ Vm,
    float* __restrict__ Pp)
{
  __shared__ float Ss[64][64];
  __shared__ float Vs[64][64];
  const int bid = blockIdx.x;
  const int swz = (bid & 7) * ((16 * ZH) >> 3) + (bid >> 3);
  const int ks = swz & 15, z = swz >> 4, b = z >> 3, h = z & 7;
  const int tid = threadIdx.x;
  const int k0 = ks * 64;
#pragma unroll
  for (int i = 0; i < 4; ++i) {
    const int idx = tid + (i << 8);
    const int row = idx >> 4, c4 = (idx & 15) << 2;
    *reinterpret_cast<float4*>(&Ss[row][c4]) =
        *reinterpret_cast<const float4*>(S + ((size_t)z * 64 + row) * Ls + k0 + c4);
    *reinterpret_cast<float4*>(&Vs[row][c4]) =
        *reinterpret_cast<const float4*>(Vm + ((size_t)(b * Ls + k0 + row)) * DM + h * DHd + c4);
  }
  __syncthreads();
  const int d = tid & 63, w = tid >> 6;
  float acc[16] = {};
  for (int k = 0; k < 64; ++k) {
    const float vk = Vs[k][d];
#pragma unroll
    for (int i = 0; i < 16; ++i)
      acc[i] += Ss[w * 16 + i][k] * vk;
  }
  float* outb = Pp + ((size_t)ks * ZH + z) * 4096;
#pragma unroll
  for (int i = 0; i < 16; ++i)
    outb[(w * 16 + i) * 64 + d] = acc[i];
}

// ---------------- reduce 16 PV partials -> upd ----------------
__global__ __launch_bounds__(256) void k_pv_red(
    const float* __restrict__ Pp, float* __restrict__ upd)
{
  const int z = blockIdx.x, tid = threadIdx.x;
#pragma unroll
  for (int e = tid; e < 4096; e += 256) {
    float s = 0.f;
#pragma unroll
    for (int ks = 0; ks < 16; ++ks)
      s += Pp[((size_t)ks * ZH + z) * 4096 + e];
    upd[(size_t)z * 4096 + e] = s;
  }
}

// ---------------- ProbSparse sampled scores, compact layout ----------------
template<int UU>
__global__ __launch_bounds__(256) void k_mscore3(
    const float* __restrict__ Qz, const float* __restrict__ Kz,
    const int* __restrict__ smp, float* __restrict__ Ms)
{
  const int bid = blockIdx.x;
  const int swz = (bid & 7) * 128 + (bid >> 3);
  const int gw = swz * 4 + (threadIdx.x >> 6);
  const int lane = threadIdx.x & 63;
  const int li = lane >> 2, dp = (lane & 3) * 16;
  const int l = (gw & 63) * 16 + li;
  const int z = gw >> 6;
  const float* qb = Qz + ((size_t)z * Ls + l) * 64 + dp;
  const float4 q0 = *(const float4*)(qb);
  const float4 q1 = *(const float4*)(qb + 4);
  const float4 q2 = *(const float4*)(qb + 8);
  const float4 q3 = *(const float4*)(qb + 12);
  int kidx[UU];
#pragma unroll
  for (int u = 0; u < UU; ++u) kidx[u] = smp[l * UU + u];
  const float* kzb = Kz + (size_t)z * Ls * 64 + dp;
  float mx = -1e30f, sm = 0.f;
#pragma unroll
  for (int u = 0; u < UU; ++u) {
    const float* kb = kzb + (size_t)kidx[u] * 64;
    const float4 k0 = *(const float4*)(kb);
    const float4 k1 = *(const float4*)(kb + 4);
    const float4 k2 = *(const float4*)(kb + 8);
    const float4 k3 = *(const float4*)(kb + 12);
    float d = q0.x*k0.x + q0.y*k0.y + q0.z*k0.z + q0.w*k0.w
            + q1.x*k1.x + q1.y*k1.y + q1.z*k1.z + q1.w*k1.w
            + q2.x*k2.x + q2.y*k2.y + q2.z*k2.z + q2.w*k2.w
            + q3.x*k3.x + q3.y*k3.y + q3.z*k3.z + q3.w*k3.w;
    d += __shfl_xor(d, 1);
    d += __shfl_xor(d, 2);
    mx = fmaxf(mx, d);
    sm += d;
  }
  if ((lane & 3) == 0) Ms[z * Ls + l] = mx - sm * (1.0f / Ls);
}

// runtime-U fallback
__global__ __launch_bounds__(256) void k_mscore3g(
    const float* __restrict__ Qz, const float* __restrict__ Kz,
    const int* __restrict__ smp, float* __restrict__ Ms, int U)
{
  const int bid = blockIdx.x;
  const int swz = (bid & 7) * 128 + (bid >> 3);
  const int gw = swz * 4 + (threadIdx.x >> 6);
  const int lane = threadIdx.x & 63;
  const int li = lane >> 2, dp = (lane & 3) * 16;
  const int l = (gw & 63) * 16 + li;
  const int z = gw >> 6;
  const float* qb = Qz + ((size_t)z * Ls + l) * 64 + dp;
  const float4 q0 = *(const float4*)(qb);
  const float4 q1 = *(const float4*)(qb + 4);
  const float4 q2 = *(const float4*)(qb + 8);
  const float4 q3 = *(const float4*)(qb + 12);
  const float* kzb = Kz + (size_t)z * Ls * 64 + dp;
  float mx = -1e30f, sm = 0.f;
  for (int u = 0; u < U; ++u) {
    const float* kb = kzb + (size_t)smp[l * U + u] * 64;
    const float4 k0 = *(const float4*)(kb);
    const float4 k1 = *(const float4*)(kb + 4);
    const float4 k2 = *(const float4*)(kb + 8);
    const float4 k3 = *(const float4*)(kb + 12);
    float d = q0.x*k0.x + q0.y*k0.y + q0.z*k0.z + q0.w*k0.w
            + q1.x*k1.x + q1.y*k1.y + q1.z*k1.z + q1.w*k1.w
            + q2.x*k2.x + q2.y*k2.y + q2.z*k2.z + q2.w*k2.w
            + q3.x*k3.x + q3.y*k3.y + q3.z*k3.z + q3.w*k3.w;
    d += __shfl_xor(d, 1);
    d += __shfl_xor(d, 2);
    mx = fmaxf(mx, d);
    sm += d;
  }
  if ((lane & 3) == 0) Ms[z * Ls + l] = mx - sm * (1.0f / Ls);
}

// ---------------- wave-parallel top-U ----------------
__global__ __launch_bounds__(64) void k_topk_w(
    const float* __restrict__ Ms, int* __restrict__ top, int U)
{
  const int z = blockIdx.x, lane = threadIdx.x;
  float v[16];
#pragma unroll
  for (int j = 0; j < 16; ++j) v[j] = Ms[z * Ls + j * 64 + lane];
  for (int it = 0; it < U; ++it) {
    float bv = -1e30f; int bi = 0x7fffffff;
#pragma unroll
    for (int j = 0; j < 16; ++j) {
      const int idx = j * 64 + lane;
      if (v[j] > bv) { bv = v[j]; bi = idx; }
    }
#pragma unroll
    for (int off = 1; off < 64; off <<= 1) {
      const float ov = __shfl_xor(bv, off);
      const int   oi = __shfl_xor(bi, off);
      if (ov > bv || (ov == bv && oi < bi)) { bv = ov; bi = oi; }
    }
    if (lane == 0) top[z * U + it] = bi;
    if ((bi & 63) == lane) v[bi >> 6] = -1e30f;
  }
}

// ---------------- mean of V: stage 1 ----------------
__global__ __launch_bounds__(256) void k_meanv1(
    const float* __restrict__ Vm, float* __restrict__ mvp)
{
  __shared__ float ps[4][64];
  const int gid = blockIdx.x, z = gid >> 3, c = gid & 7, b = z >> 3, h = z & 7;
  const int d = threadIdx.x & 63, g = threadIdx.x >> 6;
  float s = 0.f;
  const int kb = c * 128 + g * 32;
  for (int k = kb; k < kb + 32; ++k)
    s += Vm[((size_t)(b * Ls + k)) * DM + h * DHd + d];
  ps[g][d] = s;
  __syncthreads();
  if (g == 0) mvp[(z * 8 + c) * 64 + d] = ps[0][d] + ps[1][d] + ps[2][d] + ps[3][d];
}

// ---------------- broadcast mean-V into bf16 ctx ----------------
__global__ __launch_bounds__(256) void k_ctxfillb(
    const float* __restrict__ mvp, __hip_bfloat16* __restrict__ ctx)
{
  const int i = blockIdx.x * 256 + threadIdx.x;
  const int c4 = (i & 127) << 2;
  const int row = i >> 7;
  const int b = row >> 10;
  const int h = c4 >> 6;
  const float* base = mvp + ((b * 8 + h) * 8) * 64 + (c4 & 63);
  float4 a = {0.f, 0.f, 0.f, 0.f};
#pragma unroll
  for (int c = 0; c < 8; ++c) {
    float4 m4 = *reinterpret_cast<const float4*>(base + c * 64);
    a.x += m4.x; a.y += m4.y; a.z += m4.z; a.w += m4.w;
  }
  const float inv = 1.0f / Ls;
  short4v o;
  o.x = f2bf(a.x * inv); o.y = f2bf(a.y * inv);
  o.z = f2bf(a.z * inv); o.w = f2bf(a.w * inv);
  *reinterpret_cast<short4v*>(ctx + (size_t)row * DM + c4) = o;
}

// ---------------- scatter upd rows into bf16 ctx ----------------
__global__ __launch_bounds__(256) void k_scatterb(
    const float* __restrict__ upd, const int* __restrict__ top,
    __hip_bfloat16* __restrict__ ctx, int U, int Uld)
{
  const int z = blockIdx.x, b = z >> 3, h = z & 7;
  const int d = threadIdx.x & 63;
  for (int u = threadIdx.x >> 6; u < U; u += 4) {
    int row = top[z * U + u];
    ctx[((size_t)(b * Ls + row)) * DM + h * DHd + d] =
        __float2bfloat16(upd[((size_t)z * Uld + u) * DHd + d]);
  }
}

// ------- LayerNorm over sum of NP partials (+bias) (+residual) -------
template<int NP>
__global__ __launch_bounds__(256) void k_ln2(
    const float* __restrict__ x0, const float* __restrict__ x1,
    const float* __restrict__ x2, const float* __restrict__ x3,
    const float* __restrict__ res, const float* __restrict__ bias,
    const float* __restrict__ g, const float* __restrict__ be,
    float* __restrict__ outf, __hip_bfloat16* __restrict__ outb)
{
  __shared__ float red[4];
  const int row = blockIdx.x, tid = threadIdx.x;
  const size_t base = (size_t)row * DM;
  float2 v = *reinterpret_cast<const float2*>(x0 + base + tid * 2);
  if (NP > 1) {
    float2 a = *reinterpret_cast<const float2*>(x1 + base + tid * 2);
    v.x += a.x; v.y += a.y;
  }
  if (NP > 2) {
    float2 a = *reinterpret_cast<const float2*>(x2 + base + tid * 2);
    v.x += a.x; v.y += a.y;
  }
  if (NP > 3) {
    float2 a = *reinterpret_cast<const float2*>(x3 + base + tid * 2);
    v.x += a.x; v.y += a.y;
  }
  if (bias) {
    float2 a = *reinterpret_cast<const float2*>(bias + tid * 2);
    v.x += a.x; v.y += a.y;
  }
  if (res) {
    float2 r2 = *reinterpret_cast<const float2*>(res + base + tid * 2);
    v.x += r2.x; v.y += r2.y;
  }
  float s = v.x + v.y;
#pragma unroll
  for (int off = 32; off; off >>= 1) s += __shfl_xor(s, off);
  if ((tid & 63) == 0) red[tid >> 6] = s;
  __syncthreads();
  s = red[0] + red[1] + red[2] + red[3];
  const float mean = s * (1.0f / DM);
  __syncthreads();
  float dx = v.x - mean, dy = v.y - mean;
  float q = dx * dx + dy * dy;
#pragma unroll
  for (int off = 32; off; off >>= 1) q += __shfl_xor(q, off);
  if ((tid & 63) == 0) red[tid >> 6] = q;
  __syncthreads();
  q = red[0] + red[1] + red[2] + red[3];
  const float inv = rsqrtf(q * (1.0f / DM) + 1e-5f);
  float2 gg = *reinterpret_cast<const float2*>(g + tid * 2);
  float2 bb = *reinterpret_cast<const float2*>(be + tid * 2);
  float ox = dx * inv * gg.x + bb.x;
  float oy = dy * inv * gg.y + bb.y;
  if (outf) {
    float2 o; o.x = ox; o.y = oy;
    *reinterpret_cast<float2*>(outf + base + tid * 2) = o;
  }
  if (outb) {
    short2 ob; ob.x = f2bf(ox); ob.y = f2bf(oy);
    *reinterpret_cast<short2*>(outb + base + tid * 2) = ob;
  }
}

extern "C" void kernel_launch(void* const* d_in, const int* in_sizes, int n_in,
                              void* d_out, int out_size, void* d_ws, size_t ws_size,
                              hipStream_t stream)
{
  const float* tgt = (const float*)d_in[0];
  const float* mem = (const float*)d_in[1];
  const int*   smp = (const int*)d_in[2];
  const float* wq1 = (const float*)d_in[3];  const float* bq1 = (const float*)d_in[4];
  const float* wk1 = (const float*)d_in[5];  const float* bk1 = (const float*)d_in[6];
  const float* wv1 = (const float*)d_in[7];  const float* bv1 = (const float*)d_in[8];
  const float* wo1 = (const float*)d_in[9];  const float* bo1 = (const float*)d_in[10];
  const float* wq2 = (const float*)d_in[11]; const float* bq2 = (const float*)d_in[12];
  const float* wk2 = (const float*)d_in[13]; const float* bk2 = (const float*)d_in[14];
  const float* wv2 = (const float*)d_in[15]; const float* bv2 = (const float*)d_in[16];
  const float* wo2 = (const float*)d_in[17]; const float* bo2 = (const float*)d_in[18];
  const float* c1w = (const float*)d_in[19]; const float* c1b = (const float*)d_in[20];
  const float* c2w = (const float*)d_in[21]; const float* c2b = (const float*)d_in[22];
  const float* g1  = (const float*)d_in[23]; const float* be1 = (const float*)d_in[24];
  const float* g2  = (const float*)d_in[25]; const float* be2 = (const float*)d_in[26];
  const float* g3  = (const float*)d_in[27]; const float* be3 = (const float*)d_in[28];
  float* outp = (float*)d_out;

  const int U   = in_sizes[2] / Ls;            // 35
  const int Uld = ((U + 63) / 64) * 64;        // 64

  char* ws = (char*)d_ws;
  const size_t SZ = (size_t)MR * DM * sizeof(float);       // 16.78 MB
  float* Qz   = (float*)(ws);
  float* Kz   = (float*)(ws + SZ);
  float* W0   = Qz;
  float* W1   = Kz;
  float* W2   = (float*)(ws + 2 * SZ);
  float* Sbuf = (float*)(ws + 3 * SZ);                     // prob scores / FFN hidden
  float* Pp   = Sbuf + (size_t)ZH * 64 * Ls;               // PV partials
  __hip_bfloat16* Tb  = (__hip_bfloat16*)(ws + 5 * SZ);
  __hip_bfloat16* Mb  = (__hip_bfloat16*)(ws + 5 * SZ + SZ / 2);
  __hip_bfloat16* Xb  = (__hip_bfloat16*)(ws + 6 * SZ);
  __hip_bfloat16* Vtb = (__hip_bfloat16*)(ws + 6 * SZ + SZ / 2);
  __hip_bfloat16* Wt3 = Vtb;                 // [wq1b;wk1b;wv1b] (dead before Vtb written)
  float* CP2 = (float*)(ws + 5 * SZ);        // conv2 partial 2 (Tb/Mb dead by then)
  float* CP3 = (float*)(ws + 6 * SZ);        // conv2 partial 3 (Xb/Vtb dead by then)
  char* tail = ws + 7 * SZ;
  __hip_bfloat16* wo1b = (__hip_bfloat16*)tail; tail += DM * DM * 2;
  __hip_bfloat16* wq2b = (__hip_bfloat16*)tail; tail += DM * DM * 2;
  __hip_bfloat16* wk2b = (__hip_bfloat16*)tail; tail += DM * DM * 2;
  __hip_bfloat16* wv2b = (__hip_bfloat16*)tail; tail += DM * DM * 2;
  __hip_bfloat16* wo2b = (__hip_bfloat16*)tail; tail += DM * DM * 2;
  __hip_bfloat16* c1wb = (__hip_bfloat16*)tail; tail += DM * 4 * DM * 2;
  __hip_bfloat16* c2wb = (__hip_bfloat16*)tail; tail += DM * 4 * DM * 2;
  float* Ms  = (float*)tail; tail += (size_t)ZH * Ls * 4;
  int*   top = (int*)tail;   tail += (size_t)ZH * Uld * 4;
  float* mvp = (float*)tail; tail += (size_t)ZH * 8 * DHd * 4;
  float* upd = (float*)tail; tail += (size_t)ZH * Uld * DHd * 4;
  __hip_bfloat16* Kb = Tb;
  __hip_bfloat16* Qb = (__hip_bfloat16*)d_out;  // parked until final LN
  __hip_bfloat16* hb = (__hip_bfloat16*)Sbuf;

  auto wcvt = [&](const float* Wm, __hip_bfloat16* Wt, int K, int N) {
    k_wt_cvt<<<dim3(K / 32, N / 32), 256, 0, stream>>>(Wm, Wt, K, N);
  };

  // ---- one-time converts ----
  k_cvt<<<dim3(MR * DM / 4 / 256), 256, 0, stream>>>(tgt, Tb);
  k_cvt<<<dim3(MR * DM / 4 / 256), 256, 0, stream>>>(mem, Mb);
  wcvt(wq1, Wt3, DM, DM); wcvt(wk1, Wt3 + DM * DM, DM, DM);
  wcvt(wv1, Wt3 + 2 * DM * DM, DM, DM);
  wcvt(wo1, wo1b, DM, DM);
  wcvt(wq2, wq2b, DM, DM); wcvt(wk2, wk2b, DM, DM);
  wcvt(wv2, wv2b, DM, DM); wcvt(wo2, wo2b, DM, DM);
  wcvt(c1w, c1wb, DM, 4 * DM); wcvt(c2w, c2wb, 4 * DM, DM);

  // ---- layer-1 projections: ONE batched GEMM (Q->Qz, K->Kz, V->W2) ----
  k_gemm_mfma<10, 0><<<dim3(MR / 128, 12), 256, 0, stream>>>(
      Tb, Wt3, bq1, bk1, bv1, Qz, Kz, W2, nullptr, MR, 1536, DM);

  // ---- ProbSparse ----
  if (U == 35)
    k_mscore3<35><<<dim3(1024), 256, 0, stream>>>(Qz, Kz, smp, Ms);
  else
    k_mscore3g<<<dim3(1024), 256, 0, stream>>>(Qz, Kz, smp, Ms, U);
  k_topk_w<<<dim3(ZH), 64, 0, stream>>>(Ms, top, U);
  k_qkT<<<dim3(16 * ZH), 256, 0, stream>>>(Qz, Kz, Sbuf, top, U, U, 0.125f);
  k_softmax<<<dim3(ZH * Uld), 256, 0, stream>>>(Sbuf);
  k_pv_split<<<dim3(16 * ZH), 256, 0, stream>>>(Sbuf, W2, Pp);
  k_pv_red<<<dim3(ZH), 256, 0, stream>>>(Pp, upd);
  k_meanv1<<<dim3(ZH * 8), 256, 0, stream>>>(W2, mvp);
  k_ctxfillb<<<dim3(MR * DM / 4 / 256), 256, 0, stream>>>(mvp, Xb);
  k_scatterb<<<dim3(ZH), 256, 0, stream>>>(upd, top, Xb, U, Uld);

  dim3 gsq(MR / 128, DM / 128);
  // ---- out-proj 1 (split-K=2, partials W0/W1) + residual LN (fused reduce) ----
  k_gemm_mfma<20, 0><<<dim3(MR / 128, DM / 128, 2), 256, 0, stream>>>(
      Xb, wo1b, nullptr, nullptr, nullptr, W0, W1, nullptr, nullptr, MR, DM, DM);
  k_ln2<2><<<dim3(MR), 256, 0, stream>>>(W0, W1, nullptr, nullptr,
                                         tgt, bo1, g1, be1, nullptr, Xb);

  // ---- layer-2 projections ----
  k_gemm_mfma<1, 0><<<gsq, 256, 0, stream>>>(
      Xb, wq2b, bq2, nullptr, nullptr, Qb, nullptr, nullptr, nullptr, MR, DM, DM);
  k_gemm_mfma<11, 0><<<dim3(MR / 128, 8), 256, 0, stream>>>(
      Mb, wk2b, bk2, bv2, nullptr, Kb, Vtb, nullptr, nullptr, MR, 1024, DM);

  // ---- fused flash cross attention -> Xb (bf16) ----
  k_flash2<<<dim3(Ls / 128, ZH), 512, 0, stream>>>(Qb, Kb, Vtb, Xb);

  // ---- out-proj 2 (split-K=2) + LN (fused) ----
  k_gemm_mfma<20, 0><<<dim3(MR / 128, DM / 128, 2), 256, 0, stream>>>(
      Xb, wo2b, nullptr, nullptr, nullptr, W0, W2, nullptr, nullptr, MR, DM, DM);
  k_ln2<2><<<dim3(MR), 256, 0, stream>>>(W0, W2, nullptr, nullptr,
                                         nullptr, bo2, g2, be2, W1, Xb);

  // ---- FFN ----
  k_gemm_mfma<1, 1><<<dim3(MR / 128, 4 * DM / 128), 256, 0, stream>>>(
      Xb, c1wb, c1b, nullptr, nullptr, hb, nullptr, nullptr, nullptr, MR, 4 * DM, DM);
  k_gemm_mfma<20, 0><<<dim3(MR / 128, DM / 128, 4), 256, 0, stream>>>(
      hb, c2wb, nullptr, nullptr, nullptr, W0, W2, CP2, CP3, MR, DM, 2 * DM * 2);
  k_ln2<4><<<dim3(MR), 256, 0, stream>>>(W0, W2, CP2, CP3,
                                         W1, c2b, g3, be3, outp, nullptr);
}

// Round 8
// 369.839 us; speedup vs baseline: 5.9366x; 1.1278x over previous
//
#include <hip/hip_runtime.h>
#include <hip/hip_bf16.h>
#include <cstdint>

constexpr int Bb  = 8;
constexpr int Ls  = 1024;
constexpr int DM  = 512;
constexpr int NH  = 8;
constexpr int DHd = 64;
constexpr int MR  = Bb * Ls;   // 8192 rows
constexpr int ZH  = Bb * NH;   // 64 (b,h) pairs

typedef __attribute__((ext_vector_type(8))) short short8v;
typedef __attribute__((ext_vector_type(4))) short short4v;
typedef __attribute__((ext_vector_type(4))) float floatx4;

__device__ inline short f2bf(float x) {
  __hip_bfloat16 h = __float2bfloat16(x);
  return *reinterpret_cast<short*>(&h);
}

#define GLOAD_LDS16(g, l)                                                        \
  __builtin_amdgcn_global_load_lds(                                              \
      (const __attribute__((address_space(1))) void*)(g),                        \
      (__attribute__((address_space(3))) void*)(l), 16, 0, 0)

// ================= bf16 MFMA GEMM: C = act(A @ Wt^T + bias) =================
// MODE: 0 f32 out | 1 bf16 out | 4 bf16 out ×0.125 (flash Q) |
// 10 L1 triple (N=1536: Q->Qz, K->Kz, V->merged f32) |
// 11 L2 KV pair (N=1024: K->Kb swizzled, V->Vt transposed) |
// 20 split-K raw f32 partial (no bias; partial z -> Cout/aux1/aux2/aux3)
template<int MODE, int RELU>
__global__ __launch_bounds__(256) void k_gemm_mfma(
    const __hip_bfloat16* __restrict__ A, const __hip_bfloat16* __restrict__ Wt,
    const float* __restrict__ bias, const float* __restrict__ bias1,
    const float* __restrict__ bias2,
    void* __restrict__ Cout, void* __restrict__ aux1, void* __restrict__ aux2,
    void* __restrict__ aux3,
    int M, int N, int K)
{
  __shared__ __hip_bfloat16 As[128 * 32];
  __shared__ __hip_bfloat16 Bs[128 * 32];
  const int tid = threadIdx.x;
  const int w = tid >> 6, lane = tid & 63;
  const int wr = w >> 1, wc = w & 1;
  const int bm = blockIdx.x * 128, bn = blockIdx.y * 128;
  const int lrow = lane >> 2;
  const int lcol = (lane & 3) * 8;
  const int fr = lane & 15;
  const int fco = (lane >> 4) * 8;
  const short* Ash = (const short*)As;
  const short* Bsh = (const short*)Bs;

  const int ksl = K / gridDim.z;
  const int kb0 = blockIdx.z * ksl;

  floatx4 acc[4][4] = {};
  for (int k0 = kb0; k0 < kb0 + ksl; k0 += 32) {
#pragma unroll
    for (int i = 0; i < 2; ++i) {
      const int chunk = w * 2 + i;
      GLOAD_LDS16(A  + (size_t)(bm + chunk * 16 + lrow) * K + k0 + lcol,
                  As + chunk * 512);
      GLOAD_LDS16(Wt + (size_t)(bn + chunk * 16 + lrow) * K + k0 + lcol,
                  Bs + chunk * 512);
    }
    __syncthreads();
    short8v a[4], b[4];
#pragma unroll
    for (int mi = 0; mi < 4; ++mi)
      a[mi] = *(const short8v*)(Ash + (wr * 64 + mi * 16 + fr) * 32 + fco);
#pragma unroll
    for (int ni = 0; ni < 4; ++ni)
      b[ni] = *(const short8v*)(Bsh + (wc * 64 + ni * 16 + fr) * 32 + fco);
#pragma unroll
    for (int mi = 0; mi < 4; ++mi)
#pragma unroll
      for (int ni = 0; ni < 4; ++ni)
        acc[mi][ni] = __builtin_amdgcn_mfma_f32_16x16x32_bf16(
            a[mi], b[ni], acc[mi][ni], 0, 0, 0);
    __syncthreads();
  }
#pragma unroll
  for (int ni = 0; ni < 4; ++ni) {
    const int cn = bn + wc * 64 + ni * 16 + fr;
    float bv = 0.f;
    if (MODE == 10) {
      const float* bp = (cn < 512) ? bias : (cn < 1024 ? bias1 : bias2);
      bv = bp[cn & 511];
    } else if (MODE == 11) {
      bv = (cn < 512 ? bias : bias1)[cn & 511];
    } else if (MODE != 20) {
      bv = bias[cn];
    }
#pragma unroll
    for (int mi = 0; mi < 4; ++mi) {
#pragma unroll
      for (int j = 0; j < 4; ++j) {
        const int rm = bm + wr * 64 + mi * 16 + (lane >> 4) * 4 + j;
        float v = acc[mi][ni][j] + bv;
        if (RELU) v = fmaxf(v, 0.f);
        if (MODE == 0) {
          ((float*)Cout)[(size_t)rm * N + cn] = v;
        } else if (MODE == 1) {
          ((__hip_bfloat16*)Cout)[(size_t)rm * N + cn] = __float2bfloat16(v);
        } else if (MODE == 4) {
          ((__hip_bfloat16*)Cout)[(size_t)rm * N + cn] = __float2bfloat16(v * 0.125f);
        } else if (MODE == 10) {
          const int sel = cn >> 9, c = cn & 511;
          if (sel == 2) {
            ((float*)aux2)[(size_t)rm * 512 + c] = v;
          } else {
            float* base = sel ? (float*)aux1 : (float*)Cout;
            const int bb = rm >> 10, l = rm & 1023, hh = c >> 6, dd = c & 63;
            base[(((size_t)(bb * 8 + hh)) * 1024 + l) * 64 + dd] = v;
          }
        } else if (MODE == 11) {
          const int c = cn & 511;
          if (cn < 512) {
            const int cs = (c & ~63) | ((c & 63) ^ ((rm & 7) << 3));
            ((__hip_bfloat16*)Cout)[(size_t)rm * 512 + cs] = __float2bfloat16(v);
          } else {
            const int bb = rm >> 10, l = rm & 1023, hh = c >> 6, dd = c & 63;
            ((__hip_bfloat16*)aux1)[(size_t)((bb * 8 + hh) * 64 + dd) * 1024 +
                                    (l ^ ((dd & 7) << 3))] = __float2bfloat16(v);
          }
        } else if (MODE == 20) {
          float* pz = (float*)(blockIdx.z == 0 ? Cout :
                      blockIdx.z == 1 ? aux1 :
                      blockIdx.z == 2 ? aux2 : aux3);
          pz[(size_t)rm * N + cn] = v;
        }
      }
    }
  }
}

// ===== fused flash cross-attention v2: 512 thr, dbuf K/V, defer-max, setprio =====
// Qb pre-scaled by 0.125 (MODE 4 epilogue).
__global__ __launch_bounds__(512) void k_flash2(
    const __hip_bfloat16* __restrict__ Qb,
    const __hip_bfloat16* __restrict__ Kb,
    const __hip_bfloat16* __restrict__ Vt,
    __hip_bfloat16* __restrict__ O)
{
  __shared__ __hip_bfloat16 Ks[2][64 * 64];
  __shared__ __hip_bfloat16 Vs[2][64 * 64];
  __shared__ __hip_bfloat16 Ps[8 * 16 * 72];
  const int tid = threadIdx.x, w = tid >> 6, lane = tid & 63;
  const int g = lane >> 4, r = lane & 15;
  const int z = blockIdx.y, b = z >> 3, h = z & 7;
  const int q0 = blockIdx.x * 128 + w * 16;
  __hip_bfloat16* Pw = Ps + w * 16 * 72;

  const int srow = w * 8 + (lane >> 3);
  const int sseg = lane & 7;

  const short8v qf0 = *(const short8v*)(Qb + (size_t)(b * Ls + q0 + r) * DM + h * DHd + g * 8);
  const short8v qf1 = *(const short8v*)(Qb + (size_t)(b * Ls + q0 + r) * DM + h * DHd + 32 + g * 8);

  floatx4 oacc[4] = {};
  float m_run = -1e30f, l_run = 0.f;

  GLOAD_LDS16(Kb + (size_t)(b * Ls + srow) * DM + h * DHd + sseg * 8, &Ks[0][w * 512]);
  GLOAD_LDS16(Vt + ((size_t)z * DHd + srow) * Ls + sseg * 8, &Vs[0][w * 512]);
  asm volatile("s_waitcnt vmcnt(0)" ::: "memory");
  __builtin_amdgcn_s_barrier();

  int cur = 0;
  for (int t = 0; t < 16; ++t) {
    if (t + 1 < 16) {
      GLOAD_LDS16(Kb + (size_t)(b * Ls + (t + 1) * 64 + srow) * DM + h * DHd + sseg * 8,
                  &Ks[cur ^ 1][w * 512]);
      GLOAD_LDS16(Vt + ((size_t)z * DHd + srow) * Ls + (t + 1) * 64 + sseg * 8,
                  &Vs[cur ^ 1][w * 512]);
    }
    const __hip_bfloat16* Kc = Ks[cur];
    const __hip_bfloat16* Vc = Vs[cur];
    float sv[4][4];
    float tmax = -1e30f;
    __builtin_amdgcn_s_setprio(1);
#pragma unroll
    for (int kt = 0; kt < 4; ++kt) {
      const int key = kt * 16 + r, sw = key & 7;
      short8v a0 = *(const short8v*)(Kc + key * 64 + ((g ^ sw) * 8));
      short8v a1 = *(const short8v*)(Kc + key * 64 + (((4 + g) ^ sw) * 8));
      floatx4 c = {};
      c = __builtin_amdgcn_mfma_f32_16x16x32_bf16(a0, qf0, c, 0, 0, 0);
      c = __builtin_amdgcn_mfma_f32_16x16x32_bf16(a1, qf1, c, 0, 0, 0);
#pragma unroll
      for (int j = 0; j < 4; ++j) {
        float x = c[j];
        sv[kt][j] = x;
        tmax = fmaxf(tmax, x);
      }
    }
    __builtin_amdgcn_s_setprio(0);
    tmax = fmaxf(tmax, __shfl_xor(tmax, 16));
    tmax = fmaxf(tmax, __shfl_xor(tmax, 32));
    float m_new;
    if (__all(tmax <= m_run + 8.0f)) {      // defer-max: keep old max, skip rescale
      m_new = m_run;
    } else {
      m_new = fmaxf(m_run, tmax);
      const float fac = __expf(m_run - m_new);
      float fj[4];
#pragma unroll
      for (int j = 0; j < 4; ++j) fj[j] = __shfl(fac, (lane & 48) | (g * 4 + j));
#pragma unroll
      for (int ct = 0; ct < 4; ++ct)
#pragma unroll
        for (int j = 0; j < 4; ++j) oacc[ct][j] *= fj[j];
      l_run *= fac;
    }
    float psum = 0.f;
#pragma unroll
    for (int kt = 0; kt < 4; ++kt) {
      short4v pk;
#pragma unroll
      for (int j = 0; j < 4; ++j) {
        float p = __expf(sv[kt][j] - m_new);
        psum += p;
        pk[j] = f2bf(p);
      }
      *(short4v*)(Pw + r * 72 + kt * 16 + g * 4) = pk;
    }
    psum += __shfl_xor(psum, 16);
    psum += __shfl_xor(psum, 32);
    l_run += psum;
    m_run = m_new;
    const short8v pa0 = *(const short8v*)(Pw + r * 72 + g * 8);
    const short8v pa1 = *(const short8v*)(Pw + r * 72 + 32 + g * 8);
    __builtin_amdgcn_s_setprio(1);
#pragma unroll
    for (int ct = 0; ct < 4; ++ct) {
      const int d = ct * 16 + r, sw = d & 7;
      short8v v0 = *(const short8v*)(Vc + d * 64 + ((g ^ sw) * 8));
      short8v v1 = *(const short8v*)(Vc + d * 64 + (((4 + g) ^ sw) * 8));
      oacc[ct] = __builtin_amdgcn_mfma_f32_16x16x32_bf16(pa0, v0, oacc[ct], 0, 0, 0);
      oacc[ct] = __builtin_amdgcn_mfma_f32_16x16x32_bf16(pa1, v1, oacc[ct], 0, 0, 0);
    }
    __builtin_amdgcn_s_setprio(0);
    asm volatile("s_waitcnt vmcnt(0)" ::: "memory");
    __builtin_amdgcn_s_barrier();
    cur ^= 1;
  }
  float li[4];
#pragma unroll
  for (int j = 0; j < 4; ++j)
    li[j] = 1.0f / __shfl(l_run, (lane & 48) | (g * 4 + j));
#pragma unroll
  for (int ct = 0; ct < 4; ++ct)
#pragma unroll
    for (int j = 0; j < 4; ++j)
      O[(size_t)(b * Ls + q0 + g * 4 + j) * DM + h * DHd + ct * 16 + r] =
          __float2bfloat16(oacc[ct][j] * li[j]);
}

// ---------------- both input converts in one dispatch ----------------
__global__ __launch_bounds__(256) void k_cvt2(
    const float* __restrict__ in0, const float* __restrict__ in1,
    __hip_bfloat16* __restrict__ o0, __hip_bfloat16* __restrict__ o1)
{
  const size_t half = (size_t)MR * DM / 4;
  size_t i = (size_t)blockIdx.x * 256 + threadIdx.x;
  const float* in = in0; __hip_bfloat16* out = o0;
  if (i >= half) { i -= half; in = in1; out = o1; }
  float4 v = *reinterpret_cast<const float4*>(in + i * 4);
  short4v o;
  o.x = f2bf(v.x); o.y = f2bf(v.y); o.z = f2bf(v.z); o.w = f2bf(v.w);
  *reinterpret_cast<short4v*>(out + i * 4) = o;
}

// ---------------- ALL weight converts in one dispatch ----------------
struct WcvtArgs { const float* s[10]; __hip_bfloat16* d[10]; };
__global__ __launch_bounds__(256) void k_wcvt_all(WcvtArgs a)
{
  __shared__ float t[32][33];
  const int bid = blockIdx.x, tid = threadIdx.x;
  int widx, K, N, kblk, nblk;
  if (bid < 2048) {          // 8 square 512x512 weights, 256 blocks each
    widx = bid >> 8; const int w2 = bid & 255;
    K = 512; N = 512; kblk = w2 & 15; nblk = w2 >> 4;
  } else if (bid < 3072) {   // c1w: 512x2048
    widx = 8; const int w2 = bid - 2048;
    K = 512; N = 2048; kblk = w2 & 15; nblk = w2 >> 4;
  } else {                   // c2w: 2048x512
    widx = 9; const int w2 = bid - 3072;
    K = 2048; N = 512; kblk = w2 & 63; nblk = w2 >> 6;
  }
  const float* W = a.s[widx];
  __hip_bfloat16* Wt = a.d[widx];
  const int k0 = kblk * 32, n0 = nblk * 32;
  const int r = tid >> 3, c = (tid & 7) * 4;
  float4 v = *reinterpret_cast<const float4*>(W + (size_t)(k0 + r) * N + n0 + c);
  t[r][c + 0] = v.x; t[r][c + 1] = v.y; t[r][c + 2] = v.z; t[r][c + 3] = v.w;
  __syncthreads();
  short4v o;
  o.x = f2bf(t[c + 0][r]); o.y = f2bf(t[c + 1][r]);
  o.z = f2bf(t[c + 2][r]); o.w = f2bf(t[c + 3][r]);
  *reinterpret_cast<short4v*>(Wt + (size_t)(n0 + r) * K + k0 + c) = o;
}

// ====== fused prob attention chunk: S=Q[top]K^T, partial softmax, PV ======
// grid 16*ZH (XCD-swizzled). Outputs per (chunk,z): Op[64u][64d], Ml/Ll[64u].
__global__ __launch_bounds__(256) void k_probflash(
    const float* __restrict__ Qz, const float* __restrict__ Kz,
    const float* __restrict__ Vm, const int* __restrict__ top,
    float* __restrict__ Op, float* __restrict__ Ml, float* __restrict__ Ll,
    int U)
{
  __shared__ float Qs[DHd][64 + 4];   // [d][u]; reused as Ss[u][key] later
  __shared__ float Ks[DHd][64 + 4];   // [d][key]
  __shared__ float Vs[64][64];        // [key][d]
  const int bid = blockIdx.x;
  const int swz = (bid & 7) * ((16 * ZH) >> 3) + (bid >> 3);
  const int kc = swz & 15, z = swz >> 4, b = z >> 3, h = z & 7;
  const int tid = threadIdx.x;
  const int k0 = kc * 64;
#pragma unroll
  for (int i = 0; i < 4; ++i) {
    const int idx = tid + (i << 8);
    const int r = idx >> 4, c4 = (idx & 15) << 2;
    int u = r; if (u >= U) u = U - 1;
    const int qr = top[z * U + u];
    float4 q4 = *reinterpret_cast<const float4*>(Qz + ((size_t)z * Ls + qr) * 64 + c4);
    Qs[c4 + 0][r] = q4.x; Qs[c4 + 1][r] = q4.y; Qs[c4 + 2][r] = q4.z; Qs[c4 + 3][r] = q4.w;
    float4 k4 = *reinterpret_cast<const float4*>(Kz + ((size_t)z * Ls + k0 + r) * 64 + c4);
    Ks[c4 + 0][r] = k4.x; Ks[c4 + 1][r] = k4.y; Ks[c4 + 2][r] = k4.z; Ks[c4 + 3][r] = k4.w;
    *reinterpret_cast<float4*>(&Vs[r][c4]) =
        *reinterpret_cast<const float4*>(Vm + ((size_t)(b * Ls + k0 + r)) * DM + h * DHd + c4);
  }
  __syncthreads();
  const int mB = (tid >> 4) << 2, nB = (tid & 15) << 2;
  float acc[4][4] = {};
#pragma unroll
  for (int kk = 0; kk < DHd; ++kk) {
    float4 a4 = *reinterpret_cast<const float4*>(&Qs[kk][mB]);
    float4 b4 = *reinterpret_cast<const float4*>(&Ks[kk][nB]);
    const float av[4] = {a4.x, a4.y, a4.z, a4.w};
#pragma unroll
    for (int i = 0; i < 4; ++i) {
      acc[i][0] += av[i] * b4.x; acc[i][1] += av[i] * b4.y;
      acc[i][2] += av[i] * b4.z; acc[i][3] += av[i] * b4.w;
    }
  }
  __syncthreads();                    // everyone done reading Qs
  float (*Ss)[68] = (float (*)[68])Qs;   // reuse Qs region as S[u][key]
#pragma unroll
  for (int i = 0; i < 4; ++i) {
    float4 o;
    o.x = acc[i][0] * 0.125f; o.y = acc[i][1] * 0.125f;
    o.z = acc[i][2] * 0.125f; o.w = acc[i][3] * 0.125f;
    *reinterpret_cast<float4*>(&Ss[mB + i][nB]) = o;
  }
  __syncthreads();
  // per-row partial softmax: 4 lanes per row, 16 keys each
  {
    const int row = tid >> 2, q = tid & 3;
    float mx = -1e30f;
#pragma unroll
    for (int j = 0; j < 16; ++j) mx = fmaxf(mx, Ss[row][q * 16 + j]);
    mx = fmaxf(mx, __shfl_xor(mx, 1));
    mx = fmaxf(mx, __shfl_xor(mx, 2));
    float se = 0.f;
#pragma unroll
    for (int j = 0; j < 16; ++j) {
      float p = __expf(Ss[row][q * 16 + j] - mx);
      Ss[row][q * 16 + j] = p;
      se += p;
    }
    se += __shfl_xor(se, 1);
    se += __shfl_xor(se, 2);
    if (q == 0) {
      Ml[((size_t)kc * ZH + z) * 64 + row] = mx;
      Ll[((size_t)kc * ZH + z) * 64 + row] = se;
    }
  }
  __syncthreads();
  // PV partial
  const int d = tid & 63, w = tid >> 6;
  float acc2[16] = {};
  for (int k = 0; k < 64; ++k) {
    const float vk = Vs[k][d];
#pragma unroll
    for (int i = 0; i < 16; ++i)
      acc2[i] += Ss[w * 16 + i][k] * vk;
  }
  float* outb = Op + ((size_t)kc * ZH + z) * 4096;
#pragma unroll
  for (int i = 0; i < 16; ++i)
    outb[(w * 16 + i) * 64 + d] = acc2[i];
}

// ------ flash-combine 16 chunks + scatter into bf16 ctx (replaces scatterb) ------
__global__ __launch_bounds__(256) void k_prob_comb(
    const float* __restrict__ Op, const float* __restrict__ Ml,
    const float* __restrict__ Ll, const int* __restrict__ top,
    __hip_bfloat16* __restrict__ ctx, int U)
{
  __shared__ float wsh[16][64];
  __shared__ float Lsh[64];
  const int z = blockIdx.x, b = z >> 3, h = z & 7;
  const int tid = threadIdx.x;
  if (tid < 64) {
    float M = -1e30f;
#pragma unroll
    for (int c = 0; c < 16; ++c)
      M = fmaxf(M, Ml[((size_t)c * ZH + z) * 64 + tid]);
    float L = 0.f;
#pragma unroll
    for (int c = 0; c < 16; ++c) {
      float wv = __expf(Ml[((size_t)c * ZH + z) * 64 + tid] - M);
      wsh[c][tid] = wv;
      L += wv * Ll[((size_t)c * ZH + z) * 64 + tid];
    }
    Lsh[tid] = L;
  }
  __syncthreads();
  for (int e = tid; e < U * 64; e += 256) {
    const int u = e >> 6, d = e & 63;
    float s = 0.f;
#pragma unroll
    for (int c = 0; c < 16; ++c)
      s += wsh[c][u] * Op[((size_t)c * ZH + z) * 4096 + u * 64 + d];
    const int row = top[z * U + u];
    ctx[((size_t)(b * Ls + row)) * DM + h * DHd + d] =
        __float2bfloat16(s / Lsh[u]);
  }
}

// ---------------- ProbSparse sampled scores, compact layout ----------------
template<int UU>
__global__ __launch_bounds__(256) void k_mscore3(
    const float* __restrict__ Qz, const float* __restrict__ Kz,
    const int* __restrict__ smp, float* __restrict__ Ms)
{
  const int bid = blockIdx.x;
  const int swz = (bid & 7) * 128 + (bid >> 3);
  const int gw = swz * 4 + (threadIdx.x >> 6);
  const int lane = threadIdx.x & 63;
  const int li = lane >> 2, dp = (lane & 3) * 16;
  const int l = (gw & 63) * 16 + li;
  const int z = gw >> 6;
  const float* qb = Qz + ((size_t)z * Ls + l) * 64 + dp;
  const float4 q0 = *(const float4*)(qb);
  const float4 q1 = *(const float4*)(qb + 4);
  const float4 q2 = *(const float4*)(qb + 8);
  const float4 q3 = *(const float4*)(qb + 12);
  int kidx[UU];
#pragma unroll
  for (int u = 0; u < UU; ++u) kidx[u] = smp[l * UU + u];
  const float* kzb = Kz + (size_t)z * Ls * 64 + dp;
  float mx = -1e30f, sm = 0.f;
#pragma unroll
  for (int u = 0; u < UU; ++u) {
    const float* kb = kzb + (size_t)kidx[u] * 64;
    const float4 k0 = *(const float4*)(kb);
    const float4 k1 = *(const float4*)(kb + 4);
    const float4 k2 = *(const float4*)(kb + 8);
    const float4 k3 = *(const float4*)(kb + 12);
    float d = q0.x*k0.x + q0.y*k0.y + q0.z*k0.z + q0.w*k0.w
            + q1.x*k1.x + q1.y*k1.y + q1.z*k1.z + q1.w*k1.w
            + q2.x*k2.x + q2.y*k2.y + q2.z*k2.z + q2.w*k2.w
            + q3.x*k3.x + q3.y*k3.y + q3.z*k3.z + q3.w*k3.w;
    d += __shfl_xor(d, 1);
    d += __shfl_xor(d, 2);
    mx = fmaxf(mx, d);
    sm += d;
  }
  if ((lane & 3) == 0) Ms[z * Ls + l] = mx - sm * (1.0f / Ls);
}

// runtime-U fallback
__global__ __launch_bounds__(256) void k_mscore3g(
    const float* __restrict__ Qz, const float* __restrict__ Kz,
    const int* __restrict__ smp, float* __restrict__ Ms, int U)
{
  const int bid = blockIdx.x;
  const int swz = (bid & 7) * 128 + (bid >> 3);
  const int gw = swz * 4 + (threadIdx.x >> 6);
  const int lane = threadIdx.x & 63;
  const int li = lane >> 2, dp = (lane & 3) * 16;
  const int l = (gw & 63) * 16 + li;
  const int z = gw >> 6;
  const float* qb = Qz + ((size_t)z * Ls + l) * 64 + dp;
  const float4 q0 = *(const float4*)(qb);
  const float4 q1 = *(const float4*)(qb + 4);
  const float4 q2 = *(const float4*)(qb + 8);
  const float4 q3 = *(const float4*)(qb + 12);
  const float* kzb = Kz + (size_t)z * Ls * 64 + dp;
  float mx = -1e30f, sm = 0.f;
  for (int u = 0; u < U; ++u) {
    const float* kb = kzb + (size_t)smp[l * U + u] * 64;
    const float4 k0 = *(const float4*)(kb);
    const float4 k1 = *(const float4*)(kb + 4);
    const float4 k2 = *(const float4*)(kb + 8);
    const float4 k3 = *(const float4*)(kb + 12);
    float d = q0.x*k0.x + q0.y*k0.y + q0.z*k0.z + q0.w*k0.w
            + q1.x*k1.x + q1.y*k1.y + q1.z*k1.z + q1.w*k1.w
            + q2.x*k2.x + q2.y*k2.y + q2.z*k2.z + q2.w*k2.w
            + q3.x*k3.x + q3.y*k3.y + q3.z*k3.z + q3.w*k3.w;
    d += __shfl_xor(d, 1);
    d += __shfl_xor(d, 2);
    mx = fmaxf(mx, d);
    sm += d;
  }
  if ((lane & 3) == 0) Ms[z * Ls + l] = mx - sm * (1.0f / Ls);
}

// ---------------- wave-parallel top-U ----------------
__global__ __launch_bounds__(64) void k_topk_w(
    const float* __restrict__ Ms, int* __restrict__ top, int U)
{
  const int z = blockIdx.x, lane = threadIdx.x;
  float v[16];
#pragma unroll
  for (int j = 0; j < 16; ++j) v[j] = Ms[z * Ls + j * 64 + lane];
  for (int it = 0; it < U; ++it) {
    float bv = -1e30f; int bi = 0x7fffffff;
#pragma unroll
    for (int j = 0; j < 16; ++j) {
      const int idx = j * 64 + lane;
      if (v[j] > bv) { bv = v[j]; bi = idx; }
    }
#pragma unroll
    for (int off = 1; off < 64; off <<= 1) {
      const float ov = __shfl_xor(bv, off);
      const int   oi = __shfl_xor(bi, off);
      if (ov > bv || (ov == bv && oi < bi)) { bv = ov; bi = oi; }
    }
    if (lane == 0) top[z * U + it] = bi;
    if ((bi & 63) == lane) v[bi >> 6] = -1e30f;
  }
}

// ---------------- mean of V: stage 1 ----------------
__global__ __launch_bounds__(256) void k_meanv1(
    const float* __restrict__ Vm, float* __restrict__ mvp)
{
  __shared__ float ps[4][64];
  const int gid = blockIdx.x, z = gid >> 3, c = gid & 7, b = z >> 3, h = z & 7;
  const int d = threadIdx.x & 63, g = threadIdx.x >> 6;
  float s = 0.f;
  const int kb = c * 128 + g * 32;
  for (int k = kb; k < kb + 32; ++k)
    s += Vm[((size_t)(b * Ls + k)) * DM + h * DHd + d];
  ps[g][d] = s;
  __syncthreads();
  if (g == 0) mvp[(z * 8 + c) * 64 + d] = ps[0][d] + ps[1][d] + ps[2][d] + ps[3][d];
}

// ---------------- broadcast mean-V into bf16 ctx ----------------
__global__ __launch_bounds__(256) void k_ctxfillb(
    const float* __restrict__ mvp, __hip_bfloat16* __restrict__ ctx)
{
  const int i = blockIdx.x * 256 + threadIdx.x;
  const int c4 = (i & 127) << 2;
  const int row = i >> 7;
  const int b = row >> 10;
  const int h = c4 >> 6;
  const float* base = mvp + ((b * 8 + h) * 8) * 64 + (c4 & 63);
  float4 a = {0.f, 0.f, 0.f, 0.f};
#pragma unroll
  for (int c = 0; c < 8; ++c) {
    float4 m4 = *reinterpret_cast<const float4*>(base + c * 64);
    a.x += m4.x; a.y += m4.y; a.z += m4.z; a.w += m4.w;
  }
  const float inv = 1.0f / Ls;
  short4v o;
  o.x = f2bf(a.x * inv); o.y = f2bf(a.y * inv);
  o.z = f2bf(a.z * inv); o.w = f2bf(a.w * inv);
  *reinterpret_cast<short4v*>(ctx + (size_t)row * DM + c4) = o;
}

// ------- LayerNorm over sum of NP partials (+bias) (+residual) -------
template<int NP>
__global__ __launch_bounds__(256) void k_ln2(
    const float* __restrict__ x0, const float* __restrict__ x1,
    const float* __restrict__ x2, const float* __restrict__ x3,
    const float* __restrict__ res, const float* __restrict__ bias,
    const float* __restrict__ g, const float* __restrict__ be,
    float* __restrict__ outf, __hip_bfloat16* __restrict__ outb)
{
  __shared__ float red[4];
  const int row = blockIdx.x, tid = threadIdx.x;
  const size_t base = (size_t)row * DM;
  float2 v = *reinterpret_cast<const float2*>(x0 + base + tid * 2);
  if (NP > 1) {
    float2 a = *reinterpret_cast<const float2*>(x1 + base + tid * 2);
    v.x += a.x; v.y += a.y;
  }
  if (NP > 2) {
    float2 a = *reinterpret_cast<const float2*>(x2 + base + tid * 2);
    v.x += a.x; v.y += a.y;
  }
  if (NP > 3) {
    float2 a = *reinterpret_cast<const float2*>(x3 + base + tid * 2);
    v.x += a.x; v.y += a.y;
  }
  if (bias) {
    float2 a = *reinterpret_cast<const float2*>(bias + tid * 2);
    v.x += a.x; v.y += a.y;
  }
  if (res) {
    float2 r2 = *reinterpret_cast<const float2*>(res + base + tid * 2);
    v.x += r2.x; v.y += r2.y;
  }
  float s = v.x + v.y;
#pragma unroll
  for (int off = 32; off; off >>= 1) s += __shfl_xor(s, off);
  if ((tid & 63) == 0) red[tid >> 6] = s;
  __syncthreads();
  s = red[0] + red[1] + red[2] + red[3];
  const float mean = s * (1.0f / DM);
  __syncthreads();
  float dx = v.x - mean, dy = v.y - mean;
  float q = dx * dx + dy * dy;
#pragma unroll
  for (int off = 32; off; off >>= 1) q += __shfl_xor(q, off);
  if ((tid & 63) == 0) red[tid >> 6] = q;
  __syncthreads();
  q = red[0] + red[1] + red[2] + red[3];
  const float inv = rsqrtf(q * (1.0f / DM) + 1e-5f);
  float2 gg = *reinterpret_cast<const float2*>(g + tid * 2);
  float2 bb = *reinterpret_cast<const float2*>(be + tid * 2);
  float ox = dx * inv * gg.x + bb.x;
  float oy = dy * inv * gg.y + bb.y;
  if (outf) {
    float2 o; o.x = ox; o.y = oy;
    *reinterpret_cast<float2*>(outf + base + tid * 2) = o;
  }
  if (outb) {
    short2 ob; ob.x = f2bf(ox); ob.y = f2bf(oy);
    *reinterpret_cast<short2*>(outb + base + tid * 2) = ob;
  }
}

extern "C" void kernel_launch(void* const* d_in, const int* in_sizes, int n_in,
                              void* d_out, int out_size, void* d_ws, size_t ws_size,
                              hipStream_t stream)
{
  const float* tgt = (const float*)d_in[0];
  const float* mem = (const float*)d_in[1];
  const int*   smp = (const int*)d_in[2];
  const float* wq1 = (const float*)d_in[3];  const float* bq1 = (const float*)d_in[4];
  const float* wk1 = (const float*)d_in[5];  const float* bk1 = (const float*)d_in[6];
  const float* wv1 = (const float*)d_in[7];  const float* bv1 = (const float*)d_in[8];
  const float* wo1 = (const float*)d_in[9];  const float* bo1 = (const float*)d_in[10];
  const float* wq2 = (const float*)d_in[11]; const float* bq2 = (const float*)d_in[12];
  const float* wk2 = (const float*)d_in[13]; const float* bk2 = (const float*)d_in[14];
  const float* wv2 = (const float*)d_in[15]; const float* bv2 = (const float*)d_in[16];
  const float* wo2 = (const float*)d_in[17]; const float* bo2 = (const float*)d_in[18];
  const float* c1w = (const float*)d_in[19]; const float* c1b = (const float*)d_in[20];
  const float* c2w = (const float*)d_in[21]; const float* c2b = (const float*)d_in[22];
  const float* g1  = (const float*)d_in[23]; const float* be1 = (const float*)d_in[24];
  const float* g2  = (const float*)d_in[25]; const float* be2 = (const float*)d_in[26];
  const float* g3  = (const float*)d_in[27]; const float* be3 = (const float*)d_in[28];
  float* outp = (float*)d_out;

  const int U   = in_sizes[2] / Ls;            // 35

  char* ws = (char*)d_ws;
  const size_t SZ = (size_t)MR * DM * sizeof(float);       // 16.78 MB
  float* Qz   = (float*)(ws);
  float* Kz   = (float*)(ws + SZ);
  float* W0   = Qz;
  float* W1   = Kz;
  float* W2   = (float*)(ws + 2 * SZ);
  float* Sbuf = (float*)(ws + 3 * SZ);                     // FFN hidden region
  float* Op   = Sbuf + (size_t)ZH * 64 * Ls;               // prob PV partials (16.8 MB)
  __hip_bfloat16* Tb  = (__hip_bfloat16*)(ws + 5 * SZ);
  __hip_bfloat16* Mb  = (__hip_bfloat16*)(ws + 5 * SZ + SZ / 2);
  __hip_bfloat16* Xb  = (__hip_bfloat16*)(ws + 6 * SZ);
  __hip_bfloat16* Vtb = (__hip_bfloat16*)(ws + 6 * SZ + SZ / 2);
  __hip_bfloat16* Wt3 = Vtb;                 // [wq1b;wk1b;wv1b] (dead before Vtb written)
  float* CP2 = (float*)(ws + 5 * SZ);        // conv2 partial 2
  float* CP3 = (float*)(ws + 6 * SZ);        // conv2 partial 3
  char* tail = ws + 7 * SZ;
  __hip_bfloat16* wo1b = (__hip_bfloat16*)tail; tail += DM * DM * 2;
  __hip_bfloat16* wq2b = (__hip_bfloat16*)tail; tail += DM * DM * 2;
  __hip_bfloat16* wk2b = (__hip_bfloat16*)tail; tail += DM * DM * 2;
  __hip_bfloat16* wv2b = (__hip_bfloat16*)tail; tail += DM * DM * 2;
  __hip_bfloat16* wo2b = (__hip_bfloat16*)tail; tail += DM * DM * 2;
  __hip_bfloat16* c1wb = (__hip_bfloat16*)tail; tail += DM * 4 * DM * 2;
  __hip_bfloat16* c2wb = (__hip_bfloat16*)tail; tail += DM * 4 * DM * 2;
  float* Ms  = (float*)tail; tail += (size_t)ZH * Ls * 4;
  int*   top = (int*)tail;   tail += (size_t)ZH * 64 * 4;
  float* mvp = (float*)tail; tail += (size_t)ZH * 8 * DHd * 4;
  float* Ml  = (float*)tail; tail += (size_t)16 * ZH * 64 * 4;
  float* Ll  = (float*)tail; tail += (size_t)16 * ZH * 64 * 4;
  __hip_bfloat16* Kb = Tb;
  __hip_bfloat16* Qb = (__hip_bfloat16*)d_out;  // parked until final LN
  __hip_bfloat16* hb = (__hip_bfloat16*)Sbuf;

  // ---- one-time converts (2 dispatches total) ----
  k_cvt2<<<dim3(2 * MR * DM / 4 / 256), 256, 0, stream>>>(tgt, mem, Tb, Mb);
  WcvtArgs wa;
  wa.s[0] = wq1; wa.d[0] = Wt3;
  wa.s[1] = wk1; wa.d[1] = Wt3 + DM * DM;
  wa.s[2] = wv1; wa.d[2] = Wt3 + 2 * DM * DM;
  wa.s[3] = wo1; wa.d[3] = wo1b;
  wa.s[4] = wq2; wa.d[4] = wq2b;
  wa.s[5] = wk2; wa.d[5] = wk2b;
  wa.s[6] = wv2; wa.d[6] = wv2b;
  wa.s[7] = wo2; wa.d[7] = wo2b;
  wa.s[8] = c1w; wa.d[8] = c1wb;
  wa.s[9] = c2w; wa.d[9] = c2wb;
  k_wcvt_all<<<dim3(4096), 256, 0, stream>>>(wa);

  // ---- layer-1 projections: ONE batched GEMM (Q->Qz, K->Kz, V->W2) ----
  k_gemm_mfma<10, 0><<<dim3(MR / 128, 12), 256, 0, stream>>>(
      Tb, Wt3, bq1, bk1, bv1, Qz, Kz, W2, nullptr, MR, 1536, DM);

  // ---- ProbSparse ----
  if (U == 35)
    k_mscore3<35><<<dim3(1024), 256, 0, stream>>>(Qz, Kz, smp, Ms);
  else
    k_mscore3g<<<dim3(1024), 256, 0, stream>>>(Qz, Kz, smp, Ms, U);
  k_topk_w<<<dim3(ZH), 64, 0, stream>>>(Ms, top, U);
  k_probflash<<<dim3(16 * ZH), 256, 0, stream>>>(Qz, Kz, W2, top, Op, Ml, Ll, U);
  k_meanv1<<<dim3(ZH * 8), 256, 0, stream>>>(W2, mvp);
  k_ctxfillb<<<dim3(MR * DM / 4 / 256), 256, 0, stream>>>(mvp, Xb);
  k_prob_comb<<<dim3(ZH), 256, 0, stream>>>(Op, Ml, Ll, top, Xb, U);

  dim3 gsq(MR / 128, DM / 128);
  // ---- out-proj 1 (split-K=2) + residual LN (fused reduce) ----
  k_gemm_mfma<20, 0><<<dim3(MR / 128, DM / 128, 2), 256, 0, stream>>>(
      Xb, wo1b, nullptr, nullptr, nullptr, W0, W1, nullptr, nullptr, MR, DM, DM);
  k_ln2<2><<<dim3(MR), 256, 0, stream>>>(W0, W1, nullptr, nullptr,
                                         tgt, bo1, g1, be1, nullptr, Xb);

  // ---- layer-2 projections (Q pre-scaled by 0.125 via MODE 4) ----
  k_gemm_mfma<4, 0><<<gsq, 256, 0, stream>>>(
      Xb, wq2b, bq2, nullptr, nullptr, Qb, nullptr, nullptr, nullptr, MR, DM, DM);
  k_gemm_mfma<11, 0><<<dim3(MR / 128, 8), 256, 0, stream>>>(
      Mb, wk2b, bk2, bv2, nullptr, Kb, Vtb, nullptr, nullptr, MR, 1024, DM);

  // ---- fused flash cross attention -> Xb (bf16) ----
  k_flash2<<<dim3(Ls / 128, ZH), 512, 0, stream>>>(Qb, Kb, Vtb, Xb);

  // ---- out-proj 2 (split-K=2) + LN (fused) ----
  k_gemm_mfma<20, 0><<<dim3(MR / 128, DM / 128, 2), 256, 0, stream>>>(
      Xb, wo2b, nullptr, nullptr, nullptr, W0, W2, nullptr, nullptr, MR, DM, DM);
  k_ln2<2><<<dim3(MR), 256, 0, stream>>>(W0, W2, nullptr, nullptr,
                                         nullptr, bo2, g2, be2, W1, Xb);

  // ---- FFN ----
  k_gemm_mfma<1, 1><<<dim3(MR / 128, 4 * DM / 128), 256, 0, stream>>>(
      Xb, c1wb, c1b, nullptr, nullptr, hb, nullptr, nullptr, nullptr, MR, 4 * DM, DM);
  k_gemm_mfma<20, 0><<<dim3(MR / 128, DM / 128, 4), 256, 0, stream>>>(
      hb, c2wb, nullptr, nullptr, nullptr, W0, W2, CP2, CP3, MR, DM, 2 * DM * 2);
  k_ln2<4><<<dim3(MR), 256, 0, stream>>>(W0, W2, CP2, CP3,
                                         W1, c2b, g3, be3, outp, nullptr);
}

// Round 9
// 345.521 us; speedup vs baseline: 6.3544x; 1.0704x over previous
//
#include <hip/hip_runtime.h>
#include <hip/hip_bf16.h>
#include <cstdint>

constexpr int Bb  = 8;
constexpr int Ls  = 1024;
constexpr int DM  = 512;
constexpr int NH  = 8;
constexpr int DHd = 64;
constexpr int MR  = Bb * Ls;   // 8192 rows
constexpr int ZH  = Bb * NH;   // 64 (b,h) pairs

typedef __attribute__((ext_vector_type(8))) short short8v;
typedef __attribute__((ext_vector_type(4))) short short4v;
typedef __attribute__((ext_vector_type(4))) float floatx4;

__device__ inline short f2bf(float x) {
  __hip_bfloat16 h = __float2bfloat16(x);
  return *reinterpret_cast<short*>(&h);
}
__device__ inline float bf2f(short s) {
  return __uint_as_float(((uint32_t)(uint16_t)s) << 16);
}

#define GLOAD_LDS16(g, l)                                                        \
  __builtin_amdgcn_global_load_lds(                                              \
      (const __attribute__((address_space(1))) void*)(g),                        \
      (__attribute__((address_space(3))) void*)(l), 16, 0, 0)

// ================= bf16 MFMA GEMM: C = act(A @ Wt^T + bias) =================
// MODE: 1 bf16 out |
// 10 L1 triple (N=1536: Q->Qz f32 + Qzb bf16, K->Kz f32 + Kzb bf16, V->merged f32)
//    aux3 = QKzb base (Qzb, then Kzb at +ZH*Ls*64)
// 12 L2 triple (N=1536: Q(x1)->Qb bf16 x0.125, K(mem)->Kb swizzled, V(mem)->Vt
//    transposed); aux3 = second A matrix (mem) used for bn>=512
// 20 split-K raw f32 partial (no bias; partial z -> Cout/aux1/aux2/aux3)
template<int MODE, int RELU>
__global__ __launch_bounds__(256) void k_gemm_mfma(
    const __hip_bfloat16* __restrict__ A, const __hip_bfloat16* __restrict__ Wt,
    const float* __restrict__ bias, const float* __restrict__ bias1,
    const float* __restrict__ bias2,
    void* __restrict__ Cout, void* __restrict__ aux1, void* __restrict__ aux2,
    void* __restrict__ aux3,
    int M, int N, int K)
{
  __shared__ __hip_bfloat16 As[128 * 32];
  __shared__ __hip_bfloat16 Bs[128 * 32];
  const int tid = threadIdx.x;
  const int w = tid >> 6, lane = tid & 63;
  const int wr = w >> 1, wc = w & 1;
  const int bm = blockIdx.x * 128, bn = blockIdx.y * 128;
  const int lrow = lane >> 2;
  const int lcol = (lane & 3) * 8;
  const int fr = lane & 15;
  const int fco = (lane >> 4) * 8;
  const short* Ash = (const short*)As;
  const short* Bsh = (const short*)Bs;

  const __hip_bfloat16* Asrc = A;
  if (MODE == 12 && bn >= 512) Asrc = (const __hip_bfloat16*)aux3;

  const int ksl = K / gridDim.z;
  const int kb0 = blockIdx.z * ksl;

  floatx4 acc[4][4] = {};
  for (int k0 = kb0; k0 < kb0 + ksl; k0 += 32) {
#pragma unroll
    for (int i = 0; i < 2; ++i) {
      const int chunk = w * 2 + i;
      GLOAD_LDS16(Asrc + (size_t)(bm + chunk * 16 + lrow) * K + k0 + lcol,
                  As + chunk * 512);
      GLOAD_LDS16(Wt + (size_t)(bn + chunk * 16 + lrow) * K + k0 + lcol,
                  Bs + chunk * 512);
    }
    __syncthreads();
    short8v a[4], b[4];
#pragma unroll
    for (int mi = 0; mi < 4; ++mi)
      a[mi] = *(const short8v*)(Ash + (wr * 64 + mi * 16 + fr) * 32 + fco);
#pragma unroll
    for (int ni = 0; ni < 4; ++ni)
      b[ni] = *(const short8v*)(Bsh + (wc * 64 + ni * 16 + fr) * 32 + fco);
#pragma unroll
    for (int mi = 0; mi < 4; ++mi)
#pragma unroll
      for (int ni = 0; ni < 4; ++ni)
        acc[mi][ni] = __builtin_amdgcn_mfma_f32_16x16x32_bf16(
            a[mi], b[ni], acc[mi][ni], 0, 0, 0);
    __syncthreads();
  }
#pragma unroll
  for (int ni = 0; ni < 4; ++ni) {
    const int cn = bn + wc * 64 + ni * 16 + fr;
    float bv = 0.f;
    if (MODE == 10 || MODE == 12) {
      const float* bp = (cn < 512) ? bias : (cn < 1024 ? bias1 : bias2);
      bv = bp[cn & 511];
    } else if (MODE != 20) {
      bv = bias[cn];
    }
#pragma unroll
    for (int mi = 0; mi < 4; ++mi) {
#pragma unroll
      for (int j = 0; j < 4; ++j) {
        const int rm = bm + wr * 64 + mi * 16 + (lane >> 4) * 4 + j;
        float v = acc[mi][ni][j] + bv;
        if (RELU) v = fmaxf(v, 0.f);
        if (MODE == 1) {
          ((__hip_bfloat16*)Cout)[(size_t)rm * N + cn] = __float2bfloat16(v);
        } else if (MODE == 10) {
          const int sel = cn >> 9, c = cn & 511;
          if (sel == 2) {
            ((float*)aux2)[(size_t)rm * 512 + c] = v;
          } else {
            const int bb = rm >> 10, l = rm & 1023, hh = c >> 6, dd = c & 63;
            const size_t ci = (((size_t)(bb * 8 + hh)) * 1024 + l) * 64 + dd;
            float* base = sel ? (float*)aux1 : (float*)Cout;
            base[ci] = v;
            __hip_bfloat16* bb16 = (__hip_bfloat16*)aux3 +
                                   (sel ? (size_t)ZH * Ls * 64 : 0);
            bb16[ci] = __float2bfloat16(v);
          }
        } else if (MODE == 12) {
          const int sel = cn >> 9, c = cn & 511;
          if (sel == 0) {
            ((__hip_bfloat16*)Cout)[(size_t)rm * 512 + c] =
                __float2bfloat16(v * 0.125f);
          } else if (sel == 1) {
            const int cs = (c & ~63) | ((c & 63) ^ ((rm & 7) << 3));
            ((__hip_bfloat16*)aux1)[(size_t)rm * 512 + cs] = __float2bfloat16(v);
          } else {
            const int bb = rm >> 10, l = rm & 1023, hh = c >> 6, dd = c & 63;
            ((__hip_bfloat16*)aux2)[(size_t)((bb * 8 + hh) * 64 + dd) * 1024 +
                                    (l ^ ((dd & 7) << 3))] = __float2bfloat16(v);
          }
        } else if (MODE == 20) {
          float* pz = (float*)(blockIdx.z == 0 ? Cout :
                      blockIdx.z == 1 ? aux1 :
                      blockIdx.z == 2 ? aux2 : aux3);
          pz[(size_t)rm * N + cn] = v;
        }
      }
    }
  }
}

// ===== fused flash cross-attention v2: 512 thr, dbuf K/V, defer-max, setprio =====
// Qb pre-scaled by 0.125.
__global__ __launch_bounds__(512) void k_flash2(
    const __hip_bfloat16* __restrict__ Qb,
    const __hip_bfloat16* __restrict__ Kb,
    const __hip_bfloat16* __restrict__ Vt,
    __hip_bfloat16* __restrict__ O)
{
  __shared__ __hip_bfloat16 Ks[2][64 * 64];
  __shared__ __hip_bfloat16 Vs[2][64 * 64];
  __shared__ __hip_bfloat16 Ps[8 * 16 * 72];
  const int tid = threadIdx.x, w = tid >> 6, lane = tid & 63;
  const int g = lane >> 4, r = lane & 15;
  const int z = blockIdx.y, b = z >> 3, h = z & 7;
  const int q0 = blockIdx.x * 128 + w * 16;
  __hip_bfloat16* Pw = Ps + w * 16 * 72;

  const int srow = w * 8 + (lane >> 3);
  const int sseg = lane & 7;

  const short8v qf0 = *(const short8v*)(Qb + (size_t)(b * Ls + q0 + r) * DM + h * DHd + g * 8);
  const short8v qf1 = *(const short8v*)(Qb + (size_t)(b * Ls + q0 + r) * DM + h * DHd + 32 + g * 8);

  floatx4 oacc[4] = {};
  float m_run = -1e30f, l_run = 0.f;

  GLOAD_LDS16(Kb + (size_t)(b * Ls + srow) * DM + h * DHd + sseg * 8, &Ks[0][w * 512]);
  GLOAD_LDS16(Vt + ((size_t)z * DHd + srow) * Ls + sseg * 8, &Vs[0][w * 512]);
  asm volatile("s_waitcnt vmcnt(0)" ::: "memory");
  __builtin_amdgcn_s_barrier();

  int cur = 0;
  for (int t = 0; t < 16; ++t) {
    if (t + 1 < 16) {
      GLOAD_LDS16(Kb + (size_t)(b * Ls + (t + 1) * 64 + srow) * DM + h * DHd + sseg * 8,
                  &Ks[cur ^ 1][w * 512]);
      GLOAD_LDS16(Vt + ((size_t)z * DHd + srow) * Ls + (t + 1) * 64 + sseg * 8,
                  &Vs[cur ^ 1][w * 512]);
    }
    const __hip_bfloat16* Kc = Ks[cur];
    const __hip_bfloat16* Vc = Vs[cur];
    float sv[4][4];
    float tmax = -1e30f;
    __builtin_amdgcn_s_setprio(1);
#pragma unroll
    for (int kt = 0; kt < 4; ++kt) {
      const int key = kt * 16 + r, sw = key & 7;
      short8v a0 = *(const short8v*)(Kc + key * 64 + ((g ^ sw) * 8));
      short8v a1 = *(const short8v*)(Kc + key * 64 + (((4 + g) ^ sw) * 8));
      floatx4 c = {};
      c = __builtin_amdgcn_mfma_f32_16x16x32_bf16(a0, qf0, c, 0, 0, 0);
      c = __builtin_amdgcn_mfma_f32_16x16x32_bf16(a1, qf1, c, 0, 0, 0);
#pragma unroll
      for (int j = 0; j < 4; ++j) {
        float x = c[j];
        sv[kt][j] = x;
        tmax = fmaxf(tmax, x);
      }
    }
    __builtin_amdgcn_s_setprio(0);
    tmax = fmaxf(tmax, __shfl_xor(tmax, 16));
    tmax = fmaxf(tmax, __shfl_xor(tmax, 32));
    float m_new;
    if (__all(tmax <= m_run + 8.0f)) {
      m_new = m_run;
    } else {
      m_new = fmaxf(m_run, tmax);
      const float fac = __expf(m_run - m_new);
      float fj[4];
#pragma unroll
      for (int j = 0; j < 4; ++j) fj[j] = __shfl(fac, (lane & 48) | (g * 4 + j));
#pragma unroll
      for (int ct = 0; ct < 4; ++ct)
#pragma unroll
        for (int j = 0; j < 4; ++j) oacc[ct][j] *= fj[j];
      l_run *= fac;
    }
    float psum = 0.f;
#pragma unroll
    for (int kt = 0; kt < 4; ++kt) {
      short4v pk;
#pragma unroll
      for (int j = 0; j < 4; ++j) {
        float p = __expf(sv[kt][j] - m_new);
        psum += p;
        pk[j] = f2bf(p);
      }
      *(short4v*)(Pw + r * 72 + kt * 16 + g * 4) = pk;
    }
    psum += __shfl_xor(psum, 16);
    psum += __shfl_xor(psum, 32);
    l_run += psum;
    m_run = m_new;
    const short8v pa0 = *(const short8v*)(Pw + r * 72 + g * 8);
    const short8v pa1 = *(const short8v*)(Pw + r * 72 + 32 + g * 8);
    __builtin_amdgcn_s_setprio(1);
#pragma unroll
    for (int ct = 0; ct < 4; ++ct) {
      const int d = ct * 16 + r, sw = d & 7;
      short8v v0 = *(const short8v*)(Vc + d * 64 + ((g ^ sw) * 8));
      short8v v1 = *(const short8v*)(Vc + d * 64 + (((4 + g) ^ sw) * 8));
      oacc[ct] = __builtin_amdgcn_mfma_f32_16x16x32_bf16(pa0, v0, oacc[ct], 0, 0, 0);
      oacc[ct] = __builtin_amdgcn_mfma_f32_16x16x32_bf16(pa1, v1, oacc[ct], 0, 0, 0);
    }
    __builtin_amdgcn_s_setprio(0);
    asm volatile("s_waitcnt vmcnt(0)" ::: "memory");
    __builtin_amdgcn_s_barrier();
    cur ^= 1;
  }
  float li[4];
#pragma unroll
  for (int j = 0; j < 4; ++j)
    li[j] = 1.0f / __shfl(l_run, (lane & 48) | (g * 4 + j));
#pragma unroll
  for (int ct = 0; ct < 4; ++ct)
#pragma unroll
    for (int j = 0; j < 4; ++j)
      O[(size_t)(b * Ls + q0 + g * 4 + j) * DM + h * DHd + ct * 16 + r] =
          __float2bfloat16(oacc[ct][j] * li[j]);
}

// ---------------- ALL converts (2 activations + 10 weights) in one dispatch ----------------
struct CvtArgs { const float* s[12]; __hip_bfloat16* d[12]; };
__global__ __launch_bounds__(256) void k_cvt_all(CvtArgs a)
{
  const int bid = blockIdx.x, tid = threadIdx.x;
  if (bid < 8192) {      // activations: s[10]=tgt->d[10], s[11]=mem->d[11]
    const size_t half = (size_t)MR * DM / 4;
    size_t i = (size_t)bid * 256 + tid;
    const float* in = a.s[10]; __hip_bfloat16* out = a.d[10];
    if (i >= half) { i -= half; in = a.s[11]; out = a.d[11]; }
    float4 v = *reinterpret_cast<const float4*>(in + i * 4);
    short4v o;
    o.x = f2bf(v.x); o.y = f2bf(v.y); o.z = f2bf(v.z); o.w = f2bf(v.w);
    *reinterpret_cast<short4v*>(out + i * 4) = o;
    return;
  }
  __shared__ float t[32][33];
  const int wb = bid - 8192;
  int widx, K, N, kblk, nblk;
  if (wb < 2048) {
    widx = wb >> 8; const int w2 = wb & 255;
    K = 512; N = 512; kblk = w2 & 15; nblk = w2 >> 4;
  } else if (wb < 3072) {
    widx = 8; const int w2 = wb - 2048;
    K = 512; N = 2048; kblk = w2 & 15; nblk = w2 >> 4;
  } else {
    widx = 9; const int w2 = wb - 3072;
    K = 2048; N = 512; kblk = w2 & 63; nblk = w2 >> 6;
  }
  const float* W = a.s[widx];
  __hip_bfloat16* Wt = a.d[widx];
  const int k0 = kblk * 32, n0 = nblk * 32;
  const int r = tid >> 3, c = (tid & 7) * 4;
  float4 v = *reinterpret_cast<const float4*>(W + (size_t)(k0 + r) * N + n0 + c);
  t[r][c + 0] = v.x; t[r][c + 1] = v.y; t[r][c + 2] = v.z; t[r][c + 3] = v.w;
  __syncthreads();
  short4v o;
  o.x = f2bf(t[c + 0][r]); o.y = f2bf(t[c + 1][r]);
  o.z = f2bf(t[c + 2][r]); o.w = f2bf(t[c + 3][r]);
  *reinterpret_cast<short4v*>(Wt + (size_t)(n0 + r) * K + k0 + c) = o;
}

// ====== fused prob attention chunk: S=Q[top]K^T, partial softmax, PV ======
__global__ __launch_bounds__(256) void k_probflash(
    const float* __restrict__ Qz, const float* __restrict__ Kz,
    const float* __restrict__ Vm, const int* __restrict__ top,
    float* __restrict__ Op, float* __restrict__ Ml, float* __restrict__ Ll,
    int U)
{
  __shared__ float Qs[DHd][64 + 4];
  __shared__ float Ks[DHd][64 + 4];
  __shared__ float Vs[64][64];
  const int bid = blockIdx.x;
  const int swz = (bid & 7) * ((16 * ZH) >> 3) + (bid >> 3);
  const int kc = swz & 15, z = swz >> 4, b = z >> 3, h = z & 7;
  const int tid = threadIdx.x;
  const int k0 = kc * 64;
#pragma unroll
  for (int i = 0; i < 4; ++i) {
    const int idx = tid + (i << 8);
    const int r = idx >> 4, c4 = (idx & 15) << 2;
    int u = r; if (u >= U) u = U - 1;
    const int qr = top[z * U + u];
    float4 q4 = *reinterpret_cast<const float4*>(Qz + ((size_t)z * Ls + qr) * 64 + c4);
    Qs[c4 + 0][r] = q4.x; Qs[c4 + 1][r] = q4.y; Qs[c4 + 2][r] = q4.z; Qs[c4 + 3][r] = q4.w;
    float4 k4 = *reinterpret_cast<const float4*>(Kz + ((size_t)z * Ls + k0 + r) * 64 + c4);
    Ks[c4 + 0][r] = k4.x; Ks[c4 + 1][r] = k4.y; Ks[c4 + 2][r] = k4.z; Ks[c4 + 3][r] = k4.w;
    *reinterpret_cast<float4*>(&Vs[r][c4]) =
        *reinterpret_cast<const float4*>(Vm + ((size_t)(b * Ls + k0 + r)) * DM + h * DHd + c4);
  }
  __syncthreads();
  const int mB = (tid >> 4) << 2, nB = (tid & 15) << 2;
  float acc[4][4] = {};
#pragma unroll
  for (int kk = 0; kk < DHd; ++kk) {
    float4 a4 = *reinterpret_cast<const float4*>(&Qs[kk][mB]);
    float4 b4 = *reinterpret_cast<const float4*>(&Ks[kk][nB]);
    const float av[4] = {a4.x, a4.y, a4.z, a4.w};
#pragma unroll
    for (int i = 0; i < 4; ++i) {
      acc[i][0] += av[i] * b4.x; acc[i][1] += av[i] * b4.y;
      acc[i][2] += av[i] * b4.z; acc[i][3] += av[i] * b4.w;
    }
  }
  __syncthreads();
  float (*Ss)[68] = (float (*)[68])Qs;
#pragma unroll
  for (int i = 0; i < 4; ++i) {
    float4 o;
    o.x = acc[i][0] * 0.125f; o.y = acc[i][1] * 0.125f;
    o.z = acc[i][2] * 0.125f; o.w = acc[i][3] * 0.125f;
    *reinterpret_cast<float4*>(&Ss[mB + i][nB]) = o;
  }
  __syncthreads();
  {
    const int row = tid >> 2, q = tid & 3;
    float mx = -1e30f;
#pragma unroll
    for (int j = 0; j < 16; ++j) mx = fmaxf(mx, Ss[row][q * 16 + j]);
    mx = fmaxf(mx, __shfl_xor(mx, 1));
    mx = fmaxf(mx, __shfl_xor(mx, 2));
    float se = 0.f;
#pragma unroll
    for (int j = 0; j < 16; ++j) {
      float p = __expf(Ss[row][q * 16 + j] - mx);
      Ss[row][q * 16 + j] = p;
      se += p;
    }
    se += __shfl_xor(se, 1);
    se += __shfl_xor(se, 2);
    if (q == 0) {
      Ml[((size_t)kc * ZH + z) * 64 + row] = mx;
      Ll[((size_t)kc * ZH + z) * 64 + row] = se;
    }
  }
  __syncthreads();
  const int d = tid & 63, w = tid >> 6;
  float acc2[16] = {};
  for (int k = 0; k < 64; ++k) {
    const float vk = Vs[k][d];
#pragma unroll
    for (int i = 0; i < 16; ++i)
      acc2[i] += Ss[w * 16 + i][k] * vk;
  }
  float* outb = Op + ((size_t)kc * ZH + z) * 4096;
#pragma unroll
  for (int i = 0; i < 16; ++i)
    outb[(w * 16 + i) * 64 + d] = acc2[i];
}

// ------ flash-combine 16 chunks + scatter into bf16 ctx ------
__global__ __launch_bounds__(256) void k_prob_comb(
    const float* __restrict__ Op, const float* __restrict__ Ml,
    const float* __restrict__ Ll, const int* __restrict__ top,
    __hip_bfloat16* __restrict__ ctx, int U)
{
  __shared__ float wsh[16][64];
  __shared__ float Lsh[64];
  const int z = blockIdx.x, b = z >> 3, h = z & 7;
  const int tid = threadIdx.x;
  if (tid < 64) {
    float M = -1e30f;
#pragma unroll
    for (int c = 0; c < 16; ++c)
      M = fmaxf(M, Ml[((size_t)c * ZH + z) * 64 + tid]);
    float L = 0.f;
#pragma unroll
    for (int c = 0; c < 16; ++c) {
      float wv = __expf(Ml[((size_t)c * ZH + z) * 64 + tid] - M);
      wsh[c][tid] = wv;
      L += wv * Ll[((size_t)c * ZH + z) * 64 + tid];
    }
    Lsh[tid] = L;
  }
  __syncthreads();
  for (int e = tid; e < U * 64; e += 256) {
    const int u = e >> 6, d = e & 63;
    float s = 0.f;
#pragma unroll
    for (int c = 0; c < 16; ++c)
      s += wsh[c][u] * Op[((size_t)c * ZH + z) * 4096 + u * 64 + d];
    const int row = top[z * U + u];
    ctx[((size_t)(b * Ls + row)) * DM + h * DHd + d] =
        __float2bfloat16(s / Lsh[u]);
  }
}

// ---- ProbSparse sampled scores, bf16 compact gather, 8 lanes/query ----
template<int UU>
__global__ __launch_bounds__(256) void k_mscore4(
    const __hip_bfloat16* __restrict__ Qzb, const __hip_bfloat16* __restrict__ Kzb,
    const int* __restrict__ smp, float* __restrict__ Ms)
{
  const int bid = blockIdx.x;                       // 2048 blocks
  const int swz = (bid & 7) * 256 + (bid >> 3);     // XCD chunk swizzle
  const int gw = swz * 4 + (threadIdx.x >> 6);      // 8192 waves
  const int lane = threadIdx.x & 63;
  const int li = lane >> 3, dp = (lane & 7) * 8;
  const int l = (gw & 127) * 8 + li;
  const int z = gw >> 7;
  const short8v q8 = *(const short8v*)(Qzb + ((size_t)z * Ls + l) * 64 + dp);
  float qf[8];
#pragma unroll
  for (int j = 0; j < 8; ++j) qf[j] = bf2f(q8[j]);
  int kidx[UU];
#pragma unroll
  for (int u = 0; u < UU; ++u) kidx[u] = smp[l * UU + u];
  const __hip_bfloat16* kzb = Kzb + (size_t)z * Ls * 64 + dp;
  float mx = -1e30f, sm = 0.f;
#pragma unroll
  for (int u = 0; u < UU; ++u) {
    const short8v k8 = *(const short8v*)(kzb + (size_t)kidx[u] * 64);
    float d = qf[0] * bf2f(k8[0]) + qf[1] * bf2f(k8[1])
            + qf[2] * bf2f(k8[2]) + qf[3] * bf2f(k8[3])
            + qf[4] * bf2f(k8[4]) + qf[5] * bf2f(k8[5])
            + qf[6] * bf2f(k8[6]) + qf[7] * bf2f(k8[7]);
    d += __shfl_xor(d, 1);
    d += __shfl_xor(d, 2);
    d += __shfl_xor(d, 4);
    mx = fmaxf(mx, d);
    sm += d;
  }
  if ((lane & 7) == 0) Ms[z * Ls + l] = mx - sm * (1.0f / Ls);
}

// runtime-U fallback
__global__ __launch_bounds__(256) void k_mscore4g(
    const __hip_bfloat16* __restrict__ Qzb, const __hip_bfloat16* __restrict__ Kzb,
    const int* __restrict__ smp, float* __restrict__ Ms, int U)
{
  const int bid = blockIdx.x;
  const int swz = (bid & 7) * 256 + (bid >> 3);
  const int gw = swz * 4 + (threadIdx.x >> 6);
  const int lane = threadIdx.x & 63;
  const int li = lane >> 3, dp = (lane & 7) * 8;
  const int l = (gw & 127) * 8 + li;
  const int z = gw >> 7;
  const short8v q8 = *(const short8v*)(Qzb + ((size_t)z * Ls + l) * 64 + dp);
  float qf[8];
#pragma unroll
  for (int j = 0; j < 8; ++j) qf[j] = bf2f(q8[j]);
  const __hip_bfloat16* kzb = Kzb + (size_t)z * Ls * 64 + dp;
  float mx = -1e30f, sm = 0.f;
  for (int u = 0; u < U; ++u) {
    const short8v k8 = *(const short8v*)(kzb + (size_t)smp[l * U + u] * 64);
    float d = qf[0] * bf2f(k8[0]) + qf[1] * bf2f(k8[1])
            + qf[2] * bf2f(k8[2]) + qf[3] * bf2f(k8[3])
            + qf[4] * bf2f(k8[4]) + qf[5] * bf2f(k8[5])
            + qf[6] * bf2f(k8[6]) + qf[7] * bf2f(k8[7]);
    d += __shfl_xor(d, 1);
    d += __shfl_xor(d, 2);
    d += __shfl_xor(d, 4);
    mx = fmaxf(mx, d);
    sm += d;
  }
  if ((lane & 7) == 0) Ms[z * Ls + l] = mx - sm * (1.0f / Ls);
}

// ---------------- wave-parallel top-U ----------------
__global__ __launch_bounds__(64) void k_topk_w(
    const float* __restrict__ Ms, int* __restrict__ top, int U)
{
  const int z = blockIdx.x, lane = threadIdx.x;
  float v[16];
#pragma unroll
  for (int j = 0; j < 16; ++j) v[j] = Ms[z * Ls + j * 64 + lane];
  for (int it = 0; it < U; ++it) {
    float bv = -1e30f; int bi = 0x7fffffff;
#pragma unroll
    for (int j = 0; j < 16; ++j) {
      const int idx = j * 64 + lane;
      if (v[j] > bv) { bv = v[j]; bi = idx; }
    }
#pragma unroll
    for (int off = 1; off < 64; off <<= 1) {
      const float ov = __shfl_xor(bv, off);
      const int   oi = __shfl_xor(bi, off);
      if (ov > bv || (ov == bv && oi < bi)) { bv = ov; bi = oi; }
    }
    if (lane == 0) top[z * U + it] = bi;
    if ((bi & 63) == lane) v[bi >> 6] = -1e30f;
  }
}

// ---------------- mean of V: stage 1 ----------------
__global__ __launch_bounds__(256) void k_meanv1(
    const float* __restrict__ Vm, float* __restrict__ mvp)
{
  __shared__ float ps[4][64];
  const int gid = blockIdx.x, z = gid >> 3, c = gid & 7, b = z >> 3, h = z & 7;
  const int d = threadIdx.x & 63, g = threadIdx.x >> 6;
  float s = 0.f;
  const int kb = c * 128 + g * 32;
  for (int k = kb; k < kb + 32; ++k)
    s += Vm[((size_t)(b * Ls + k)) * DM + h * DHd + d];
  ps[g][d] = s;
  __syncthreads();
  if (g == 0) mvp[(z * 8 + c) * 64 + d] = ps[0][d] + ps[1][d] + ps[2][d] + ps[3][d];
}

// ---------------- broadcast mean-V into bf16 ctx ----------------
__global__ __launch_bounds__(256) void k_ctxfillb(
    const float* __restrict__ mvp, __hip_bfloat16* __restrict__ ctx)
{
  const int i = blockIdx.x * 256 + threadIdx.x;
  const int c4 = (i & 127) << 2;
  const int row = i >> 7;
  const int b = row >> 10;
  const int h = c4 >> 6;
  const float* base = mvp + ((b * 8 + h) * 8) * 64 + (c4 & 63);
  float4 a = {0.f, 0.f, 0.f, 0.f};
#pragma unroll
  for (int c = 0; c < 8; ++c) {
    float4 m4 = *reinterpret_cast<const float4*>(base + c * 64);
    a.x += m4.x; a.y += m4.y; a.z += m4.z; a.w += m4.w;
  }
  const float inv = 1.0f / Ls;
  short4v o;
  o.x = f2bf(a.x * inv); o.y = f2bf(a.y * inv);
  o.z = f2bf(a.z * inv); o.w = f2bf(a.w * inv);
  *reinterpret_cast<short4v*>(ctx + (size_t)row * DM + c4) = o;
}

// ------- LayerNorm over sum of NP partials (+bias) (+residual) -------
template<int NP>
__global__ __launch_bounds__(256) void k_ln2(
    const float* __restrict__ x0, const float* __restrict__ x1,
    const float* __restrict__ x2, const float* __restrict__ x3,
    const float* __restrict__ res, const float* __restrict__ bias,
    const float* __restrict__ g, const float* __restrict__ be,
    float* __restrict__ outf, __hip_bfloat16* __restrict__ outb)
{
  __shared__ float red[4];
  const int row = blockIdx.x, tid = threadIdx.x;
  const size_t base = (size_t)row * DM;
  float2 v = *reinterpret_cast<const float2*>(x0 + base + tid * 2);
  if (NP > 1) {
    float2 a = *reinterpret_cast<const float2*>(x1 + base + tid * 2);
    v.x += a.x; v.y += a.y;
  }
  if (NP > 2) {
    float2 a = *reinterpret_cast<const float2*>(x2 + base + tid * 2);
    v.x += a.x; v.y += a.y;
  }
  if (NP > 3) {
    float2 a = *reinterpret_cast<const float2*>(x3 + base + tid * 2);
    v.x += a.x; v.y += a.y;
  }
  if (bias) {
    float2 a = *reinterpret_cast<const float2*>(bias + tid * 2);
    v.x += a.x; v.y += a.y;
  }
  if (res) {
    float2 r2 = *reinterpret_cast<const float2*>(res + base + tid * 2);
    v.x += r2.x; v.y += r2.y;
  }
  float s = v.x + v.y;
#pragma unroll
  for (int off = 32; off; off >>= 1) s += __shfl_xor(s, off);
  if ((tid & 63) == 0) red[tid >> 6] = s;
  __syncthreads();
  s = red[0] + red[1] + red[2] + red[3];
  const float mean = s * (1.0f / DM);
  __syncthreads();
  float dx = v.x - mean, dy = v.y - mean;
  float q = dx * dx + dy * dy;
#pragma unroll
  for (int off = 32; off; off >>= 1) q += __shfl_xor(q, off);
  if ((tid & 63) == 0) red[tid >> 6] = q;
  __syncthreads();
  q = red[0] + red[1] + red[2] + red[3];
  const float inv = rsqrtf(q * (1.0f / DM) + 1e-5f);
  float2 gg = *reinterpret_cast<const float2*>(g + tid * 2);
  float2 bb = *reinterpret_cast<const float2*>(be + tid * 2);
  float ox = dx * inv * gg.x + bb.x;
  float oy = dy * inv * gg.y + bb.y;
  if (outf) {
    float2 o; o.x = ox; o.y = oy;
    *reinterpret_cast<float2*>(outf + base + tid * 2) = o;
  }
  if (outb) {
    short2 ob; ob.x = f2bf(ox); ob.y = f2bf(oy);
    *reinterpret_cast<short2*>(outb + base + tid * 2) = ob;
  }
}

extern "C" void kernel_launch(void* const* d_in, const int* in_sizes, int n_in,
                              void* d_out, int out_size, void* d_ws, size_t ws_size,
                              hipStream_t stream)
{
  const float* tgt = (const float*)d_in[0];
  const float* mem = (const float*)d_in[1];
  const int*   smp = (const int*)d_in[2];
  const float* wq1 = (const float*)d_in[3];  const float* bq1 = (const float*)d_in[4];
  const float* wk1 = (const float*)d_in[5];  const float* bk1 = (const float*)d_in[6];
  const float* wv1 = (const float*)d_in[7];  const float* bv1 = (const float*)d_in[8];
  const float* wo1 = (const float*)d_in[9];  const float* bo1 = (const float*)d_in[10];
  const float* wq2 = (const float*)d_in[11]; const float* bq2 = (const float*)d_in[12];
  const float* wk2 = (const float*)d_in[13]; const float* bk2 = (const float*)d_in[14];
  const float* wv2 = (const float*)d_in[15]; const float* bv2 = (const float*)d_in[16];
  const float* wo2 = (const float*)d_in[17]; const float* bo2 = (const float*)d_in[18];
  const float* c1w = (const float*)d_in[19]; const float* c1b = (const float*)d_in[20];
  const float* c2w = (const float*)d_in[21]; const float* c2b = (const float*)d_in[22];
  const float* g1  = (const float*)d_in[23]; const float* be1 = (const float*)d_in[24];
  const float* g2  = (const float*)d_in[25]; const float* be2 = (const float*)d_in[26];
  const float* g3  = (const float*)d_in[27]; const float* be3 = (const float*)d_in[28];
  float* outp = (float*)d_out;

  const int U   = in_sizes[2] / Ls;            // 35

  char* ws = (char*)d_ws;
  const size_t SZ = (size_t)MR * DM * sizeof(float);       // 16.78 MB
  float* Qz   = (float*)(ws);
  float* Kz   = (float*)(ws + SZ);
  float* W0   = Qz;
  float* W1   = Kz;
  float* W2   = (float*)(ws + 2 * SZ);
  float* Sbuf = (float*)(ws + 3 * SZ);                     // FFN hidden / QKzb region
  float* Op   = Sbuf + (size_t)ZH * 64 * Ls;               // prob PV partials
  __hip_bfloat16* QKzb = (__hip_bfloat16*)Sbuf;            // Qzb, then Kzb
  __hip_bfloat16* Qzb = QKzb;
  __hip_bfloat16* Kzb = QKzb + (size_t)ZH * Ls * 64;
  __hip_bfloat16* Tb  = (__hip_bfloat16*)(ws + 5 * SZ);
  __hip_bfloat16* Mb  = (__hip_bfloat16*)(ws + 5 * SZ + SZ / 2);
  __hip_bfloat16* Xb  = (__hip_bfloat16*)(ws + 6 * SZ);
  __hip_bfloat16* Vtb = (__hip_bfloat16*)(ws + 6 * SZ + SZ / 2);
  __hip_bfloat16* Wt3 = Vtb;                 // [wq1b;wk1b;wv1b] (dead before Vtb written)
  float* CP2 = (float*)(ws + 5 * SZ);        // conv2 partial 2
  float* CP3 = (float*)(ws + 6 * SZ);        // conv2 partial 3
  char* tail = ws + 7 * SZ;
  __hip_bfloat16* wo1b = (__hip_bfloat16*)tail; tail += DM * DM * 2;
  __hip_bfloat16* wq2b = (__hip_bfloat16*)tail; tail += DM * DM * 2;
  __hip_bfloat16* wk2b = (__hip_bfloat16*)tail; tail += DM * DM * 2;
  __hip_bfloat16* wv2b = (__hip_bfloat16*)tail; tail += DM * DM * 2;
  __hip_bfloat16* wo2b = (__hip_bfloat16*)tail; tail += DM * DM * 2;
  __hip_bfloat16* c1wb = (__hip_bfloat16*)tail; tail += DM * 4 * DM * 2;
  __hip_bfloat16* c2wb = (__hip_bfloat16*)tail; tail += DM * 4 * DM * 2;
  float* Ms  = (float*)tail; tail += (size_t)ZH * Ls * 4;
  int*   top = (int*)tail;   tail += (size_t)ZH * 64 * 4;
  float* mvp = (float*)tail; tail += (size_t)ZH * 8 * DHd * 4;
  float* Ml  = (float*)tail; tail += (size_t)16 * ZH * 64 * 4;
  float* Ll  = (float*)tail; tail += (size_t)16 * ZH * 64 * 4;
  __hip_bfloat16* Kb = Tb;
  __hip_bfloat16* Qb = (__hip_bfloat16*)d_out;  // parked until final LN
  __hip_bfloat16* hb = (__hip_bfloat16*)Sbuf;

  // ---- ALL converts, one dispatch ----
  CvtArgs ca;
  ca.s[0] = wq1; ca.d[0] = Wt3;
  ca.s[1] = wk1; ca.d[1] = Wt3 + DM * DM;
  ca.s[2] = wv1; ca.d[2] = Wt3 + 2 * DM * DM;
  ca.s[3] = wo1; ca.d[3] = wo1b;
  ca.s[4] = wq2; ca.d[4] = wq2b;
  ca.s[5] = wk2; ca.d[5] = wk2b;
  ca.s[6] = wv2; ca.d[6] = wv2b;
  ca.s[7] = wo2; ca.d[7] = wo2b;
  ca.s[8] = c1w; ca.d[8] = c1wb;
  ca.s[9] = c2w; ca.d[9] = c2wb;
  ca.s[10] = tgt; ca.d[10] = Tb;
  ca.s[11] = mem; ca.d[11] = Mb;
  k_cvt_all<<<dim3(12288), 256, 0, stream>>>(ca);

  // ---- layer-1 projections: ONE batched GEMM (Q->Qz(+bf16), K->Kz(+bf16), V->W2) ----
  k_gemm_mfma<10, 0><<<dim3(MR / 128, 12), 256, 0, stream>>>(
      Tb, Wt3, bq1, bk1, bv1, Qz, Kz, W2, QKzb, MR, 1536, DM);

  // ---- ProbSparse ----
  if (U == 35)
    k_mscore4<35><<<dim3(2048), 256, 0, stream>>>(Qzb, Kzb, smp, Ms);
  else
    k_mscore4g<<<dim3(2048), 256, 0, stream>>>(Qzb, Kzb, smp, Ms, U);
  k_topk_w<<<dim3(ZH), 64, 0, stream>>>(Ms, top, U);
  k_probflash<<<dim3(16 * ZH), 256, 0, stream>>>(Qz, Kz, W2, top, Op, Ml, Ll, U);
  k_meanv1<<<dim3(ZH * 8), 256, 0, stream>>>(W2, mvp);
  k_ctxfillb<<<dim3(MR * DM / 4 / 256), 256, 0, stream>>>(mvp, Xb);
  k_prob_comb<<<dim3(ZH), 256, 0, stream>>>(Op, Ml, Ll, top, Xb, U);

  // ---- out-proj 1 (split-K=2) + residual LN (fused reduce) ----
  k_gemm_mfma<20, 0><<<dim3(MR / 128, DM / 128, 2), 256, 0, stream>>>(
      Xb, wo1b, nullptr, nullptr, nullptr, W0, W1, nullptr, nullptr, MR, DM, DM);
  k_ln2<2><<<dim3(MR), 256, 0, stream>>>(W0, W1, nullptr, nullptr,
                                         tgt, bo1, g1, be1, nullptr, Xb);

  // ---- layer-2 projections: ONE triple (Q from Xb; K,V from Mb via aux3) ----
  k_gemm_mfma<12, 0><<<dim3(MR / 128, 12), 256, 0, stream>>>(
      Xb, wq2b, bq2, bk2, bv2, Qb, Kb, Vtb, (void*)Mb, MR, 1536, DM);

  // ---- fused flash cross attention -> Xb (bf16) ----
  k_flash2<<<dim3(Ls / 128, ZH), 512, 0, stream>>>(Qb, Kb, Vtb, Xb);

  // ---- out-proj 2 (split-K=2) + LN (fused) ----
  k_gemm_mfma<20, 0><<<dim3(MR / 128, DM / 128, 2), 256, 0, stream>>>(
      Xb, wo2b, nullptr, nullptr, nullptr, W0, W2, nullptr, nullptr, MR, DM, DM);
  k_ln2<2><<<dim3(MR), 256, 0, stream>>>(W0, W2, nullptr, nullptr,
                                         nullptr, bo2, g2, be2, W1, Xb);

  // ---- FFN ----
  k_gemm_mfma<1, 1><<<dim3(MR / 128, 4 * DM / 128), 256, 0, stream>>>(
      Xb, c1wb, c1b, nullptr, nullptr, hb, nullptr, nullptr, nullptr, MR, 4 * DM, DM);
  k_gemm_mfma<20, 0><<<dim3(MR / 128, DM / 128, 4), 256, 0, stream>>>(
      hb, c2wb, nullptr, nullptr, nullptr, W0, W2, CP2, CP3, MR, DM, 2 * DM * 2);
  k_ln2<4><<<dim3(MR), 256, 0, stream>>>(W0, W2, CP2, CP3,
                                         W1, c2b, g3, be3, outp, nullptr);
}

// Round 10
// 332.449 us; speedup vs baseline: 6.6042x; 1.0393x over previous
//
#include <hip/hip_runtime.h>
#include <hip/hip_bf16.h>
#include <cstdint>

constexpr int Bb  = 8;
constexpr int Ls  = 1024;
constexpr int DM  = 512;
constexpr int NH  = 8;
constexpr int DHd = 64;
constexpr int MR  = Bb * Ls;   // 8192 rows
constexpr int ZH  = Bb * NH;   // 64 (b,h) pairs

typedef __attribute__((ext_vector_type(8))) short short8v;
typedef __attribute__((ext_vector_type(4))) short short4v;
typedef __attribute__((ext_vector_type(4))) float floatx4;

__device__ inline short f2bf(float x) {
  __hip_bfloat16 h = __float2bfloat16(x);
  return *reinterpret_cast<short*>(&h);
}
__device__ inline float bf2f(short s) {
  return __uint_as_float(((uint32_t)(uint16_t)s) << 16);
}

#define GLOAD_LDS16(g, l)                                                        \
  __builtin_amdgcn_global_load_lds(                                              \
      (const __attribute__((address_space(1))) void*)(g),                        \
      (__attribute__((address_space(3))) void*)(l), 16, 0, 0)

// ================= bf16 MFMA GEMM, double-buffered prefetch =================
// MODE: 1 bf16 out |
// 10 L1 triple (N=1536: Q->Qz f32 + Qzb bf16, K->Kz f32 + Kzb bf16, V->merged f32)
//    aux3 = QKzb base (Qzb, then Kzb at +ZH*Ls*64)
// 12 L2 triple (N=1536: Q(x1)->Qb bf16 x0.125, K(mem)->Kb swizzled, V(mem)->Vt
//    transposed); aux3 = second A matrix (mem) used for bn>=512
// 20 split-K raw f32 partial (no bias; partial z -> Cout/aux1/aux2/aux3)
template<int MODE, int RELU>
__global__ __launch_bounds__(256) void k_gemm_mfma(
    const __hip_bfloat16* __restrict__ A, const __hip_bfloat16* __restrict__ Wt,
    const float* __restrict__ bias, const float* __restrict__ bias1,
    const float* __restrict__ bias2,
    void* __restrict__ Cout, void* __restrict__ aux1, void* __restrict__ aux2,
    void* __restrict__ aux3,
    int M, int N, int K)
{
  __shared__ __hip_bfloat16 As[2][128 * 32];
  __shared__ __hip_bfloat16 Bs[2][128 * 32];
  const int tid = threadIdx.x;
  const int w = tid >> 6, lane = tid & 63;
  const int wr = w >> 1, wc = w & 1;
  const int bm = blockIdx.x * 128, bn = blockIdx.y * 128;
  const int lrow = lane >> 2;
  const int lcol = (lane & 3) * 8;
  const int fr = lane & 15;
  const int fco = (lane >> 4) * 8;

  const __hip_bfloat16* Asrc = A;
  if (MODE == 12 && bn >= 512) Asrc = (const __hip_bfloat16*)aux3;

  const int ksl = K / gridDim.z;
  const int kb0 = blockIdx.z * ksl;
  const int nst = ksl / 32;

  const int chunk0 = w * 2, chunk1 = w * 2 + 1;
  const size_t aoff0 = (size_t)(bm + chunk0 * 16 + lrow) * K + lcol;
  const size_t aoff1 = (size_t)(bm + chunk1 * 16 + lrow) * K + lcol;
  const size_t boff0 = (size_t)(bn + chunk0 * 16 + lrow) * K + lcol;
  const size_t boff1 = (size_t)(bn + chunk1 * 16 + lrow) * K + lcol;

  // prologue: stage step 0 into buffer 0
  {
    const int k0 = kb0;
    GLOAD_LDS16(Asrc + aoff0 + k0, &As[0][chunk0 * 512]);
    GLOAD_LDS16(Asrc + aoff1 + k0, &As[0][chunk1 * 512]);
    GLOAD_LDS16(Wt + boff0 + k0, &Bs[0][chunk0 * 512]);
    GLOAD_LDS16(Wt + boff1 + k0, &Bs[0][chunk1 * 512]);
  }
  asm volatile("s_waitcnt vmcnt(0)" ::: "memory");
  __builtin_amdgcn_s_barrier();

  floatx4 acc[4][4] = {};
  int cur = 0;
  for (int t = 0; t < nst; ++t) {
    if (t + 1 < nst) {                // prefetch next K-step into other buffer
      const int k0 = kb0 + (t + 1) * 32;
      GLOAD_LDS16(Asrc + aoff0 + k0, &As[cur ^ 1][chunk0 * 512]);
      GLOAD_LDS16(Asrc + aoff1 + k0, &As[cur ^ 1][chunk1 * 512]);
      GLOAD_LDS16(Wt + boff0 + k0, &Bs[cur ^ 1][chunk0 * 512]);
      GLOAD_LDS16(Wt + boff1 + k0, &Bs[cur ^ 1][chunk1 * 512]);
    }
    const short* Ash = (const short*)As[cur];
    const short* Bsh = (const short*)Bs[cur];
    short8v a[4], b[4];
#pragma unroll
    for (int mi = 0; mi < 4; ++mi)
      a[mi] = *(const short8v*)(Ash + (wr * 64 + mi * 16 + fr) * 32 + fco);
#pragma unroll
    for (int ni = 0; ni < 4; ++ni)
      b[ni] = *(const short8v*)(Bsh + (wc * 64 + ni * 16 + fr) * 32 + fco);
#pragma unroll
    for (int mi = 0; mi < 4; ++mi)
#pragma unroll
      for (int ni = 0; ni < 4; ++ni)
        acc[mi][ni] = __builtin_amdgcn_mfma_f32_16x16x32_bf16(
            a[mi], b[ni], acc[mi][ni], 0, 0, 0);
    asm volatile("s_waitcnt vmcnt(0)" ::: "memory");   // next tile landed
    __builtin_amdgcn_s_barrier();                      // all waves done with cur
    cur ^= 1;
  }
#pragma unroll
  for (int ni = 0; ni < 4; ++ni) {
    const int cn = bn + wc * 64 + ni * 16 + fr;
    float bv = 0.f;
    if (MODE == 10 || MODE == 12) {
      const float* bp = (cn < 512) ? bias : (cn < 1024 ? bias1 : bias2);
      bv = bp[cn & 511];
    } else if (MODE != 20) {
      bv = bias[cn];
    }
#pragma unroll
    for (int mi = 0; mi < 4; ++mi) {
#pragma unroll
      for (int j = 0; j < 4; ++j) {
        const int rm = bm + wr * 64 + mi * 16 + (lane >> 4) * 4 + j;
        float v = acc[mi][ni][j] + bv;
        if (RELU) v = fmaxf(v, 0.f);
        if (MODE == 1) {
          ((__hip_bfloat16*)Cout)[(size_t)rm * N + cn] = __float2bfloat16(v);
        } else if (MODE == 10) {
          const int sel = cn >> 9, c = cn & 511;
          if (sel == 2) {
            ((float*)aux2)[(size_t)rm * 512 + c] = v;
          } else {
            const int bb = rm >> 10, l = rm & 1023, hh = c >> 6, dd = c & 63;
            const size_t ci = (((size_t)(bb * 8 + hh)) * 1024 + l) * 64 + dd;
            float* base = sel ? (float*)aux1 : (float*)Cout;
            base[ci] = v;
            __hip_bfloat16* bb16 = (__hip_bfloat16*)aux3 +
                                   (sel ? (size_t)ZH * Ls * 64 : 0);
            bb16[ci] = __float2bfloat16(v);
          }
        } else if (MODE == 12) {
          const int sel = cn >> 9, c = cn & 511;
          if (sel == 0) {
            ((__hip_bfloat16*)Cout)[(size_t)rm * 512 + c] =
                __float2bfloat16(v * 0.125f);
          } else if (sel == 1) {
            const int cs = (c & ~63) | ((c & 63) ^ ((rm & 7) << 3));
            ((__hip_bfloat16*)aux1)[(size_t)rm * 512 + cs] = __float2bfloat16(v);
          } else {
            const int bb = rm >> 10, l = rm & 1023, hh = c >> 6, dd = c & 63;
            ((__hip_bfloat16*)aux2)[(size_t)((bb * 8 + hh) * 64 + dd) * 1024 +
                                    (l ^ ((dd & 7) << 3))] = __float2bfloat16(v);
          }
        } else if (MODE == 20) {
          float* pz = (float*)(blockIdx.z == 0 ? Cout :
                      blockIdx.z == 1 ? aux1 :
                      blockIdx.z == 2 ? aux2 : aux3);
          pz[(size_t)rm * N + cn] = v;
        }
      }
    }
  }
}

// ===== fused flash cross-attention v2: 512 thr, dbuf K/V, defer-max, setprio =====
// Qb pre-scaled by 0.125.
__global__ __launch_bounds__(512) void k_flash2(
    const __hip_bfloat16* __restrict__ Qb,
    const __hip_bfloat16* __restrict__ Kb,
    const __hip_bfloat16* __restrict__ Vt,
    __hip_bfloat16* __restrict__ O)
{
  __shared__ __hip_bfloat16 Ks[2][64 * 64];
  __shared__ __hip_bfloat16 Vs[2][64 * 64];
  __shared__ __hip_bfloat16 Ps[8 * 16 * 72];
  const int tid = threadIdx.x, w = tid >> 6, lane = tid & 63;
  const int g = lane >> 4, r = lane & 15;
  const int z = blockIdx.y, b = z >> 3, h = z & 7;
  const int q0 = blockIdx.x * 128 + w * 16;
  __hip_bfloat16* Pw = Ps + w * 16 * 72;

  const int srow = w * 8 + (lane >> 3);
  const int sseg = lane & 7;

  const short8v qf0 = *(const short8v*)(Qb + (size_t)(b * Ls + q0 + r) * DM + h * DHd + g * 8);
  const short8v qf1 = *(const short8v*)(Qb + (size_t)(b * Ls + q0 + r) * DM + h * DHd + 32 + g * 8);

  floatx4 oacc[4] = {};
  float m_run = -1e30f, l_run = 0.f;

  GLOAD_LDS16(Kb + (size_t)(b * Ls + srow) * DM + h * DHd + sseg * 8, &Ks[0][w * 512]);
  GLOAD_LDS16(Vt + ((size_t)z * DHd + srow) * Ls + sseg * 8, &Vs[0][w * 512]);
  asm volatile("s_waitcnt vmcnt(0)" ::: "memory");
  __builtin_amdgcn_s_barrier();

  int cur = 0;
  for (int t = 0; t < 16; ++t) {
    if (t + 1 < 16) {
      GLOAD_LDS16(Kb + (size_t)(b * Ls + (t + 1) * 64 + srow) * DM + h * DHd + sseg * 8,
                  &Ks[cur ^ 1][w * 512]);
      GLOAD_LDS16(Vt + ((size_t)z * DHd + srow) * Ls + (t + 1) * 64 + sseg * 8,
                  &Vs[cur ^ 1][w * 512]);
    }
    const __hip_bfloat16* Kc = Ks[cur];
    const __hip_bfloat16* Vc = Vs[cur];
    float sv[4][4];
    float tmax = -1e30f;
    __builtin_amdgcn_s_setprio(1);
#pragma unroll
    for (int kt = 0; kt < 4; ++kt) {
      const int key = kt * 16 + r, sw = key & 7;
      short8v a0 = *(const short8v*)(Kc + key * 64 + ((g ^ sw) * 8));
      short8v a1 = *(const short8v*)(Kc + key * 64 + (((4 + g) ^ sw) * 8));
      floatx4 c = {};
      c = __builtin_amdgcn_mfma_f32_16x16x32_bf16(a0, qf0, c, 0, 0, 0);
      c = __builtin_amdgcn_mfma_f32_16x16x32_bf16(a1, qf1, c, 0, 0, 0);
#pragma unroll
      for (int j = 0; j < 4; ++j) {
        float x = c[j];
        sv[kt][j] = x;
        tmax = fmaxf(tmax, x);
      }
    }
    __builtin_amdgcn_s_setprio(0);
    tmax = fmaxf(tmax, __shfl_xor(tmax, 16));
    tmax = fmaxf(tmax, __shfl_xor(tmax, 32));
    float m_new;
    if (__all(tmax <= m_run + 8.0f)) {
      m_new = m_run;
    } else {
      m_new = fmaxf(m_run, tmax);
      const float fac = __expf(m_run - m_new);
      float fj[4];
#pragma unroll
      for (int j = 0; j < 4; ++j) fj[j] = __shfl(fac, (lane & 48) | (g * 4 + j));
#pragma unroll
      for (int ct = 0; ct < 4; ++ct)
#pragma unroll
        for (int j = 0; j < 4; ++j) oacc[ct][j] *= fj[j];
      l_run *= fac;
    }
    float psum = 0.f;
#pragma unroll
    for (int kt = 0; kt < 4; ++kt) {
      short4v pk;
#pragma unroll
      for (int j = 0; j < 4; ++j) {
        float p = __expf(sv[kt][j] - m_new);
        psum += p;
        pk[j] = f2bf(p);
      }
      *(short4v*)(Pw + r * 72 + kt * 16 + g * 4) = pk;
    }
    psum += __shfl_xor(psum, 16);
    psum += __shfl_xor(psum, 32);
    l_run += psum;
    m_run = m_new;
    const short8v pa0 = *(const short8v*)(Pw + r * 72 + g * 8);
    const short8v pa1 = *(const short8v*)(Pw + r * 72 + 32 + g * 8);
    __builtin_amdgcn_s_setprio(1);
#pragma unroll
    for (int ct = 0; ct < 4; ++ct) {
      const int d = ct * 16 + r, sw = d & 7;
      short8v v0 = *(const short8v*)(Vc + d * 64 + ((g ^ sw) * 8));
      short8v v1 = *(const short8v*)(Vc + d * 64 + (((4 + g) ^ sw) * 8));
      oacc[ct] = __builtin_amdgcn_mfma_f32_16x16x32_bf16(pa0, v0, oacc[ct], 0, 0, 0);
      oacc[ct] = __builtin_amdgcn_mfma_f32_16x16x32_bf16(pa1, v1, oacc[ct], 0, 0, 0);
    }
    __builtin_amdgcn_s_setprio(0);
    asm volatile("s_waitcnt vmcnt(0)" ::: "memory");
    __builtin_amdgcn_s_barrier();
    cur ^= 1;
  }
  float li[4];
#pragma unroll
  for (int j = 0; j < 4; ++j)
    li[j] = 1.0f / __shfl(l_run, (lane & 48) | (g * 4 + j));
#pragma unroll
  for (int ct = 0; ct < 4; ++ct)
#pragma unroll
    for (int j = 0; j < 4; ++j)
      O[(size_t)(b * Ls + q0 + g * 4 + j) * DM + h * DHd + ct * 16 + r] =
          __float2bfloat16(oacc[ct][j] * li[j]);
}

// ---------------- ALL converts (2 activations + 10 weights) in one dispatch ----------------
struct CvtArgs { const float* s[12]; __hip_bfloat16* d[12]; };
__global__ __launch_bounds__(256) void k_cvt_all(CvtArgs a)
{
  const int bid = blockIdx.x, tid = threadIdx.x;
  if (bid < 8192) {
    const size_t half = (size_t)MR * DM / 4;
    size_t i = (size_t)bid * 256 + tid;
    const float* in = a.s[10]; __hip_bfloat16* out = a.d[10];
    if (i >= half) { i -= half; in = a.s[11]; out = a.d[11]; }
    float4 v = *reinterpret_cast<const float4*>(in + i * 4);
    short4v o;
    o.x = f2bf(v.x); o.y = f2bf(v.y); o.z = f2bf(v.z); o.w = f2bf(v.w);
    *reinterpret_cast<short4v*>(out + i * 4) = o;
    return;
  }
  __shared__ float t[32][33];
  const int wb = bid - 8192;
  int widx, K, N, kblk, nblk;
  if (wb < 2048) {
    widx = wb >> 8; const int w2 = wb & 255;
    K = 512; N = 512; kblk = w2 & 15; nblk = w2 >> 4;
  } else if (wb < 3072) {
    widx = 8; const int w2 = wb - 2048;
    K = 512; N = 2048; kblk = w2 & 15; nblk = w2 >> 4;
  } else {
    widx = 9; const int w2 = wb - 3072;
    K = 2048; N = 512; kblk = w2 & 63; nblk = w2 >> 6;
  }
  const float* W = a.s[widx];
  __hip_bfloat16* Wt = a.d[widx];
  const int k0 = kblk * 32, n0 = nblk * 32;
  const int r = tid >> 3, c = (tid & 7) * 4;
  float4 v = *reinterpret_cast<const float4*>(W + (size_t)(k0 + r) * N + n0 + c);
  t[r][c + 0] = v.x; t[r][c + 1] = v.y; t[r][c + 2] = v.z; t[r][c + 3] = v.w;
  __syncthreads();
  short4v o;
  o.x = f2bf(t[c + 0][r]); o.y = f2bf(t[c + 1][r]);
  o.z = f2bf(t[c + 2][r]); o.w = f2bf(t[c + 3][r]);
  *reinterpret_cast<short4v*>(Wt + (size_t)(n0 + r) * K + k0 + c) = o;
}

// ====== fused prob attention chunk: S=Q[top]K^T, partial softmax, PV, V-colsum ======
__global__ __launch_bounds__(256) void k_probflash(
    const float* __restrict__ Qz, const float* __restrict__ Kz,
    const float* __restrict__ Vm, const int* __restrict__ top,
    float* __restrict__ Op, float* __restrict__ Ml, float* __restrict__ Ll,
    float* __restrict__ mvp, int U)
{
  __shared__ float Qs[DHd][64 + 4];
  __shared__ float Ks[DHd][64 + 4];
  __shared__ float Vs[64][64];
  __shared__ float ps[4][64];
  const int bid = blockIdx.x;
  const int swz = (bid & 7) * ((16 * ZH) >> 3) + (bid >> 3);
  const int kc = swz & 15, z = swz >> 4, b = z >> 3, h = z & 7;
  const int tid = threadIdx.x;
  const int k0 = kc * 64;
#pragma unroll
  for (int i = 0; i < 4; ++i) {
    const int idx = tid + (i << 8);
    const int r = idx >> 4, c4 = (idx & 15) << 2;
    int u = r; if (u >= U) u = U - 1;
    const int qr = top[z * U + u];
    float4 q4 = *reinterpret_cast<const float4*>(Qz + ((size_t)z * Ls + qr) * 64 + c4);
    Qs[c4 + 0][r] = q4.x; Qs[c4 + 1][r] = q4.y; Qs[c4 + 2][r] = q4.z; Qs[c4 + 3][r] = q4.w;
    float4 k4 = *reinterpret_cast<const float4*>(Kz + ((size_t)z * Ls + k0 + r) * 64 + c4);
    Ks[c4 + 0][r] = k4.x; Ks[c4 + 1][r] = k4.y; Ks[c4 + 2][r] = k4.z; Ks[c4 + 3][r] = k4.w;
    *reinterpret_cast<float4*>(&Vs[r][c4]) =
        *reinterpret_cast<const float4*>(Vm + ((size_t)(b * Ls + k0 + r)) * DM + h * DHd + c4);
  }
  __syncthreads();
  const int mB = (tid >> 4) << 2, nB = (tid & 15) << 2;
  float acc[4][4] = {};
#pragma unroll
  for (int kk = 0; kk < DHd; ++kk) {
    float4 a4 = *reinterpret_cast<const float4*>(&Qs[kk][mB]);
    float4 b4 = *reinterpret_cast<const float4*>(&Ks[kk][nB]);
    const float av[4] = {a4.x, a4.y, a4.z, a4.w};
#pragma unroll
    for (int i = 0; i < 4; ++i) {
      acc[i][0] += av[i] * b4.x; acc[i][1] += av[i] * b4.y;
      acc[i][2] += av[i] * b4.z; acc[i][3] += av[i] * b4.w;
    }
  }
  __syncthreads();
  float (*Ss)[68] = (float (*)[68])Qs;
#pragma unroll
  for (int i = 0; i < 4; ++i) {
    float4 o;
    o.x = acc[i][0] * 0.125f; o.y = acc[i][1] * 0.125f;
    o.z = acc[i][2] * 0.125f; o.w = acc[i][3] * 0.125f;
    *reinterpret_cast<float4*>(&Ss[mB + i][nB]) = o;
  }
  __syncthreads();
  {
    const int row = tid >> 2, q = tid & 3;
    float mx = -1e30f;
#pragma unroll
    for (int j = 0; j < 16; ++j) mx = fmaxf(mx, Ss[row][q * 16 + j]);
    mx = fmaxf(mx, __shfl_xor(mx, 1));
    mx = fmaxf(mx, __shfl_xor(mx, 2));
    float se = 0.f;
#pragma unroll
    for (int j = 0; j < 16; ++j) {
      float p = __expf(Ss[row][q * 16 + j] - mx);
      Ss[row][q * 16 + j] = p;
      se += p;
    }
    se += __shfl_xor(se, 1);
    se += __shfl_xor(se, 2);
    if (q == 0) {
      Ml[((size_t)kc * ZH + z) * 64 + row] = mx;
      Ll[((size_t)kc * ZH + z) * 64 + row] = se;
    }
  }
  __syncthreads();
  const int d = tid & 63, w = tid >> 6;
  // V column partial sum (for meanV): each w sums 16 rows
  {
    float s = 0.f;
#pragma unroll
    for (int i = 0; i < 16; ++i) s += Vs[w * 16 + i][d];
    ps[w][d] = s;
  }
  float acc2[16] = {};
  for (int k = 0; k < 64; ++k) {
    const float vk = Vs[k][d];
#pragma unroll
    for (int i = 0; i < 16; ++i)
      acc2[i] += Ss[w * 16 + i][k] * vk;
  }
  float* outb = Op + ((size_t)kc * ZH + z) * 4096;
#pragma unroll
  for (int i = 0; i < 16; ++i)
    outb[(w * 16 + i) * 64 + d] = acc2[i];
  __syncthreads();
  if (w == 0)
    mvp[((size_t)z * 16 + kc) * 64 + d] = ps[0][d] + ps[1][d] + ps[2][d] + ps[3][d];
}

// ------ per-z: meanV fill of whole slice + flash-combine scatter of top-U ------
__global__ __launch_bounds__(256) void k_prob_comb2(
    const float* __restrict__ Op, const float* __restrict__ Ml,
    const float* __restrict__ Ll, const int* __restrict__ top,
    const float* __restrict__ mvp, __hip_bfloat16* __restrict__ ctx, int U)
{
  __shared__ float wsh[16][64];
  __shared__ float Lsh[64];
  __shared__ short4v mvb[16];
  const int z = blockIdx.x, b = z >> 3, h = z & 7;
  const int tid = threadIdx.x;
  if (tid < 64) {
    float M = -1e30f;
#pragma unroll
    for (int c = 0; c < 16; ++c)
      M = fmaxf(M, Ml[((size_t)c * ZH + z) * 64 + tid]);
    float L = 0.f;
#pragma unroll
    for (int c = 0; c < 16; ++c) {
      float wv = __expf(Ml[((size_t)c * ZH + z) * 64 + tid] - M);
      wsh[c][tid] = wv;
      L += wv * Ll[((size_t)c * ZH + z) * 64 + tid];
    }
    Lsh[tid] = L;
    // meanV for this (z): sum 16 chunk partials
    float s = 0.f;
#pragma unroll
    for (int c = 0; c < 16; ++c) s += mvp[((size_t)z * 16 + c) * 64 + tid];
    const short mb = f2bf(s * (1.0f / Ls));
    ((short*)mvb)[tid] = mb;
  }
  __syncthreads();
  // fill whole z-slice with meanV
  __hip_bfloat16* base = ctx + (size_t)(b * Ls) * DM + h * DHd;
  for (int i = tid; i < 1024 * 16; i += 256) {
    const int row = i >> 4, c4 = i & 15;
    *reinterpret_cast<short4v*>(base + (size_t)row * DM + c4 * 4) = mvb[c4];
  }
  __syncthreads();
  // scatter top-U rows
  for (int e = tid; e < U * 64; e += 256) {
    const int u = e >> 6, d = e & 63;
    float s = 0.f;
#pragma unroll
    for (int c = 0; c < 16; ++c)
      s += wsh[c][u] * Op[((size_t)c * ZH + z) * 4096 + u * 64 + d];
    const int row = top[z * U + u];
    ctx[((size_t)(b * Ls + row)) * DM + h * DHd + d] =
        __float2bfloat16(s / Lsh[u]);
  }
}

// ---- ProbSparse sampled scores, bf16 compact gather, 8 lanes/query ----
template<int UU>
__global__ __launch_bounds__(256) void k_mscore4(
    const __hip_bfloat16* __restrict__ Qzb, const __hip_bfloat16* __restrict__ Kzb,
    const int* __restrict__ smp, float* __restrict__ Ms)
{
  const int bid = blockIdx.x;
  const int swz = (bid & 7) * 256 + (bid >> 3);
  const int gw = swz * 4 + (threadIdx.x >> 6);
  const int lane = threadIdx.x & 63;
  const int li = lane >> 3, dp = (lane & 7) * 8;
  const int l = (gw & 127) * 8 + li;
  const int z = gw >> 7;
  const short8v q8 = *(const short8v*)(Qzb + ((size_t)z * Ls + l) * 64 + dp);
  float qf[8];
#pragma unroll
  for (int j = 0; j < 8; ++j) qf[j] = bf2f(q8[j]);
  int kidx[UU];
#pragma unroll
  for (int u = 0; u < UU; ++u) kidx[u] = smp[l * UU + u];
  const __hip_bfloat16* kzb = Kzb + (size_t)z * Ls * 64 + dp;
  float mx = -1e30f, sm = 0.f;
#pragma unroll
  for (int u = 0; u < UU; ++u) {
    const short8v k8 = *(const short8v*)(kzb + (size_t)kidx[u] * 64);
    float d = qf[0] * bf2f(k8[0]) + qf[1] * bf2f(k8[1])
            + qf[2] * bf2f(k8[2]) + qf[3] * bf2f(k8[3])
            + qf[4] * bf2f(k8[4]) + qf[5] * bf2f(k8[5])
            + qf[6] * bf2f(k8[6]) + qf[7] * bf2f(k8[7]);
    d += __shfl_xor(d, 1);
    d += __shfl_xor(d, 2);
    d += __shfl_xor(d, 4);
    mx = fmaxf(mx, d);
    sm += d;
  }
  if ((lane & 7) == 0) Ms[z * Ls + l] = mx - sm * (1.0f / Ls);
}

// runtime-U fallback
__global__ __launch_bounds__(256) void k_mscore4g(
    const __hip_bfloat16* __restrict__ Qzb, const __hip_bfloat16* __restrict__ Kzb,
    const int* __restrict__ smp, float* __restrict__ Ms, int U)
{
  const int bid = blockIdx.x;
  const int swz = (bid & 7) * 256 + (bid >> 3);
  const int gw = swz * 4 + (threadIdx.x >> 6);
  const int lane = threadIdx.x & 63;
  const int li = lane >> 3, dp = (lane & 7) * 8;
  const int l = (gw & 127) * 8 + li;
  const int z = gw >> 7;
  const short8v q8 = *(const short8v*)(Qzb + ((size_t)z * Ls + l) * 64 + dp);
  float qf[8];
#pragma unroll
  for (int j = 0; j < 8; ++j) qf[j] = bf2f(q8[j]);
  const __hip_bfloat16* kzb = Kzb + (size_t)z * Ls * 64 + dp;
  float mx = -1e30f, sm = 0.f;
  for (int u = 0; u < U; ++u) {
    const short8v k8 = *(const short8v*)(kzb + (size_t)smp[l * U + u] * 64);
    float d = qf[0] * bf2f(k8[0]) + qf[1] * bf2f(k8[1])
            + qf[2] * bf2f(k8[2]) + qf[3] * bf2f(k8[3])
            + qf[4] * bf2f(k8[4]) + qf[5] * bf2f(k8[5])
            + qf[6] * bf2f(k8[6]) + qf[7] * bf2f(k8[7]);
    d += __shfl_xor(d, 1);
    d += __shfl_xor(d, 2);
    d += __shfl_xor(d, 4);
    mx = fmaxf(mx, d);
    sm += d;
  }
  if ((lane & 7) == 0) Ms[z * Ls + l] = mx - sm * (1.0f / Ls);
}

// ---------------- wave-parallel top-U ----------------
__global__ __launch_bounds__(64) void k_topk_w(
    const float* __restrict__ Ms, int* __restrict__ top, int U)
{
  const int z = blockIdx.x, lane = threadIdx.x;
  float v[16];
#pragma unroll
  for (int j = 0; j < 16; ++j) v[j] = Ms[z * Ls + j * 64 + lane];
  for (int it = 0; it < U; ++it) {
    float bv = -1e30f; int bi = 0x7fffffff;
#pragma unroll
    for (int j = 0; j < 16; ++j) {
      const int idx = j * 64 + lane;
      if (v[j] > bv) { bv = v[j]; bi = idx; }
    }
#pragma unroll
    for (int off = 1; off < 64; off <<= 1) {
      const float ov = __shfl_xor(bv, off);
      const int   oi = __shfl_xor(bi, off);
      if (ov > bv || (ov == bv && oi < bi)) { bv = ov; bi = oi; }
    }
    if (lane == 0) top[z * U + it] = bi;
    if ((bi & 63) == lane) v[bi >> 6] = -1e30f;
  }
}

// ------- LayerNorm over sum of NP partials (+bias) (+residual) -------
template<int NP>
__global__ __launch_bounds__(256) void k_ln2(
    const float* __restrict__ x0, const float* __restrict__ x1,
    const float* __restrict__ x2, const float* __restrict__ x3,
    const float* __restrict__ res, const float* __restrict__ bias,
    const float* __restrict__ g, const float* __restrict__ be,
    float* __restrict__ outf, __hip_bfloat16* __restrict__ outb)
{
  __shared__ float red[4];
  const int row = blockIdx.x, tid = threadIdx.x;
  const size_t base = (size_t)row * DM;
  float2 v = *reinterpret_cast<const float2*>(x0 + base + tid * 2);
  if (NP > 1) {
    float2 a = *reinterpret_cast<const float2*>(x1 + base + tid * 2);
    v.x += a.x; v.y += a.y;
  }
  if (NP > 2) {
    float2 a = *reinterpret_cast<const float2*>(x2 + base + tid * 2);
    v.x += a.x; v.y += a.y;
  }
  if (NP > 3) {
    float2 a = *reinterpret_cast<const float2*>(x3 + base + tid * 2);
    v.x += a.x; v.y += a.y;
  }
  if (bias) {
    float2 a = *reinterpret_cast<const float2*>(bias + tid * 2);
    v.x += a.x; v.y += a.y;
  }
  if (res) {
    float2 r2 = *reinterpret_cast<const float2*>(res + base + tid * 2);
    v.x += r2.x; v.y += r2.y;
  }
  float s = v.x + v.y;
#pragma unroll
  for (int off = 32; off; off >>= 1) s += __shfl_xor(s, off);
  if ((tid & 63) == 0) red[tid >> 6] = s;
  __syncthreads();
  s = red[0] + red[1] + red[2] + red[3];
  const float mean = s * (1.0f / DM);
  __syncthreads();
  float dx = v.x - mean, dy = v.y - mean;
  float q = dx * dx + dy * dy;
#pragma unroll
  for (int off = 32; off; off >>= 1) q += __shfl_xor(q, off);
  if ((tid & 63) == 0) red[tid >> 6] = q;
  __syncthreads();
  q = red[0] + red[1] + red[2] + red[3];
  const float inv = rsqrtf(q * (1.0f / DM) + 1e-5f);
  float2 gg = *reinterpret_cast<const float2*>(g + tid * 2);
  float2 bb = *reinterpret_cast<const float2*>(be + tid * 2);
  float ox = dx * inv * gg.x + bb.x;
  float oy = dy * inv * gg.y + bb.y;
  if (outf) {
    float2 o; o.x = ox; o.y = oy;
    *reinterpret_cast<float2*>(outf + base + tid * 2) = o;
  }
  if (outb) {
    short2 ob; ob.x = f2bf(ox); ob.y = f2bf(oy);
    *reinterpret_cast<short2*>(outb + base + tid * 2) = ob;
  }
}

extern "C" void kernel_launch(void* const* d_in, const int* in_sizes, int n_in,
                              void* d_out, int out_size, void* d_ws, size_t ws_size,
                              hipStream_t stream)
{
  const float* tgt = (const float*)d_in[0];
  const float* mem = (const float*)d_in[1];
  const int*   smp = (const int*)d_in[2];
  const float* wq1 = (const float*)d_in[3];  const float* bq1 = (const float*)d_in[4];
  const float* wk1 = (const float*)d_in[5];  const float* bk1 = (const float*)d_in[6];
  const float* wv1 = (const float*)d_in[7];  const float* bv1 = (const float*)d_in[8];
  const float* wo1 = (const float*)d_in[9];  const float* bo1 = (const float*)d_in[10];
  const float* wq2 = (const float*)d_in[11]; const float* bq2 = (const float*)d_in[12];
  const float* wk2 = (const float*)d_in[13]; const float* bk2 = (const float*)d_in[14];
  const float* wv2 = (const float*)d_in[15]; const float* bv2 = (const float*)d_in[16];
  const float* wo2 = (const float*)d_in[17]; const float* bo2 = (const float*)d_in[18];
  const float* c1w = (const float*)d_in[19]; const float* c1b = (const float*)d_in[20];
  const float* c2w = (const float*)d_in[21]; const float* c2b = (const float*)d_in[22];
  const float* g1  = (const float*)d_in[23]; const float* be1 = (const float*)d_in[24];
  const float* g2  = (const float*)d_in[25]; const float* be2 = (const float*)d_in[26];
  const float* g3  = (const float*)d_in[27]; const float* be3 = (const float*)d_in[28];
  float* outp = (float*)d_out;

  const int U   = in_sizes[2] / Ls;            // 35

  char* ws = (char*)d_ws;
  const size_t SZ = (size_t)MR * DM * sizeof(float);       // 16.78 MB
  float* Qz   = (float*)(ws);
  float* Kz   = (float*)(ws + SZ);
  float* W0   = Qz;
  float* W1   = Kz;
  float* W2   = (float*)(ws + 2 * SZ);
  float* Sbuf = (float*)(ws + 3 * SZ);                     // FFN hidden / QKzb region
  float* Op   = Sbuf + (size_t)ZH * 64 * Ls;               // prob PV partials
  __hip_bfloat16* QKzb = (__hip_bfloat16*)Sbuf;            // Qzb, then Kzb
  __hip_bfloat16* Qzb = QKzb;
  __hip_bfloat16* Kzb = QKzb + (size_t)ZH * Ls * 64;
  __hip_bfloat16* Tb  = (__hip_bfloat16*)(ws + 5 * SZ);
  __hip_bfloat16* Mb  = (__hip_bfloat16*)(ws + 5 * SZ + SZ / 2);
  __hip_bfloat16* Xb  = (__hip_bfloat16*)(ws + 6 * SZ);
  __hip_bfloat16* Vtb = (__hip_bfloat16*)(ws + 6 * SZ + SZ / 2);
  __hip_bfloat16* Wt3 = Vtb;                 // [wq1b;wk1b;wv1b] (dead before Vtb written)
  float* CP2 = (float*)(ws + 5 * SZ);        // conv2 partial 2
  float* CP3 = (float*)(ws + 6 * SZ);        // conv2 partial 3
  char* tail = ws + 7 * SZ;
  __hip_bfloat16* wo1b = (__hip_bfloat16*)tail; tail += DM * DM * 2;
  __hip_bfloat16* wq2b = (__hip_bfloat16*)tail; tail += DM * DM * 2;
  __hip_bfloat16* wk2b = (__hip_bfloat16*)tail; tail += DM * DM * 2;
  __hip_bfloat16* wv2b = (__hip_bfloat16*)tail; tail += DM * DM * 2;
  __hip_bfloat16* wo2b = (__hip_bfloat16*)tail; tail += DM * DM * 2;
  __hip_bfloat16* c1wb = (__hip_bfloat16*)tail; tail += DM * 4 * DM * 2;
  __hip_bfloat16* c2wb = (__hip_bfloat16*)tail; tail += DM * 4 * DM * 2;
  float* Ms  = (float*)tail; tail += (size_t)ZH * Ls * 4;
  int*   top = (int*)tail;   tail += (size_t)ZH * 64 * 4;
  float* mvp = (float*)tail; tail += (size_t)ZH * 16 * DHd * 4;
  float* Ml  = (float*)tail; tail += (size_t)16 * ZH * 64 * 4;
  float* Ll  = (float*)tail; tail += (size_t)16 * ZH * 64 * 4;
  __hip_bfloat16* Kb = Tb;
  __hip_bfloat16* Qb = (__hip_bfloat16*)d_out;  // parked until final LN
  __hip_bfloat16* hb = (__hip_bfloat16*)Sbuf;

  // ---- ALL converts, one dispatch ----
  CvtArgs ca;
  ca.s[0] = wq1; ca.d[0] = Wt3;
  ca.s[1] = wk1; ca.d[1] = Wt3 + DM * DM;
  ca.s[2] = wv1; ca.d[2] = Wt3 + 2 * DM * DM;
  ca.s[3] = wo1; ca.d[3] = wo1b;
  ca.s[4] = wq2; ca.d[4] = wq2b;
  ca.s[5] = wk2; ca.d[5] = wk2b;
  ca.s[6] = wv2; ca.d[6] = wv2b;
  ca.s[7] = wo2; ca.d[7] = wo2b;
  ca.s[8] = c1w; ca.d[8] = c1wb;
  ca.s[9] = c2w; ca.d[9] = c2wb;
  ca.s[10] = tgt; ca.d[10] = Tb;
  ca.s[11] = mem; ca.d[11] = Mb;
  k_cvt_all<<<dim3(12288), 256, 0, stream>>>(ca);

  // ---- layer-1 projections: ONE batched GEMM (Q->Qz(+bf16), K->Kz(+bf16), V->W2) ----
  k_gemm_mfma<10, 0><<<dim3(MR / 128, 12), 256, 0, stream>>>(
      Tb, Wt3, bq1, bk1, bv1, Qz, Kz, W2, QKzb, MR, 1536, DM);

  // ---- ProbSparse ----
  if (U == 35)
    k_mscore4<35><<<dim3(2048), 256, 0, stream>>>(Qzb, Kzb, smp, Ms);
  else
    k_mscore4g<<<dim3(2048), 256, 0, stream>>>(Qzb, Kzb, smp, Ms, U);
  k_topk_w<<<dim3(ZH), 64, 0, stream>>>(Ms, top, U);
  k_probflash<<<dim3(16 * ZH), 256, 0, stream>>>(Qz, Kz, W2, top, Op, Ml, Ll, mvp, U);
  k_prob_comb2<<<dim3(ZH), 256, 0, stream>>>(Op, Ml, Ll, top, mvp, Xb, U);

  // ---- out-proj 1 (split-K=2) + residual LN (fused reduce) ----
  k_gemm_mfma<20, 0><<<dim3(MR / 128, DM / 128, 2), 256, 0, stream>>>(
      Xb, wo1b, nullptr, nullptr, nullptr, W0, W1, nullptr, nullptr, MR, DM, DM);
  k_ln2<2><<<dim3(MR), 256, 0, stream>>>(W0, W1, nullptr, nullptr,
                                         tgt, bo1, g1, be1, nullptr, Xb);

  // ---- layer-2 projections: ONE triple (Q from Xb; K,V from Mb via aux3) ----
  k_gemm_mfma<12, 0><<<dim3(MR / 128, 12), 256, 0, stream>>>(
      Xb, wq2b, bq2, bk2, bv2, Qb, Kb, Vtb, (void*)Mb, MR, 1536, DM);

  // ---- fused flash cross attention -> Xb (bf16) ----
  k_flash2<<<dim3(Ls / 128, ZH), 512, 0, stream>>>(Qb, Kb, Vtb, Xb);

  // ---- out-proj 2 (split-K=2) + LN (fused) ----
  k_gemm_mfma<20, 0><<<dim3(MR / 128, DM / 128, 2), 256, 0, stream>>>(
      Xb, wo2b, nullptr, nullptr, nullptr, W0, W2, nullptr, nullptr, MR, DM, DM);
  k_ln2<2><<<dim3(MR), 256, 0, stream>>>(W0, W2, nullptr, nullptr,
                                         nullptr, bo2, g2, be2, W1, Xb);

  // ---- FFN ----
  k_gemm_mfma<1, 1><<<dim3(MR / 128, 4 * DM / 128), 256, 0, stream>>>(
      Xb, c1wb, c1b, nullptr, nullptr, hb, nullptr, nullptr, nullptr, MR, 4 * DM, DM);
  k_gemm_mfma<20, 0><<<dim3(MR / 128, DM / 128, 4), 256, 0, stream>>>(
      hb, c2wb, nullptr, nullptr, nullptr, W0, W2, CP2, CP3, MR, DM, 2 * DM * 2);
  k_ln2<4><<<dim3(MR), 256, 0, stream>>>(W0, W2, CP2, CP3,
                                         W1, c2b, g3, be3, outp, nullptr);
}

// Round 11
// 304.376 us; speedup vs baseline: 7.2133x; 1.0922x over previous
//
#include <hip/hip_runtime.h>
#include <hip/hip_bf16.h>
#include <cstdint>

constexpr int Bb  = 8;
constexpr int Ls  = 1024;
constexpr int DM  = 512;
constexpr int NH  = 8;
constexpr int DHd = 64;
constexpr int MR  = Bb * Ls;   // 8192 rows
constexpr int ZH  = Bb * NH;   // 64 (b,h) pairs

typedef __attribute__((ext_vector_type(8))) short short8v;
typedef __attribute__((ext_vector_type(4))) short short4v;
typedef __attribute__((ext_vector_type(4))) float floatx4;

__device__ inline short f2bf(float x) {
  __hip_bfloat16 h = __float2bfloat16(x);
  return *reinterpret_cast<short*>(&h);
}
__device__ inline float bf2f(short s) {
  return __uint_as_float(((uint32_t)(uint16_t)s) << 16);
}

#define GLOAD_LDS16(g, l)                                                        \
  __builtin_amdgcn_global_load_lds(                                              \
      (const __attribute__((address_space(1))) void*)(g),                        \
      (__attribute__((address_space(3))) void*)(l), 16, 0, 0)

// ================= bf16 MFMA GEMM, double-buffered prefetch =================
// MODE: 1 bf16 out |
// 10 L1 triple (N=1536: Q->Qzb bf16 compact, K->Kzb bf16 compact, V->merged f32)
//    aux2 = V f32 merged; aux3 = QKzb base (Qzb, then Kzb at +ZH*Ls*64)
// 12 L2 triple (N=1536: Q(x1)->Qb bf16 x0.125, K(mem)->Kb swizzled, V(mem)->Vt
//    transposed, vectorized); aux3 = second A matrix (mem) used for bn>=512
// 20 split-K raw f32 partial (no bias; partial z -> Cout/aux1/aux2/aux3)
template<int MODE, int RELU>
__global__ __launch_bounds__(256) void k_gemm_mfma(
    const __hip_bfloat16* __restrict__ A, const __hip_bfloat16* __restrict__ Wt,
    const float* __restrict__ bias, const float* __restrict__ bias1,
    const float* __restrict__ bias2,
    void* __restrict__ Cout, void* __restrict__ aux1, void* __restrict__ aux2,
    void* __restrict__ aux3,
    int M, int N, int K)
{
  __shared__ __hip_bfloat16 As[2][128 * 32];
  __shared__ __hip_bfloat16 Bs[2][128 * 32];
  const int tid = threadIdx.x;
  const int w = tid >> 6, lane = tid & 63;
  const int wr = w >> 1, wc = w & 1;
  const int bm = blockIdx.x * 128, bn = blockIdx.y * 128;
  const int lrow = lane >> 2;
  const int lcol = (lane & 3) * 8;
  const int fr = lane & 15;
  const int fco = (lane >> 4) * 8;

  const __hip_bfloat16* Asrc = A;
  if (MODE == 12 && bn >= 512) Asrc = (const __hip_bfloat16*)aux3;

  const int ksl = K / gridDim.z;
  const int kb0 = blockIdx.z * ksl;
  const int nst = ksl / 32;

  const int chunk0 = w * 2, chunk1 = w * 2 + 1;
  const size_t aoff0 = (size_t)(bm + chunk0 * 16 + lrow) * K + lcol;
  const size_t aoff1 = (size_t)(bm + chunk1 * 16 + lrow) * K + lcol;
  const size_t boff0 = (size_t)(bn + chunk0 * 16 + lrow) * K + lcol;
  const size_t boff1 = (size_t)(bn + chunk1 * 16 + lrow) * K + lcol;

  {
    const int k0 = kb0;
    GLOAD_LDS16(Asrc + aoff0 + k0, &As[0][chunk0 * 512]);
    GLOAD_LDS16(Asrc + aoff1 + k0, &As[0][chunk1 * 512]);
    GLOAD_LDS16(Wt + boff0 + k0, &Bs[0][chunk0 * 512]);
    GLOAD_LDS16(Wt + boff1 + k0, &Bs[0][chunk1 * 512]);
  }
  asm volatile("s_waitcnt vmcnt(0)" ::: "memory");
  __builtin_amdgcn_s_barrier();

  floatx4 acc[4][4] = {};
  int cur = 0;
  for (int t = 0; t < nst; ++t) {
    if (t + 1 < nst) {
      const int k0 = kb0 + (t + 1) * 32;
      GLOAD_LDS16(Asrc + aoff0 + k0, &As[cur ^ 1][chunk0 * 512]);
      GLOAD_LDS16(Asrc + aoff1 + k0, &As[cur ^ 1][chunk1 * 512]);
      GLOAD_LDS16(Wt + boff0 + k0, &Bs[cur ^ 1][chunk0 * 512]);
      GLOAD_LDS16(Wt + boff1 + k0, &Bs[cur ^ 1][chunk1 * 512]);
    }
    const short* Ash = (const short*)As[cur];
    const short* Bsh = (const short*)Bs[cur];
    short8v a[4], b[4];
#pragma unroll
    for (int mi = 0; mi < 4; ++mi)
      a[mi] = *(const short8v*)(Ash + (wr * 64 + mi * 16 + fr) * 32 + fco);
#pragma unroll
    for (int ni = 0; ni < 4; ++ni)
      b[ni] = *(const short8v*)(Bsh + (wc * 64 + ni * 16 + fr) * 32 + fco);
#pragma unroll
    for (int mi = 0; mi < 4; ++mi)
#pragma unroll
      for (int ni = 0; ni < 4; ++ni)
        acc[mi][ni] = __builtin_amdgcn_mfma_f32_16x16x32_bf16(
            a[mi], b[ni], acc[mi][ni], 0, 0, 0);
    asm volatile("s_waitcnt vmcnt(0)" ::: "memory");
    __builtin_amdgcn_s_barrier();
    cur ^= 1;
  }
#pragma unroll
  for (int ni = 0; ni < 4; ++ni) {
    const int cn = bn + wc * 64 + ni * 16 + fr;
    float bv = 0.f;
    if (MODE == 10 || MODE == 12) {
      const float* bp = (cn < 512) ? bias : (cn < 1024 ? bias1 : bias2);
      bv = bp[cn & 511];
    } else if (MODE != 20) {
      bv = bias[cn];
    }
#pragma unroll
    for (int mi = 0; mi < 4; ++mi) {
      const int rm0 = bm + wr * 64 + mi * 16 + (lane >> 4) * 4;
      float vv[4];
#pragma unroll
      for (int j = 0; j < 4; ++j) {
        float v = acc[mi][ni][j] + bv;
        if (RELU) v = fmaxf(v, 0.f);
        vv[j] = v;
      }
      if (MODE == 1) {
#pragma unroll
        for (int j = 0; j < 4; ++j)
          ((__hip_bfloat16*)Cout)[(size_t)(rm0 + j) * N + cn] = __float2bfloat16(vv[j]);
      } else if (MODE == 10) {
        const int sel = cn >> 9, c = cn & 511;
        if (sel == 2) {
#pragma unroll
          for (int j = 0; j < 4; ++j)
            ((float*)aux2)[(size_t)(rm0 + j) * 512 + c] = vv[j];
        } else {
          const int hh = c >> 6, dd = c & 63;
          const int bb = rm0 >> 10, l0 = rm0 & 1023;
          __hip_bfloat16* bb16 = (__hip_bfloat16*)aux3 +
                                 (sel ? (size_t)ZH * Ls * 64 : 0);
#pragma unroll
          for (int j = 0; j < 4; ++j)
            bb16[(((size_t)(bb * 8 + hh)) * 1024 + l0 + j) * 64 + dd] =
                __float2bfloat16(vv[j]);
        }
      } else if (MODE == 12) {
        const int sel = cn >> 9, c = cn & 511;
        if (sel == 0) {
#pragma unroll
          for (int j = 0; j < 4; ++j)
            ((__hip_bfloat16*)Cout)[(size_t)(rm0 + j) * 512 + c] =
                __float2bfloat16(vv[j] * 0.125f);
        } else if (sel == 1) {
          const int cs = (c & ~63) | ((c & 63) ^ ((rm0 & 7) << 3));
          // note: rows rm0..rm0+3 share (rm&7)>>?  No: (rm&7) varies with j.
#pragma unroll
          for (int j = 0; j < 4; ++j) {
            const int rm = rm0 + j;
            const int cj = (c & ~63) | ((c & 63) ^ ((rm & 7) << 3));
            ((__hip_bfloat16*)aux1)[(size_t)rm * 512 + cj] = __float2bfloat16(vv[j]);
          }
          (void)cs;
        } else {
          // V transpose: 4 consecutive l -> one 8B vector write (XOR-safe)
          const int hh = c >> 6, dd = c & 63;
          const int bb = rm0 >> 10, l0 = rm0 & 1023;
          short4v pk;
#pragma unroll
          for (int j = 0; j < 4; ++j) pk[j] = f2bf(vv[j]);
          *(short4v*)((__hip_bfloat16*)aux2 +
                      (size_t)((bb * 8 + hh) * 64 + dd) * 1024 +
                      ((l0 ^ ((dd & 7) << 3)))) = pk;
        }
      } else if (MODE == 20) {
        float* pz = (float*)(blockIdx.z == 0 ? Cout :
                    blockIdx.z == 1 ? aux1 :
                    blockIdx.z == 2 ? aux2 : aux3);
#pragma unroll
        for (int j = 0; j < 4; ++j)
          pz[(size_t)(rm0 + j) * N + cn] = vv[j];
      }
    }
  }
}

// ===== fused flash cross-attention v2: 512 thr, dbuf K/V, defer-max, setprio =====
__global__ __launch_bounds__(512) void k_flash2(
    const __hip_bfloat16* __restrict__ Qb,
    const __hip_bfloat16* __restrict__ Kb,
    const __hip_bfloat16* __restrict__ Vt,
    __hip_bfloat16* __restrict__ O)
{
  __shared__ __hip_bfloat16 Ks[2][64 * 64];
  __shared__ __hip_bfloat16 Vs[2][64 * 64];
  __shared__ __hip_bfloat16 Ps[8 * 16 * 72];
  const int tid = threadIdx.x, w = tid >> 6, lane = tid & 63;
  const int g = lane >> 4, r = lane & 15;
  const int z = blockIdx.y, b = z >> 3, h = z & 7;
  const int q0 = blockIdx.x * 128 + w * 16;
  __hip_bfloat16* Pw = Ps + w * 16 * 72;

  const int srow = w * 8 + (lane >> 3);
  const int sseg = lane & 7;

  const short8v qf0 = *(const short8v*)(Qb + (size_t)(b * Ls + q0 + r) * DM + h * DHd + g * 8);
  const short8v qf1 = *(const short8v*)(Qb + (size_t)(b * Ls + q0 + r) * DM + h * DHd + 32 + g * 8);

  floatx4 oacc[4] = {};
  float m_run = -1e30f, l_run = 0.f;

  GLOAD_LDS16(Kb + (size_t)(b * Ls + srow) * DM + h * DHd + sseg * 8, &Ks[0][w * 512]);
  GLOAD_LDS16(Vt + ((size_t)z * DHd + srow) * Ls + sseg * 8, &Vs[0][w * 512]);
  asm volatile("s_waitcnt vmcnt(0)" ::: "memory");
  __builtin_amdgcn_s_barrier();

  int cur = 0;
  for (int t = 0; t < 16; ++t) {
    if (t + 1 < 16) {
      GLOAD_LDS16(Kb + (size_t)(b * Ls + (t + 1) * 64 + srow) * DM + h * DHd + sseg * 8,
                  &Ks[cur ^ 1][w * 512]);
      GLOAD_LDS16(Vt + ((size_t)z * DHd + srow) * Ls + (t + 1) * 64 + sseg * 8,
                  &Vs[cur ^ 1][w * 512]);
    }
    const __hip_bfloat16* Kc = Ks[cur];
    const __hip_bfloat16* Vc = Vs[cur];
    float sv[4][4];
    float tmax = -1e30f;
    __builtin_amdgcn_s_setprio(1);
#pragma unroll
    for (int kt = 0; kt < 4; ++kt) {
      const int key = kt * 16 + r, sw = key & 7;
      short8v a0 = *(const short8v*)(Kc + key * 64 + ((g ^ sw) * 8));
      short8v a1 = *(const short8v*)(Kc + key * 64 + (((4 + g) ^ sw) * 8));
      floatx4 c = {};
      c = __builtin_amdgcn_mfma_f32_16x16x32_bf16(a0, qf0, c, 0, 0, 0);
      c = __builtin_amdgcn_mfma_f32_16x16x32_bf16(a1, qf1, c, 0, 0, 0);
#pragma unroll
      for (int j = 0; j < 4; ++j) {
        float x = c[j];
        sv[kt][j] = x;
        tmax = fmaxf(tmax, x);
      }
    }
    __builtin_amdgcn_s_setprio(0);
    tmax = fmaxf(tmax, __shfl_xor(tmax, 16));
    tmax = fmaxf(tmax, __shfl_xor(tmax, 32));
    float m_new;
    if (__all(tmax <= m_run + 8.0f)) {
      m_new = m_run;
    } else {
      m_new = fmaxf(m_run, tmax);
      const float fac = __expf(m_run - m_new);
      float fj[4];
#pragma unroll
      for (int j = 0; j < 4; ++j) fj[j] = __shfl(fac, (lane & 48) | (g * 4 + j));
#pragma unroll
      for (int ct = 0; ct < 4; ++ct)
#pragma unroll
        for (int j = 0; j < 4; ++j) oacc[ct][j] *= fj[j];
      l_run *= fac;
    }
    float psum = 0.f;
#pragma unroll
    for (int kt = 0; kt < 4; ++kt) {
      short4v pk;
#pragma unroll
      for (int j = 0; j < 4; ++j) {
        float p = __expf(sv[kt][j] - m_new);
        psum += p;
        pk[j] = f2bf(p);
      }
      *(short4v*)(Pw + r * 72 + kt * 16 + g * 4) = pk;
    }
    psum += __shfl_xor(psum, 16);
    psum += __shfl_xor(psum, 32);
    l_run += psum;
    m_run = m_new;
    const short8v pa0 = *(const short8v*)(Pw + r * 72 + g * 8);
    const short8v pa1 = *(const short8v*)(Pw + r * 72 + 32 + g * 8);
    __builtin_amdgcn_s_setprio(1);
#pragma unroll
    for (int ct = 0; ct < 4; ++ct) {
      const int d = ct * 16 + r, sw = d & 7;
      short8v v0 = *(const short8v*)(Vc + d * 64 + ((g ^ sw) * 8));
      short8v v1 = *(const short8v*)(Vc + d * 64 + (((4 + g) ^ sw) * 8));
      oacc[ct] = __builtin_amdgcn_mfma_f32_16x16x32_bf16(pa0, v0, oacc[ct], 0, 0, 0);
      oacc[ct] = __builtin_amdgcn_mfma_f32_16x16x32_bf16(pa1, v1, oacc[ct], 0, 0, 0);
    }
    __builtin_amdgcn_s_setprio(0);
    asm volatile("s_waitcnt vmcnt(0)" ::: "memory");
    __builtin_amdgcn_s_barrier();
    cur ^= 1;
  }
  float li[4];
#pragma unroll
  for (int j = 0; j < 4; ++j)
    li[j] = 1.0f / __shfl(l_run, (lane & 48) | (g * 4 + j));
#pragma unroll
  for (int ct = 0; ct < 4; ++ct)
#pragma unroll
    for (int j = 0; j < 4; ++j)
      O[(size_t)(b * Ls + q0 + g * 4 + j) * DM + h * DHd + ct * 16 + r] =
          __float2bfloat16(oacc[ct][j] * li[j]);
}

// ---------------- ALL converts (2 activations + 10 weights) in one dispatch ----------------
struct CvtArgs { const float* s[12]; __hip_bfloat16* d[12]; };
__global__ __launch_bounds__(256) void k_cvt_all(CvtArgs a)
{
  const int bid = blockIdx.x, tid = threadIdx.x;
  if (bid < 8192) {
    const size_t half = (size_t)MR * DM / 4;
    size_t i = (size_t)bid * 256 + tid;
    const float* in = a.s[10]; __hip_bfloat16* out = a.d[10];
    if (i >= half) { i -= half; in = a.s[11]; out = a.d[11]; }
    float4 v = *reinterpret_cast<const float4*>(in + i * 4);
    short4v o;
    o.x = f2bf(v.x); o.y = f2bf(v.y); o.z = f2bf(v.z); o.w = f2bf(v.w);
    *reinterpret_cast<short4v*>(out + i * 4) = o;
    return;
  }
  __shared__ float t[32][33];
  const int wb = bid - 8192;
  int widx, K, N, kblk, nblk;
  if (wb < 2048) {
    widx = wb >> 8; const int w2 = wb & 255;
    K = 512; N = 512; kblk = w2 & 15; nblk = w2 >> 4;
  } else if (wb < 3072) {
    widx = 8; const int w2 = wb - 2048;
    K = 512; N = 2048; kblk = w2 & 15; nblk = w2 >> 4;
  } else {
    widx = 9; const int w2 = wb - 3072;
    K = 2048; N = 512; kblk = w2 & 63; nblk = w2 >> 6;
  }
  const float* W = a.s[widx];
  __hip_bfloat16* Wt = a.d[widx];
  const int k0 = kblk * 32, n0 = nblk * 32;
  const int r = tid >> 3, c = (tid & 7) * 4;
  float4 v = *reinterpret_cast<const float4*>(W + (size_t)(k0 + r) * N + n0 + c);
  t[r][c + 0] = v.x; t[r][c + 1] = v.y; t[r][c + 2] = v.z; t[r][c + 3] = v.w;
  __syncthreads();
  short4v o;
  o.x = f2bf(t[c + 0][r]); o.y = f2bf(t[c + 1][r]);
  o.z = f2bf(t[c + 2][r]); o.w = f2bf(t[c + 3][r]);
  *reinterpret_cast<short4v*>(Wt + (size_t)(n0 + r) * K + k0 + c) = o;
}

// ====== fused prob attention chunk (bf16 Q/K in, f32 compute): ======
// S=Q[top]K^T, partial softmax, PV, V-colsum
__global__ __launch_bounds__(256) void k_probflash(
    const __hip_bfloat16* __restrict__ Qzb, const __hip_bfloat16* __restrict__ Kzb,
    const float* __restrict__ Vm, const int* __restrict__ top,
    float* __restrict__ Op, float* __restrict__ Ml, float* __restrict__ Ll,
    float* __restrict__ mvp, int U)
{
  __shared__ float Qs[DHd][64 + 4];
  __shared__ float Ks[DHd][64 + 4];
  __shared__ float Vs[64][64];
  __shared__ float ps[4][64];
  const int bid = blockIdx.x;
  const int swz = (bid & 7) * ((16 * ZH) >> 3) + (bid >> 3);
  const int kc = swz & 15, z = swz >> 4, b = z >> 3, h = z & 7;
  const int tid = threadIdx.x;
  const int k0 = kc * 64;
#pragma unroll
  for (int i = 0; i < 4; ++i) {
    const int idx = tid + (i << 8);
    const int r = idx >> 4, c4 = (idx & 15) << 2;
    int u = r; if (u >= U) u = U - 1;
    const int qr = top[z * U + u];
    short4v q4 = *reinterpret_cast<const short4v*>(Qzb + ((size_t)z * Ls + qr) * 64 + c4);
    Qs[c4 + 0][r] = bf2f(q4.x); Qs[c4 + 1][r] = bf2f(q4.y);
    Qs[c4 + 2][r] = bf2f(q4.z); Qs[c4 + 3][r] = bf2f(q4.w);
    short4v k4 = *reinterpret_cast<const short4v*>(Kzb + ((size_t)z * Ls + k0 + r) * 64 + c4);
    Ks[c4 + 0][r] = bf2f(k4.x); Ks[c4 + 1][r] = bf2f(k4.y);
    Ks[c4 + 2][r] = bf2f(k4.z); Ks[c4 + 3][r] = bf2f(k4.w);
    *reinterpret_cast<float4*>(&Vs[r][c4]) =
        *reinterpret_cast<const float4*>(Vm + ((size_t)(b * Ls + k0 + r)) * DM + h * DHd + c4);
  }
  __syncthreads();
  const int mB = (tid >> 4) << 2, nB = (tid & 15) << 2;
  float acc[4][4] = {};
#pragma unroll
  for (int kk = 0; kk < DHd; ++kk) {
    float4 a4 = *reinterpret_cast<const float4*>(&Qs[kk][mB]);
    float4 b4 = *reinterpret_cast<const float4*>(&Ks[kk][nB]);
    const float av[4] = {a4.x, a4.y, a4.z, a4.w};
#pragma unroll
    for (int i = 0; i < 4; ++i) {
      acc[i][0] += av[i] * b4.x; acc[i][1] += av[i] * b4.y;
      acc[i][2] += av[i] * b4.z; acc[i][3] += av[i] * b4.w;
    }
  }
  __syncthreads();
  float (*Ss)[68] = (float (*)[68])Qs;
#pragma unroll
  for (int i = 0; i < 4; ++i) {
    float4 o;
    o.x = acc[i][0] * 0.125f; o.y = acc[i][1] * 0.125f;
    o.z = acc[i][2] * 0.125f; o.w = acc[i][3] * 0.125f;
    *reinterpret_cast<float4*>(&Ss[mB + i][nB]) = o;
  }
  __syncthreads();
  {
    const int row = tid >> 2, q = tid & 3;
    float mx = -1e30f;
#pragma unroll
    for (int j = 0; j < 16; ++j) mx = fmaxf(mx, Ss[row][q * 16 + j]);
    mx = fmaxf(mx, __shfl_xor(mx, 1));
    mx = fmaxf(mx, __shfl_xor(mx, 2));
    float se = 0.f;
#pragma unroll
    for (int j = 0; j < 16; ++j) {
      float p = __expf(Ss[row][q * 16 + j] - mx);
      Ss[row][q * 16 + j] = p;
      se += p;
    }
    se += __shfl_xor(se, 1);
    se += __shfl_xor(se, 2);
    if (q == 0) {
      Ml[((size_t)kc * ZH + z) * 64 + row] = mx;
      Ll[((size_t)kc * ZH + z) * 64 + row] = se;
    }
  }
  __syncthreads();
  const int d = tid & 63, w = tid >> 6;
  {
    float s = 0.f;
#pragma unroll
    for (int i = 0; i < 16; ++i) s += Vs[w * 16 + i][d];
    ps[w][d] = s;
  }
  float acc2[16] = {};
  for (int k = 0; k < 64; ++k) {
    const float vk = Vs[k][d];
#pragma unroll
    for (int i = 0; i < 16; ++i)
      acc2[i] += Ss[w * 16 + i][k] * vk;
  }
  float* outb = Op + ((size_t)kc * ZH + z) * 4096;
#pragma unroll
  for (int i = 0; i < 16; ++i)
    outb[(w * 16 + i) * 64 + d] = acc2[i];
  __syncthreads();
  if (w == 0)
    mvp[((size_t)z * 16 + kc) * 64 + d] = ps[0][d] + ps[1][d] + ps[2][d] + ps[3][d];
}

// ------ per-z: meanV fill of whole slice + flash-combine scatter of top-U ------
__global__ __launch_bounds__(256) void k_prob_comb2(
    const float* __restrict__ Op, const float* __restrict__ Ml,
    const float* __restrict__ Ll, const int* __restrict__ top,
    const float* __restrict__ mvp, __hip_bfloat16* __restrict__ ctx, int U)
{
  __shared__ float wsh[16][64];
  __shared__ float Lsh[64];
  __shared__ short4v mvb[16];
  const int z = blockIdx.x, b = z >> 3, h = z & 7;
  const int tid = threadIdx.x;
  if (tid < 64) {
    float M = -1e30f;
#pragma unroll
    for (int c = 0; c < 16; ++c)
      M = fmaxf(M, Ml[((size_t)c * ZH + z) * 64 + tid]);
    float L = 0.f;
#pragma unroll
    for (int c = 0; c < 16; ++c) {
      float wv = __expf(Ml[((size_t)c * ZH + z) * 64 + tid] - M);
      wsh[c][tid] = wv;
      L += wv * Ll[((size_t)c * ZH + z) * 64 + tid];
    }
    Lsh[tid] = L;
    float s = 0.f;
#pragma unroll
    for (int c = 0; c < 16; ++c) s += mvp[((size_t)z * 16 + c) * 64 + tid];
    const short mb = f2bf(s * (1.0f / Ls));
    ((short*)mvb)[tid] = mb;
  }
  __syncthreads();
  __hip_bfloat16* base = ctx + (size_t)(b * Ls) * DM + h * DHd;
  for (int i = tid; i < 1024 * 16; i += 256) {
    const int row = i >> 4, c4 = i & 15;
    *reinterpret_cast<short4v*>(base + (size_t)row * DM + c4 * 4) = mvb[c4];
  }
  __syncthreads();
  for (int e = tid; e < U * 64; e += 256) {
    const int u = e >> 6, d = e & 63;
    float s = 0.f;
#pragma unroll
    for (int c = 0; c < 16; ++c)
      s += wsh[c][u] * Op[((size_t)c * ZH + z) * 4096 + u * 64 + d];
    const int row = top[z * U + u];
    ctx[((size_t)(b * Ls + row)) * DM + h * DHd + d] =
        __float2bfloat16(s / Lsh[u]);
  }
}

// ---- ProbSparse sampled scores, bf16 compact gather, 8 lanes/query ----
template<int UU>
__global__ __launch_bounds__(256) void k_mscore4(
    const __hip_bfloat16* __restrict__ Qzb, const __hip_bfloat16* __restrict__ Kzb,
    const int* __restrict__ smp, float* __restrict__ Ms)
{
  const int bid = blockIdx.x;
  const int swz = (bid & 7) * 256 + (bid >> 3);
  const int gw = swz * 4 + (threadIdx.x >> 6);
  const int lane = threadIdx.x & 63;
  const int li = lane >> 3, dp = (lane & 7) * 8;
  const int l = (gw & 127) * 8 + li;
  const int z = gw >> 7;
  const short8v q8 = *(const short8v*)(Qzb + ((size_t)z * Ls + l) * 64 + dp);
  float qf[8];
#pragma unroll
  for (int j = 0; j < 8; ++j) qf[j] = bf2f(q8[j]);
  int kidx[UU];
#pragma unroll
  for (int u = 0; u < UU; ++u) kidx[u] = smp[l * UU + u];
  const __hip_bfloat16* kzb = Kzb + (size_t)z * Ls * 64 + dp;
  float mx = -1e30f, sm = 0.f;
#pragma unroll
  for (int u = 0; u < UU; ++u) {
    const short8v k8 = *(const short8v*)(kzb + (size_t)kidx[u] * 64);
    float d = qf[0] * bf2f(k8[0]) + qf[1] * bf2f(k8[1])
            + qf[2] * bf2f(k8[2]) + qf[3] * bf2f(k8[3])
            + qf[4] * bf2f(k8[4]) + qf[5] * bf2f(k8[5])
            + qf[6] * bf2f(k8[6]) + qf[7] * bf2f(k8[7]);
    d += __shfl_xor(d, 1);
    d += __shfl_xor(d, 2);
    d += __shfl_xor(d, 4);
    mx = fmaxf(mx, d);
    sm += d;
  }
  if ((lane & 7) == 0) Ms[z * Ls + l] = mx - sm * (1.0f / Ls);
}

// runtime-U fallback
__global__ __launch_bounds__(256) void k_mscore4g(
    const __hip_bfloat16* __restrict__ Qzb, const __hip_bfloat16* __restrict__ Kzb,
    const int* __restrict__ smp, float* __restrict__ Ms, int U)
{
  const int bid = blockIdx.x;
  const int swz = (bid & 7) * 256 + (bid >> 3);
  const int gw = swz * 4 + (threadIdx.x >> 6);
  const int lane = threadIdx.x & 63;
  const int li = lane >> 3, dp = (lane & 7) * 8;
  const int l = (gw & 127) * 8 + li;
  const int z = gw >> 7;
  const short8v q8 = *(const short8v*)(Qzb + ((size_t)z * Ls + l) * 64 + dp);
  float qf[8];
#pragma unroll
  for (int j = 0; j < 8; ++j) qf[j] = bf2f(q8[j]);
  const __hip_bfloat16* kzb = Kzb + (size_t)z * Ls * 64 + dp;
  float mx = -1e30f, sm = 0.f;
  for (int u = 0; u < U; ++u) {
    const short8v k8 = *(const short8v*)(kzb + (size_t)smp[l * U + u] * 64);
    float d = qf[0] * bf2f(k8[0]) + qf[1] * bf2f(k8[1])
            + qf[2] * bf2f(k8[2]) + qf[3] * bf2f(k8[3])
            + qf[4] * bf2f(k8[4]) + qf[5] * bf2f(k8[5])
            + qf[6] * bf2f(k8[6]) + qf[7] * bf2f(k8[7]);
    d += __shfl_xor(d, 1);
    d += __shfl_xor(d, 2);
    d += __shfl_xor(d, 4);
    mx = fmaxf(mx, d);
    sm += d;
  }
  if ((lane & 7) == 0) Ms[z * Ls + l] = mx - sm * (1.0f / Ls);
}

// ---------------- wave-parallel top-U ----------------
__global__ __launch_bounds__(64) void k_topk_w(
    const float* __restrict__ Ms, int* __restrict__ top, int U)
{
  const int z = blockIdx.x, lane = threadIdx.x;
  float v[16];
#pragma unroll
  for (int j = 0; j < 16; ++j) v[j] = Ms[z * Ls + j * 64 + lane];
  for (int it = 0; it < U; ++it) {
    float bv = -1e30f; int bi = 0x7fffffff;
#pragma unroll
    for (int j = 0; j < 16; ++j) {
      const int idx = j * 64 + lane;
      if (v[j] > bv) { bv = v[j]; bi = idx; }
    }
#pragma unroll
    for (int off = 1; off < 64; off <<= 1) {
      const float ov = __shfl_xor(bv, off);
      const int   oi = __shfl_xor(bi, off);
      if (ov > bv || (ov == bv && oi < bi)) { bv = ov; bi = oi; }
    }
    if (lane == 0) top[z * U + it] = bi;
    if ((bi & 63) == lane) v[bi >> 6] = -1e30f;
  }
}

// ------- LayerNorm over sum of NP partials (+bias) (+residual) -------
template<int NP>
__global__ __launch_bounds__(256) void k_ln2(
    const float* __restrict__ x0, const float* __restrict__ x1,
    const float* __restrict__ x2, const float* __restrict__ x3,
    const float* __restrict__ res, const float* __restrict__ bias,
    const float* __restrict__ g, const float* __restrict__ be,
    float* __restrict__ outf, __hip_bfloat16* __restrict__ outb)
{
  __shared__ float red[4];
  const int row = blockIdx.x, tid = threadIdx.x;
  const size_t base = (size_t)row * DM;
  float2 v = *reinterpret_cast<const float2*>(x0 + base + tid * 2);
  if (NP > 1) {
    float2 a = *reinterpret_cast<const float2*>(x1 + base + tid * 2);
    v.x += a.x; v.y += a.y;
  }
  if (NP > 2) {
    float2 a = *reinterpret_cast<const float2*>(x2 + base + tid * 2);
    v.x += a.x; v.y += a.y;
  }
  if (NP > 3) {
    float2 a = *reinterpret_cast<const float2*>(x3 + base + tid * 2);
    v.x += a.x; v.y += a.y;
  }
  if (bias) {
    float2 a = *reinterpret_cast<const float2*>(bias + tid * 2);
    v.x += a.x; v.y += a.y;
  }
  if (res) {
    float2 r2 = *reinterpret_cast<const float2*>(res + base + tid * 2);
    v.x += r2.x; v.y += r2.y;
  }
  float s = v.x + v.y;
#pragma unroll
  for (int off = 32; off; off >>= 1) s += __shfl_xor(s, off);
  if ((tid & 63) == 0) red[tid >> 6] = s;
  __syncthreads();
  s = red[0] + red[1] + red[2] + red[3];
  const float mean = s * (1.0f / DM);
  __syncthreads();
  float dx = v.x - mean, dy = v.y - mean;
  float q = dx * dx + dy * dy;
#pragma unroll
  for (int off = 32; off; off >>= 1) q += __shfl_xor(q, off);
  if ((tid & 63) == 0) red[tid >> 6] = q;
  __syncthreads();
  q = red[0] + red[1] + red[2] + red[3];
  const float inv = rsqrtf(q * (1.0f / DM) + 1e-5f);
  float2 gg = *reinterpret_cast<const float2*>(g + tid * 2);
  float2 bb = *reinterpret_cast<const float2*>(be + tid * 2);
  float ox = dx * inv * gg.x + bb.x;
  float oy = dy * inv * gg.y + bb.y;
  if (outf) {
    float2 o; o.x = ox; o.y = oy;
    *reinterpret_cast<float2*>(outf + base + tid * 2) = o;
  }
  if (outb) {
    short2 ob; ob.x = f2bf(ox); ob.y = f2bf(oy);
    *reinterpret_cast<short2*>(outb + base + tid * 2) = ob;
  }
}

extern "C" void kernel_launch(void* const* d_in, const int* in_sizes, int n_in,
                              void* d_out, int out_size, void* d_ws, size_t ws_size,
                              hipStream_t stream)
{
  const float* tgt = (const float*)d_in[0];
  const float* mem = (const float*)d_in[1];
  const int*   smp = (const int*)d_in[2];
  const float* wq1 = (const float*)d_in[3];  const float* bq1 = (const float*)d_in[4];
  const float* wk1 = (const float*)d_in[5];  const float* bk1 = (const float*)d_in[6];
  const float* wv1 = (const float*)d_in[7];  const float* bv1 = (const float*)d_in[8];
  const float* wo1 = (const float*)d_in[9];  const float* bo1 = (const float*)d_in[10];
  const float* wq2 = (const float*)d_in[11]; const float* bq2 = (const float*)d_in[12];
  const float* wk2 = (const float*)d_in[13]; const float* bk2 = (const float*)d_in[14];
  const float* wv2 = (const float*)d_in[15]; const float* bv2 = (const float*)d_in[16];
  const float* wo2 = (const float*)d_in[17]; const float* bo2 = (const float*)d_in[18];
  const float* c1w = (const float*)d_in[19]; const float* c1b = (const float*)d_in[20];
  const float* c2w = (const float*)d_in[21]; const float* c2b = (const float*)d_in[22];
  const float* g1  = (const float*)d_in[23]; const float* be1 = (const float*)d_in[24];
  const float* g2  = (const float*)d_in[25]; const float* be2 = (const float*)d_in[26];
  const float* g3  = (const float*)d_in[27]; const float* be3 = (const float*)d_in[28];
  float* outp = (float*)d_out;

  const int U   = in_sizes[2] / Ls;            // 35

  char* ws = (char*)d_ws;
  const size_t SZ = (size_t)MR * DM * sizeof(float);       // 16.78 MB
  float* W0   = (float*)(ws);
  float* W1   = (float*)(ws + SZ);
  float* W2   = (float*)(ws + 2 * SZ);
  float* Sbuf = (float*)(ws + 3 * SZ);                     // FFN hidden / QKzb region
  float* Op   = Sbuf + (size_t)ZH * 64 * Ls;               // prob PV partials
  __hip_bfloat16* QKzb = (__hip_bfloat16*)Sbuf;            // Qzb, then Kzb
  __hip_bfloat16* Qzb = QKzb;
  __hip_bfloat16* Kzb = QKzb + (size_t)ZH * Ls * 64;
  __hip_bfloat16* Tb  = (__hip_bfloat16*)(ws + 5 * SZ);
  __hip_bfloat16* Mb  = (__hip_bfloat16*)(ws + 5 * SZ + SZ / 2);
  __hip_bfloat16* Xb  = (__hip_bfloat16*)(ws + 6 * SZ);
  __hip_bfloat16* Vtb = (__hip_bfloat16*)(ws + 6 * SZ + SZ / 2);
  __hip_bfloat16* Wt3 = Vtb;                 // [wq1b;wk1b;wv1b] (dead before Vtb written)
  char* tail = ws + 7 * SZ;
  __hip_bfloat16* wo1b = (__hip_bfloat16*)tail; tail += DM * DM * 2;
  __hip_bfloat16* wq2b = (__hip_bfloat16*)tail; tail += DM * DM * 2;
  __hip_bfloat16* wk2b = (__hip_bfloat16*)tail; tail += DM * DM * 2;
  __hip_bfloat16* wv2b = (__hip_bfloat16*)tail; tail += DM * DM * 2;
  __hip_bfloat16* wo2b = (__hip_bfloat16*)tail; tail += DM * DM * 2;
  __hip_bfloat16* c1wb = (__hip_bfloat16*)tail; tail += DM * 4 * DM * 2;
  __hip_bfloat16* c2wb = (__hip_bfloat16*)tail; tail += DM * 4 * DM * 2;
  float* Ms  = (float*)tail; tail += (size_t)ZH * Ls * 4;
  int*   top = (int*)tail;   tail += (size_t)ZH * 64 * 4;
  float* mvp = (float*)tail; tail += (size_t)ZH * 16 * DHd * 4;
  float* Ml  = (float*)tail; tail += (size_t)16 * ZH * 64 * 4;
  float* Ll  = (float*)tail; tail += (size_t)16 * ZH * 64 * 4;
  __hip_bfloat16* Kb = Tb;
  __hip_bfloat16* Qb = (__hip_bfloat16*)d_out;  // parked until final LN
  __hip_bfloat16* hb = (__hip_bfloat16*)Sbuf;

  // ---- ALL converts, one dispatch ----
  CvtArgs ca;
  ca.s[0] = wq1; ca.d[0] = Wt3;
  ca.s[1] = wk1; ca.d[1] = Wt3 + DM * DM;
  ca.s[2] = wv1; ca.d[2] = Wt3 + 2 * DM * DM;
  ca.s[3] = wo1; ca.d[3] = wo1b;
  ca.s[4] = wq2; ca.d[4] = wq2b;
  ca.s[5] = wk2; ca.d[5] = wk2b;
  ca.s[6] = wv2; ca.d[6] = wv2b;
  ca.s[7] = wo2; ca.d[7] = wo2b;
  ca.s[8] = c1w; ca.d[8] = c1wb;
  ca.s[9] = c2w; ca.d[9] = c2wb;
  ca.s[10] = tgt; ca.d[10] = Tb;
  ca.s[11] = mem; ca.d[11] = Mb;
  k_cvt_all<<<dim3(12288), 256, 0, stream>>>(ca);

  // ---- layer-1 projections: ONE batched GEMM (Q->Qzb, K->Kzb, V->W2 f32) ----
  k_gemm_mfma<10, 0><<<dim3(MR / 128, 12), 256, 0, stream>>>(
      Tb, Wt3, bq1, bk1, bv1, nullptr, nullptr, W2, QKzb, MR, 1536, DM);

  // ---- ProbSparse ----
  if (U == 35)
    k_mscore4<35><<<dim3(2048), 256, 0, stream>>>(Qzb, Kzb, smp, Ms);
  else
    k_mscore4g<<<dim3(2048), 256, 0, stream>>>(Qzb, Kzb, smp, Ms, U);
  k_topk_w<<<dim3(ZH), 64, 0, stream>>>(Ms, top, U);
  k_probflash<<<dim3(16 * ZH), 256, 0, stream>>>(Qzb, Kzb, W2, top, Op, Ml, Ll, mvp, U);
  k_prob_comb2<<<dim3(ZH), 256, 0, stream>>>(Op, Ml, Ll, top, mvp, Xb, U);

  // ---- out-proj 1 (split-K=2) + residual LN (fused reduce) ----
  k_gemm_mfma<20, 0><<<dim3(MR / 128, DM / 128, 2), 256, 0, stream>>>(
      Xb, wo1b, nullptr, nullptr, nullptr, W0, W1, nullptr, nullptr, MR, DM, DM);
  k_ln2<2><<<dim3(MR), 256, 0, stream>>>(W0, W1, nullptr, nullptr,
                                         tgt, bo1, g1, be1, nullptr, Xb);

  // ---- layer-2 projections: ONE triple (Q from Xb; K,V from Mb via aux3) ----
  k_gemm_mfma<12, 0><<<dim3(MR / 128, 12), 256, 0, stream>>>(
      Xb, wq2b, bq2, bk2, bv2, Qb, Kb, Vtb, (void*)Mb, MR, 1536, DM);

  // ---- fused flash cross attention -> Xb (bf16) ----
  k_flash2<<<dim3(Ls / 128, ZH), 512, 0, stream>>>(Qb, Kb, Vtb, Xb);

  // ---- out-proj 2 (split-K=2) + LN (fused) ----
  k_gemm_mfma<20, 0><<<dim3(MR / 128, DM / 128, 2), 256, 0, stream>>>(
      Xb, wo2b, nullptr, nullptr, nullptr, W0, W2, nullptr, nullptr, MR, DM, DM);
  k_ln2<2><<<dim3(MR), 256, 0, stream>>>(W0, W2, nullptr, nullptr,
                                         nullptr, bo2, g2, be2, W1, Xb);

  // ---- FFN ----
  k_gemm_mfma<1, 1><<<dim3(MR / 128, 4 * DM / 128), 256, 0, stream>>>(
      Xb, c1wb, c1b, nullptr, nullptr, hb, nullptr, nullptr, nullptr, MR, 4 * DM, DM);
  k_gemm_mfma<20, 0><<<dim3(MR / 128, DM / 128, 2), 256, 0, stream>>>(
      hb, c2wb, nullptr, nullptr, nullptr, W0, W2, nullptr, nullptr, MR, DM, 2 * DM * 2);
  k_ln2<2><<<dim3(MR), 256, 0, stream>>>(W0, W2, nullptr, nullptr,
                                         W1, c2b, g3, be3, outp, nullptr);
}